// Round 2
// baseline (810.669 us; speedup 1.0000x reference)
//
#include <hip/hip_runtime.h>

// Problem constants (from reference)
#define MULT 64
#define FEATD 256
#define ZDIM 10

#define INV640f 0.03952847075210474f   // 1/sqrt(640)
#define ISQ2f   0.7071067811865476f    // 1/sqrt(2)
#define ISQ3f   0.5773502691896258f    // 1/sqrt(3)

typedef _Float16 f16_t;
typedef f16_t f16x8_t __attribute__((ext_vector_type(8)));
typedef f16_t f16x4_t __attribute__((ext_vector_type(4)));
typedef float f32x4_t __attribute__((ext_vector_type(4)));

// ---------------------------------------------------------------------------
// K0: transform x (n,256 natural: [x0(64) | x1(64,3)]) into f16 GEMM rows:
//   Xs[n*64 + u]        = x0[n,u]        (N x 64)
//   Xv[(3n+k)*64 + u]   = x1[n,u,k]      (3N x 64)
// ---------------------------------------------------------------------------
__global__ __launch_bounds__(256) void transform_x2(
    const float* __restrict__ x, f16_t* __restrict__ Xs,
    f16_t* __restrict__ Xv, int N)
{
    int idx = blockIdx.x * 256 + threadIdx.x;     // over N*64 (n,u) pairs
    if (idx >= N * MULT) return;
    int n = idx >> 6;
    int u = idx & 63;
    const float* row = x + (size_t)n * FEATD;
    Xs[idx] = (f16_t)row[u];
    const float* x1p = row + MULT + u * 3;
    Xv[((size_t)3 * n + 0) * MULT + u] = (f16_t)x1p[0];
    Xv[((size_t)3 * n + 1) * MULT + u] = (f16_t)x1p[1];
    Xv[((size_t)3 * n + 2) * MULT + u] = (f16_t)x1p[2];
}

// ---------------------------------------------------------------------------
// zprep: transpose z with INV640 folded in, in two layouts:
//   zt [v*N + n]   = z[n,v]*INV640       (for scalar-block GEMM rows, N rows)
//   ztv[v*3N + r]  = z[r/3,v]*INV640     (row-expanded for vector rows, 3N)
// ---------------------------------------------------------------------------
__global__ __launch_bounds__(256) void zprep_kernel(
    const float* __restrict__ z, float* __restrict__ zt,
    float* __restrict__ ztv, int N)
{
    int n = blockIdx.x * 256 + threadIdx.x;
    if (n >= N) return;
    const float* zr = z + (size_t)n * ZDIM;
#pragma unroll
    for (int v = 0; v < ZDIM; ++v) {
        float val = zr[v] * INV640f;
        zt[(size_t)v * N + n] = val;
        float* p = ztv + (size_t)v * 3 * N + 3 * (size_t)n;
        p[0] = val; p[1] = val; p[2] = val;
    }
}

// ---------------------------------------------------------------------------
// MFMA fctp kernels (f16). GEMM form: o[r,w] = sum_v z[r,v] * sum_u x[r,u]W[u,v,w].
// Per v: 2 MFMAs (K=64) with RAW x fragments (loop-invariant), then z folded
// into the f32 accumulator with 4 FMAs (zq float4 = z rows q*4..q*4+3).
// Single W per kernel: B[20] = 80 VGPRs -> no spill, 4 blocks/CU.
// 16x16x32 layouts: A [m=lane&15][k=q*8+j], B [k=q*8+j][n=lane&15],
// C/D col=lane&15, row=q*4+reg  (m89/m91-verified).
// ---------------------------------------------------------------------------
__device__ __forceinline__ void preload_W(
    const float* __restrict__ W, int c0, int q, int mm, f16x8_t (&B)[20])
{
    const int col = c0 + mm;
#pragma unroll
    for (int ks = 0; ks < 20; ++ks) {
        const int v = ks >> 1;
        const int ub = ((ks & 1) << 5) + (q << 3);
        const int base = v * 64 + col;
#pragma unroll
        for (int j = 0; j < 8; ++j)
            B[ks][j] = (f16_t)W[(ub + j) * 640 + base];   // W[u][v][w]
    }
}

// pass 1: s = fctp(x, z, Wsi) staged into out (natural layout)
__global__ __launch_bounds__(256, 4) void fctp_pass_out(
    const f16_t* __restrict__ Xs, const f16_t* __restrict__ Xv,
    const float* __restrict__ zt, const float* __restrict__ ztv,
    const float* __restrict__ Wsi0, const float* __restrict__ Wsi1,
    float* __restrict__ out, int N, int nsc)
{
    const int lane = threadIdx.x & 63;
    const int wave = threadIdx.x >> 6;
    const int c0 = wave << 4;            // 16-col stripe per wave
    const int q = lane >> 4;
    const int mm = lane & 15;
    const bool sc = (int)blockIdx.x < nsc;
    const float* W = sc ? Wsi0 : Wsi1;
    const f16_t* Xsel = sc ? Xs : Xv;
    const float* ztb = sc ? zt : ztv;
    const size_t zsr = sc ? (size_t)N : (size_t)3 * N;
    const int ntiles = sc ? (N >> 4) : ((3 * N) >> 4);
    const int worker = sc ? (int)blockIdx.x : ((int)blockIdx.x - nsc);
    const int nworkers = sc ? nsc : 3 * nsc;

    f16x8_t B[20];
    preload_W(W, c0, q, mm, B);

    for (int tile = worker; tile < ntiles; tile += nworkers) {
        const int r = (tile << 4) + mm;
        f16x8_t xlo = *(const f16x8_t*)(Xsel + ((size_t)r << 6) + (q << 3));
        f16x8_t xhi = *(const f16x8_t*)(Xsel + ((size_t)r << 6) + 32 + (q << 3));
        const int rb4 = (tile << 4) + (q << 2);   // this lane's 4 C-rows

        f32x4_t acc = {0.f, 0.f, 0.f, 0.f};
#pragma unroll
        for (int v = 0; v < ZDIM; ++v) {
            f32x4_t t = {0.f, 0.f, 0.f, 0.f};
            t = __builtin_amdgcn_mfma_f32_16x16x32_f16(xlo, B[2 * v], t, 0, 0, 0);
            t = __builtin_amdgcn_mfma_f32_16x16x32_f16(xhi, B[2 * v + 1], t, 0, 0, 0);
            f32x4_t zq = *(const f32x4_t*)(ztb + (size_t)v * zsr + rb4);
#pragma unroll
            for (int reg = 0; reg < 4; ++reg)
                acc[reg] = fmaf(zq[reg], t[reg], acc[reg]);
        }

        const int w = c0 + mm;
#pragma unroll
        for (int reg = 0; reg < 4; ++reg) {
            const int ro = rb4 + reg;
            if (sc) {
                out[(size_t)ro * FEATD + w] = acc[reg];               // s, scalar part
            } else {
                const unsigned nn = (unsigned)ro / 3u;
                const int k = ro - 3 * (int)nn;
                out[(size_t)nn * FEATD + MULT + w * 3 + k] = acc[reg]; // s, vec part
            }
        }
    }
}

// pass 2: xl = fctp(x, z, Wl1) staged as f16 GEMM rows xls / xlv
__global__ __launch_bounds__(256, 4) void fctp_pass_xl(
    const f16_t* __restrict__ Xs, const f16_t* __restrict__ Xv,
    const float* __restrict__ zt, const float* __restrict__ ztv,
    const float* __restrict__ Wl10, const float* __restrict__ Wl11,
    f16_t* __restrict__ xls, f16_t* __restrict__ xlv, int N, int nsc)
{
    const int lane = threadIdx.x & 63;
    const int wave = threadIdx.x >> 6;
    const int c0 = wave << 4;
    const int q = lane >> 4;
    const int mm = lane & 15;
    const bool sc = (int)blockIdx.x < nsc;
    const float* W = sc ? Wl10 : Wl11;
    const f16_t* Xsel = sc ? Xs : Xv;
    const float* ztb = sc ? zt : ztv;
    const size_t zsr = sc ? (size_t)N : (size_t)3 * N;
    const int ntiles = sc ? (N >> 4) : ((3 * N) >> 4);
    const int worker = sc ? (int)blockIdx.x : ((int)blockIdx.x - nsc);
    const int nworkers = sc ? nsc : 3 * nsc;

    f16x8_t B[20];
    preload_W(W, c0, q, mm, B);

    f16_t* Osel = sc ? xls : xlv;

    for (int tile = worker; tile < ntiles; tile += nworkers) {
        const int r = (tile << 4) + mm;
        f16x8_t xlo = *(const f16x8_t*)(Xsel + ((size_t)r << 6) + (q << 3));
        f16x8_t xhi = *(const f16x8_t*)(Xsel + ((size_t)r << 6) + 32 + (q << 3));
        const int rb4 = (tile << 4) + (q << 2);

        f32x4_t acc = {0.f, 0.f, 0.f, 0.f};
#pragma unroll
        for (int v = 0; v < ZDIM; ++v) {
            f32x4_t t = {0.f, 0.f, 0.f, 0.f};
            t = __builtin_amdgcn_mfma_f32_16x16x32_f16(xlo, B[2 * v], t, 0, 0, 0);
            t = __builtin_amdgcn_mfma_f32_16x16x32_f16(xhi, B[2 * v + 1], t, 0, 0, 0);
            f32x4_t zq = *(const f32x4_t*)(ztb + (size_t)v * zsr + rb4);
#pragma unroll
            for (int reg = 0; reg < 4; ++reg)
                acc[reg] = fmaf(zq[reg], t[reg], acc[reg]);
        }

        const int w = c0 + mm;
#pragma unroll
        for (int reg = 0; reg < 4; ++reg) {
            const int ro = rb4 + reg;
            Osel[((size_t)ro << 6) + w] = (f16_t)acc[reg];
        }
    }
}

__global__ __launch_bounds__(256, 4) void fctp_stageC_mfma(
    const float* __restrict__ aggs, const float* __restrict__ aggv,
    const float* __restrict__ zt, const float* __restrict__ ztv,
    const float* __restrict__ Wl20, const float* __restrict__ Wl21,
    float* __restrict__ out, int N, int nsc)
{
    const int lane = threadIdx.x & 63;
    const int wave = threadIdx.x >> 6;
    const int c0 = wave << 4;
    const int q = lane >> 4;
    const int mm = lane & 15;
    const bool sc = (int)blockIdx.x < nsc;
    const float* W = sc ? Wl20 : Wl21;
    const float* Asel = sc ? aggs : aggv;
    const float* ztb = sc ? zt : ztv;
    const size_t zsr = sc ? (size_t)N : (size_t)3 * N;
    const int ntiles = sc ? (N >> 4) : ((3 * N) >> 4);
    const int worker = sc ? (int)blockIdx.x : ((int)blockIdx.x - nsc);
    const int nworkers = sc ? nsc : 3 * nsc;

    f16x8_t B[20];
    preload_W(W, c0, q, mm, B);

    for (int tile = worker; tile < ntiles; tile += nworkers) {
        const int r = (tile << 4) + mm;
        const float* ap = Asel + ((size_t)r << 6) + (q << 3);
        float4 l0 = *(const float4*)(ap);
        float4 l1 = *(const float4*)(ap + 4);
        float4 h0 = *(const float4*)(ap + 32);
        float4 h1 = *(const float4*)(ap + 36);
        f16x8_t xlo, xhi;
        xlo[0] = (f16_t)l0.x; xlo[1] = (f16_t)l0.y; xlo[2] = (f16_t)l0.z; xlo[3] = (f16_t)l0.w;
        xlo[4] = (f16_t)l1.x; xlo[5] = (f16_t)l1.y; xlo[6] = (f16_t)l1.z; xlo[7] = (f16_t)l1.w;
        xhi[0] = (f16_t)h0.x; xhi[1] = (f16_t)h0.y; xhi[2] = (f16_t)h0.z; xhi[3] = (f16_t)h0.w;
        xhi[4] = (f16_t)h1.x; xhi[5] = (f16_t)h1.y; xhi[6] = (f16_t)h1.z; xhi[7] = (f16_t)h1.w;
        const int rb4 = (tile << 4) + (q << 2);

        f32x4_t acc = {0.f, 0.f, 0.f, 0.f};
#pragma unroll
        for (int v = 0; v < ZDIM; ++v) {
            f32x4_t t = {0.f, 0.f, 0.f, 0.f};
            t = __builtin_amdgcn_mfma_f32_16x16x32_f16(xlo, B[2 * v], t, 0, 0, 0);
            t = __builtin_amdgcn_mfma_f32_16x16x32_f16(xhi, B[2 * v + 1], t, 0, 0, 0);
            f32x4_t zq = *(const f32x4_t*)(ztb + (size_t)v * zsr + rb4);
#pragma unroll
            for (int reg = 0; reg < 4; ++reg)
                acc[reg] = fmaf(zq[reg], t[reg], acc[reg]);
        }

        const int w = c0 + mm;
#pragma unroll
        for (int reg = 0; reg < 4; ++reg) {
            const int ro = rb4 + reg;
            size_t idx;
            if (sc) {
                idx = (size_t)ro * FEATD + w;
            } else {
                const unsigned nn = (unsigned)ro / 3u;
                const int k = ro - 3 * (int)nn;
                idx = (size_t)nn * FEATD + MULT + w * 3 + k;
            }
            out[idx] = out[idx] + acc[reg] * 0.1f;   // s staged by pass_out; /10 here
        }
    }
}

// ---------------------------------------------------------------------------
// Counting sort of edges by dst (unchanged). scatter emits perm, sperm
// (permuted src) and eattr_p (permuted edge_attr).
// ---------------------------------------------------------------------------
__global__ __launch_bounds__(256) void hist_kernel(
    const int* __restrict__ edst, int* __restrict__ cnt, int E)
{
    int e = blockIdx.x * 256 + threadIdx.x;
    if (e >= E) return;
    atomicAdd(&cnt[edst[e]], 1);
}

__global__ __launch_bounds__(1024) void scan_block(
    const int* __restrict__ cnt, int* __restrict__ off,
    int* __restrict__ bsum, int N)
{
    __shared__ int sh[1024];
    int tid = threadIdx.x;
    int i = blockIdx.x * 1024 + tid;
    int v = (i < N) ? cnt[i] : 0;
    sh[tid] = v;
    __syncthreads();
#pragma unroll
    for (int d = 1; d < 1024; d <<= 1) {
        int t = (tid >= d) ? sh[tid - d] : 0;
        __syncthreads();
        sh[tid] += t;
        __syncthreads();
    }
    if (i < N) off[i + 1] = sh[tid];
    if (tid == 1023) bsum[blockIdx.x] = sh[1023];
    if (i == 0) off[0] = 0;
}

__global__ __launch_bounds__(64) void scan_sums(int* __restrict__ bsum, int nb)
{
    int tid = threadIdx.x;
    int v = (tid < nb) ? bsum[tid] : 0;
#pragma unroll
    for (int d = 1; d < 64; d <<= 1) {
        int t = __shfl_up(v, d, 64);
        if (tid >= d) v += t;
    }
    int ex = __shfl_up(v, 1, 64);
    if (tid == 0) ex = 0;
    if (tid < nb) bsum[tid] = ex;
}

__global__ __launch_bounds__(1024) void scan_add(
    int* __restrict__ off, const int* __restrict__ bsum, int N)
{
    int i = blockIdx.x * 1024 + threadIdx.x;
    if (i < N) off[i + 1] += bsum[blockIdx.x];
}

__global__ __launch_bounds__(256) void scatter_kernel(
    const int* __restrict__ edst, const int* __restrict__ esrc,
    const float* __restrict__ eattr, const int* __restrict__ off,
    int* __restrict__ cursor, int* __restrict__ perm,
    int* __restrict__ sperm, float* __restrict__ eattr_p, int E)
{
    int e = blockIdx.x * 256 + threadIdx.x;
    if (e >= E) return;
    int d = edst[e];
    int pos = off[d] + atomicAdd(&cursor[d], 1);
    perm[pos] = e;
    sperm[pos] = esrc[e];
    float4 at = *(const float4*)(eattr + (size_t)e * 4);
    *(float4*)(eattr_p + (size_t)pos * 4) = at;
}

// ---------------------------------------------------------------------------
// wgemm: w = elem[perm[pos]] @ tpw via MFMA, for positions [lo, lo+16*ntiles).
// One wave per 16-edge tile, 16 MFMAs cover all 256 w-cols. ISQ2/ISQ3 scales
// folded into the f16 output: wbuf[(pos-lo)*64 + u][0..3] = w1',w2',w3',w4'.
// ---------------------------------------------------------------------------
__global__ __launch_bounds__(256, 2) void wgemm_kernel(
    const int* __restrict__ perm, const float* __restrict__ elem,
    const float* __restrict__ tpw, f16_t* __restrict__ wbuf,
    int lo, int ntiles)
{
    int tt = blockIdx.x * 4 + (threadIdx.x >> 6);
    if (tt >= ntiles) return;
    const int lane = threadIdx.x & 63;
    const int mm = lane & 15, q = lane >> 4;

    // B-frags: stripe s covers cols s*16 + mm, k = q*8+j
    f16x8_t B[16];
#pragma unroll
    for (int s = 0; s < 16; ++s)
#pragma unroll
        for (int j = 0; j < 8; ++j)
            B[s][j] = (f16_t)tpw[(q * 8 + j) * 256 + s * 16 + mm];

    // A-frag: edge row mm of tile, k = q*8..q*8+7 (elem row gathered via perm)
    int p = lo + tt * 16 + mm;
    int e = perm[p];
    const float* er = elem + ((size_t)e << 5) + q * 8;
    float4 ea = *(const float4*)er;
    float4 eb = *(const float4*)(er + 4);
    f16x8_t A;
    A[0] = (f16_t)ea.x; A[1] = (f16_t)ea.y; A[2] = (f16_t)ea.z; A[3] = (f16_t)ea.w;
    A[4] = (f16_t)eb.x; A[5] = (f16_t)eb.y; A[6] = (f16_t)eb.z; A[7] = (f16_t)eb.w;

    f32x4_t D[16];
#pragma unroll
    for (int s = 0; s < 16; ++s) {
        f32x4_t zer = {0.f, 0.f, 0.f, 0.f};
        D[s] = __builtin_amdgcn_mfma_f32_16x16x32_f16(A, B[s], zer, 0, 0, 0);
    }

    // store: D col = s*16+mm -> qq = s>>2, u = (s&3)*16+mm; row = q*4+reg
#pragma unroll
    for (int reg = 0; reg < 4; ++reg) {
        const int row = q * 4 + reg;
        const size_t base = ((size_t)(tt * 16 + row)) << 6;   // row in wbuf
#pragma unroll
        for (int t = 0; t < 4; ++t) {
            const int u = t * 16 + mm;
            f16x4_t wq;
            wq[0] = (f16_t)(D[0 * 4 + t][reg] * ISQ2f);
            wq[1] = (f16_t)(D[1 * 4 + t][reg] * ISQ2f);
            wq[2] = (f16_t)(D[2 * 4 + t][reg] * ISQ2f);
            wq[3] = (f16_t)(D[3 * 4 + t][reg] * (ISQ2f * ISQ3f));
            *(f16x4_t*)(wbuf + ((base + u) << 2)) = wq;
        }
    }
}

// ---------------------------------------------------------------------------
// aggregate5: 1 wave per node, chunked over edge positions [lo, hi).
// Per edge: 8B w-load (coalesced), f16 gathers of xl[src], ~14-FMA TP,
// += into aggs/aggv (zero-initialized; same wave owns node in both chunks).
// ---------------------------------------------------------------------------
__device__ __forceinline__ void agg_edge5(
    float xs, float v0, float v1, float v2, int i, int lo,
    const f16_t* __restrict__ wbuf, const float* __restrict__ eattr_p, int u,
    float& accx, float& accy, float& accz, float& accw)
{
    f16x4_t wq = *(const f16x4_t*)(wbuf + ((((size_t)(i - lo)) << 6) + u) * 4);
    float w1 = (float)wq[0], w2 = (float)wq[1], w3 = (float)wq[2], w4 = (float)wq[3];
    float4 at = *(const float4*)(eattr_p + ((size_t)i << 2));
    float dot3 = v0 * at.y + v1 * at.z + v2 * at.w;
    accx = fmaf(w1 * xs, at.x, accx);
    accx = fmaf(w4, dot3, accx);
    float w2x = w2 * xs;
    accy = fmaf(w2x, at.y, accy);
    accz = fmaf(w2x, at.z, accz);
    accw = fmaf(w2x, at.w, accw);
    float w3s = w3 * at.x;
    accy = fmaf(w3s, v0, accy);
    accz = fmaf(w3s, v1, accz);
    accw = fmaf(w3s, v2, accw);
}

__global__ __launch_bounds__(256, 8) void aggregate5(
    const int* __restrict__ off, const int* __restrict__ sperm,
    const f16_t* __restrict__ wbuf, const float* __restrict__ eattr_p,
    const f16_t* __restrict__ xls, const f16_t* __restrict__ xlv,
    float* __restrict__ aggs, float* __restrict__ aggv,
    int N, int lo, int hi)
{
    int n = (blockIdx.x * 256 + threadIdx.x) >> 6;      // one wave per node
    if (n >= N) return;
    int u = threadIdx.x & 63;

    int s0 = __builtin_amdgcn_readfirstlane(off[n]);
    int s1 = __builtin_amdgcn_readfirstlane(off[n + 1]);
    int cs0 = s0 > lo ? s0 : lo;
    int cs1 = s1 < hi ? s1 : hi;
    if (cs0 >= cs1) return;

    float accx = 0.f, accy = 0.f, accz = 0.f, accw = 0.f;
    const int last = cs1 - 1;

    // depth-2 prefetch slots for the xl gather (the HBM-latency item)
    int sa = __builtin_amdgcn_readfirstlane(sperm[cs0]);
    float a_xs = (float)xls[((size_t)sa << 6) + u];
    float a_v0 = (float)xlv[((size_t)(3 * sa + 0) << 6) + u];
    float a_v1 = (float)xlv[((size_t)(3 * sa + 1) << 6) + u];
    float a_v2 = (float)xlv[((size_t)(3 * sa + 2) << 6) + u];
    int ib = (cs0 + 1 <= last) ? cs0 + 1 : last;
    int sb = __builtin_amdgcn_readfirstlane(sperm[ib]);
    float b_xs = (float)xls[((size_t)sb << 6) + u];
    float b_v0 = (float)xlv[((size_t)(3 * sb + 0) << 6) + u];
    float b_v1 = (float)xlv[((size_t)(3 * sb + 1) << 6) + u];
    float b_v2 = (float)xlv[((size_t)(3 * sb + 2) << 6) + u];

    int i = cs0;
    while (true) {
        agg_edge5(a_xs, a_v0, a_v1, a_v2, i, lo, wbuf, eattr_p, u,
                  accx, accy, accz, accw);
        {
            int inx = (i + 2 <= last) ? i + 2 : last;
            int sn = __builtin_amdgcn_readfirstlane(sperm[inx]);
            a_xs = (float)xls[((size_t)sn << 6) + u];
            a_v0 = (float)xlv[((size_t)(3 * sn + 0) << 6) + u];
            a_v1 = (float)xlv[((size_t)(3 * sn + 1) << 6) + u];
            a_v2 = (float)xlv[((size_t)(3 * sn + 2) << 6) + u];
        }
        if (++i > last) break;
        agg_edge5(b_xs, b_v0, b_v1, b_v2, i, lo, wbuf, eattr_p, u,
                  accx, accy, accz, accw);
        {
            int inx = (i + 2 <= last) ? i + 2 : last;
            int sn = __builtin_amdgcn_readfirstlane(sperm[inx]);
            b_xs = (float)xls[((size_t)sn << 6) + u];
            b_v0 = (float)xlv[((size_t)(3 * sn + 0) << 6) + u];
            b_v1 = (float)xlv[((size_t)(3 * sn + 1) << 6) + u];
            b_v2 = (float)xlv[((size_t)(3 * sn + 2) << 6) + u];
        }
        if (++i > last) break;
    }

    aggs[((size_t)n << 6) + u] += accx;
    aggv[((size_t)(3 * n + 0) << 6) + u] += accy;
    aggv[((size_t)(3 * n + 1) << 6) + u] += accz;
    aggv[((size_t)(3 * n + 2) << 6) + u] += accw;
}

// ---------------------------------------------------------------------------
extern "C" void kernel_launch(void* const* d_in, const int* in_sizes, int n_in,
                              void* d_out, int out_size, void* d_ws, size_t ws_size,
                              hipStream_t stream)
{
    const float* x     = (const float*)d_in[0];
    const float* z     = (const float*)d_in[1];
    const int*   esrc  = (const int*)d_in[2];
    const int*   edst  = (const int*)d_in[3];
    const float* elem  = (const float*)d_in[4];
    const float* eattr = (const float*)d_in[5];
    const float* Wsi0  = (const float*)d_in[6];
    const float* Wsi1  = (const float*)d_in[7];
    const float* Wl10  = (const float*)d_in[8];
    const float* Wl11  = (const float*)d_in[9];
    const float* Wl20  = (const float*)d_in[10];
    const float* Wl21  = (const float*)d_in[11];
    const float* tpw   = (const float*)d_in[12];
    float* out = (float*)d_out;

    const int N = in_sizes[1] / ZDIM;      // 50000
    const int E = in_sizes[2];             // 500000
    const int Ehalf = E / 2;               // 250000 (divisible by 16)

    // workspace carve-up (~226 MB, under the ~230 MB proven previously):
    f16_t* xls  = (f16_t*)d_ws;                          // N*64   f16
    f16_t* xlv  = xls + (size_t)N * 64;                  // 3N*64  f16
    float* aggs = (float*)(xlv + (size_t)3 * N * 64);    // N*64   f32
    float* aggv = aggs + (size_t)N * 64;                 // 3N*64  f32
    // region R: union of {Xs,Xv} (dead after fctp passes) and wbuf (per-chunk w)
    char*  R    = (char*)(aggv + (size_t)3 * N * 64);
    f16_t* Xs   = (f16_t*)R;                             // N*64   f16
    f16_t* Xv   = Xs + (size_t)N * 64;                   // 3N*64  f16
    f16_t* wbuf = (f16_t*)R;                             // Ehalf*256 f16 = 128 MB
    size_t Rbytes = (size_t)Ehalf * 256 * sizeof(f16_t);
    float* eattr_p = (float*)(R + Rbytes);               // E*4 f32
    int*   sperm   = (int*)(eattr_p + (size_t)E * 4);    // E
    int*   perm    = sperm + E;                          // E
    int*   cnt     = perm + E;                           // N
    int*   cursor  = cnt + N;                            // N
    int*   off     = cursor + N;                         // N+1
    int*   bsum    = off + (N + 1);                      // 64
    // z transposes, 256B-aligned for float4 loads: zt (10N) + ztv (30N) f32
    size_t zoff = (((size_t)(bsum + 64) - (size_t)d_ws) + 255) & ~(size_t)255;
    float* zt  = (float*)((char*)d_ws + zoff);           // 10N f32 (2 MB)
    float* ztv = zt + (size_t)10 * N;                    // 30N f32 (6 MB)

    const int SCAN_B = 1024;
    int nb = (N + SCAN_B - 1) / SCAN_B;  // 49 (<=64 required by scan_sums)

    hipMemsetAsync(cnt, 0, 2 * (size_t)N * sizeof(int), stream);       // cnt+cursor
    hipMemsetAsync(aggs, 0, (size_t)4 * N * 64 * sizeof(float), stream); // aggs+aggv

    int g0 = (N * MULT + 255) / 256;
    hipLaunchKernelGGL(transform_x2, dim3(g0), dim3(256), 0, stream, x, Xs, Xv, N);
    int gz = (N + 255) / 256;
    hipLaunchKernelGGL(zprep_kernel, dim3(gz), dim3(256), 0, stream, z, zt, ztv, N);

    // stageA split: two single-W passes, 4 blocks/CU each (no spill)
    hipLaunchKernelGGL(fctp_pass_xl, dim3(1024), dim3(256), 0, stream,
                       Xs, Xv, zt, ztv, Wl10, Wl11, xls, xlv, N, 256);
    hipLaunchKernelGGL(fctp_pass_out, dim3(1024), dim3(256), 0, stream,
                       Xs, Xv, zt, ztv, Wsi0, Wsi1, out, N, 256);

    int geh = (E + 255) / 256;
    hipLaunchKernelGGL(hist_kernel, dim3(geh), dim3(256), 0, stream,
                       edst, cnt, E);
    hipLaunchKernelGGL(scan_block, dim3(nb), dim3(SCAN_B), 0, stream,
                       cnt, off, bsum, N);
    hipLaunchKernelGGL(scan_sums, dim3(1), dim3(64), 0, stream, bsum, nb);
    hipLaunchKernelGGL(scan_add, dim3(nb), dim3(SCAN_B), 0, stream,
                       off, bsum, N);
    hipLaunchKernelGGL(scatter_kernel, dim3(geh), dim3(256), 0, stream,
                       edst, esrc, eattr, off, cursor, perm, sperm, eattr_p, E);

    // two node-aligned edge chunks: wgemm (w via MFMA) -> aggregate (+=)
    int wt = Ehalf / 16;                       // 15625 tiles per chunk
    int gw = (wt + 3) / 4;
    int ga = (N * 64 + 255) / 256;
    for (int c = 0; c < 2; ++c) {
        int lo = c * Ehalf, hi = lo + Ehalf;
        hipLaunchKernelGGL(wgemm_kernel, dim3(gw), dim3(256), 0, stream,
                           perm, elem, tpw, wbuf, lo, wt);
        hipLaunchKernelGGL(aggregate5, dim3(ga), dim3(256), 0, stream,
                           off, sperm, wbuf, eattr_p, xls, xlv,
                           aggs, aggv, N, lo, hi);
    }

    hipLaunchKernelGGL(fctp_stageC_mfma, dim3(1024), dim3(256), 0, stream,
                       aggs, aggv, zt, ztv, Wl20, Wl21, out, N, 256);
}

// Round 3
// 646.759 us; speedup vs baseline: 1.2534x; 1.2534x over previous
//
#include <hip/hip_runtime.h>

// Problem constants (from reference)
#define MULT 64
#define FEATD 256
#define ZDIM 10

#define INV640f 0.03952847075210474f   // 1/sqrt(640)
#define ISQ2f   0.7071067811865476f    // 1/sqrt(2)
#define ISQ3f   0.5773502691896258f    // 1/sqrt(3)

typedef _Float16 f16_t;
typedef f16_t f16x8_t __attribute__((ext_vector_type(8)));
typedef f16_t f16x4_t __attribute__((ext_vector_type(4)));
typedef float f32x4_t __attribute__((ext_vector_type(4)));

// ---------------------------------------------------------------------------
// K0: transform x (n,256 natural: [x0(64) | x1(64,3)]) into f16 GEMM rows:
//   Xs[n*64 + u]        = x0[n,u]        (N x 64)
//   Xv[(3n+k)*64 + u]   = x1[n,u,k]      (3N x 64)
// ---------------------------------------------------------------------------
__global__ __launch_bounds__(256) void transform_x2(
    const float* __restrict__ x, f16_t* __restrict__ Xs,
    f16_t* __restrict__ Xv, int N)
{
    int idx = blockIdx.x * 256 + threadIdx.x;     // over N*64 (n,u) pairs
    if (idx >= N * MULT) return;
    int n = idx >> 6;
    int u = idx & 63;
    const float* row = x + (size_t)n * FEATD;
    Xs[idx] = (f16_t)row[u];
    const float* x1p = row + MULT + u * 3;
    Xv[((size_t)3 * n + 0) * MULT + u] = (f16_t)x1p[0];
    Xv[((size_t)3 * n + 1) * MULT + u] = (f16_t)x1p[1];
    Xv[((size_t)3 * n + 2) * MULT + u] = (f16_t)x1p[2];
}

// ---------------------------------------------------------------------------
// zprep: transpose z with INV640 folded in, in two layouts:
//   zt [v*N + n]   = z[n,v]*INV640       (for scalar-block GEMM rows, N rows)
//   ztv[v*3N + r]  = z[r/3,v]*INV640     (row-expanded for vector rows, 3N)
// ---------------------------------------------------------------------------
__global__ __launch_bounds__(256) void zprep_kernel(
    const float* __restrict__ z, float* __restrict__ zt,
    float* __restrict__ ztv, int N)
{
    int n = blockIdx.x * 256 + threadIdx.x;
    if (n >= N) return;
    const float* zr = z + (size_t)n * ZDIM;
#pragma unroll
    for (int v = 0; v < ZDIM; ++v) {
        float val = zr[v] * INV640f;
        zt[(size_t)v * N + n] = val;
        float* p = ztv + (size_t)v * 3 * N + 3 * (size_t)n;
        p[0] = val; p[1] = val; p[2] = val;
    }
}

// ---------------------------------------------------------------------------
// MFMA fctp kernels (f16). GEMM form: o[r,w] = sum_v z[r,v] * sum_u x[r,u]W[u,v,w].
// Per v: 2 MFMAs (K=64) with RAW x fragments (loop-invariant), then z folded
// into the f32 accumulator with 4 FMAs (zq float4 = z rows q*4..q*4+3).
// REGISTER BUDGET NOTE: B[20] = 80 regs (AGPR side of the unified file) plus
// ~90 VGPRs working set. __launch_bounds__(256,2) (256-reg budget) is REQUIRED:
// (256,4) caps at 128 and spills B to scratch (round-2 lesson: FETCH 55->416MB).
// 16x16x32 layouts: A [m=lane&15][k=q*8+j], B [k=q*8+j][n=lane&15],
// C/D col=lane&15, row=q*4+reg  (m89/m91-verified).
// ---------------------------------------------------------------------------
__device__ __forceinline__ void preload_W(
    const float* __restrict__ W, int c0, int q, int mm, f16x8_t (&B)[20])
{
    const int col = c0 + mm;
#pragma unroll
    for (int ks = 0; ks < 20; ++ks) {
        const int v = ks >> 1;
        const int ub = ((ks & 1) << 5) + (q << 3);
        const int base = v * 64 + col;
#pragma unroll
        for (int j = 0; j < 8; ++j)
            B[ks][j] = (f16_t)W[(ub + j) * 640 + base];   // W[u][v][w]
    }
}

// pass 1: s = fctp(x, z, Wsi) staged into out (natural layout)
__global__ __launch_bounds__(256, 2) void fctp_pass_out(
    const f16_t* __restrict__ Xs, const f16_t* __restrict__ Xv,
    const float* __restrict__ zt, const float* __restrict__ ztv,
    const float* __restrict__ Wsi0, const float* __restrict__ Wsi1,
    float* __restrict__ out, int N, int nsc)
{
    const int lane = threadIdx.x & 63;
    const int wave = threadIdx.x >> 6;
    const int c0 = wave << 4;            // 16-col stripe per wave
    const int q = lane >> 4;
    const int mm = lane & 15;
    const bool sc = (int)blockIdx.x < nsc;
    const float* W = sc ? Wsi0 : Wsi1;
    const f16_t* Xsel = sc ? Xs : Xv;
    const float* ztb = sc ? zt : ztv;
    const size_t zsr = sc ? (size_t)N : (size_t)3 * N;
    const int ntiles = sc ? (N >> 4) : ((3 * N) >> 4);
    const int worker = sc ? (int)blockIdx.x : ((int)blockIdx.x - nsc);
    const int nworkers = sc ? nsc : 3 * nsc;

    f16x8_t B[20];
    preload_W(W, c0, q, mm, B);

    for (int tile = worker; tile < ntiles; tile += nworkers) {
        const int r = (tile << 4) + mm;
        f16x8_t xlo = *(const f16x8_t*)(Xsel + ((size_t)r << 6) + (q << 3));
        f16x8_t xhi = *(const f16x8_t*)(Xsel + ((size_t)r << 6) + 32 + (q << 3));
        const int rb4 = (tile << 4) + (q << 2);   // this lane's 4 C-rows

        f32x4_t acc = {0.f, 0.f, 0.f, 0.f};
#pragma unroll
        for (int v = 0; v < ZDIM; ++v) {
            f32x4_t t = {0.f, 0.f, 0.f, 0.f};
            t = __builtin_amdgcn_mfma_f32_16x16x32_f16(xlo, B[2 * v], t, 0, 0, 0);
            t = __builtin_amdgcn_mfma_f32_16x16x32_f16(xhi, B[2 * v + 1], t, 0, 0, 0);
            f32x4_t zq = *(const f32x4_t*)(ztb + (size_t)v * zsr + rb4);
#pragma unroll
            for (int reg = 0; reg < 4; ++reg)
                acc[reg] = fmaf(zq[reg], t[reg], acc[reg]);
        }

        const int w = c0 + mm;
#pragma unroll
        for (int reg = 0; reg < 4; ++reg) {
            const int ro = rb4 + reg;
            if (sc) {
                out[(size_t)ro * FEATD + w] = acc[reg];               // s, scalar part
            } else {
                const unsigned nn = (unsigned)ro / 3u;
                const int k = ro - 3 * (int)nn;
                out[(size_t)nn * FEATD + MULT + w * 3 + k] = acc[reg]; // s, vec part
            }
        }
    }
}

// pass 2: xl = fctp(x, z, Wl1) staged as f16 GEMM rows xls / xlv
__global__ __launch_bounds__(256, 2) void fctp_pass_xl(
    const f16_t* __restrict__ Xs, const f16_t* __restrict__ Xv,
    const float* __restrict__ zt, const float* __restrict__ ztv,
    const float* __restrict__ Wl10, const float* __restrict__ Wl11,
    f16_t* __restrict__ xls, f16_t* __restrict__ xlv, int N, int nsc)
{
    const int lane = threadIdx.x & 63;
    const int wave = threadIdx.x >> 6;
    const int c0 = wave << 4;
    const int q = lane >> 4;
    const int mm = lane & 15;
    const bool sc = (int)blockIdx.x < nsc;
    const float* W = sc ? Wl10 : Wl11;
    const f16_t* Xsel = sc ? Xs : Xv;
    const float* ztb = sc ? zt : ztv;
    const size_t zsr = sc ? (size_t)N : (size_t)3 * N;
    const int ntiles = sc ? (N >> 4) : ((3 * N) >> 4);
    const int worker = sc ? (int)blockIdx.x : ((int)blockIdx.x - nsc);
    const int nworkers = sc ? nsc : 3 * nsc;

    f16x8_t B[20];
    preload_W(W, c0, q, mm, B);

    f16_t* Osel = sc ? xls : xlv;

    for (int tile = worker; tile < ntiles; tile += nworkers) {
        const int r = (tile << 4) + mm;
        f16x8_t xlo = *(const f16x8_t*)(Xsel + ((size_t)r << 6) + (q << 3));
        f16x8_t xhi = *(const f16x8_t*)(Xsel + ((size_t)r << 6) + 32 + (q << 3));
        const int rb4 = (tile << 4) + (q << 2);

        f32x4_t acc = {0.f, 0.f, 0.f, 0.f};
#pragma unroll
        for (int v = 0; v < ZDIM; ++v) {
            f32x4_t t = {0.f, 0.f, 0.f, 0.f};
            t = __builtin_amdgcn_mfma_f32_16x16x32_f16(xlo, B[2 * v], t, 0, 0, 0);
            t = __builtin_amdgcn_mfma_f32_16x16x32_f16(xhi, B[2 * v + 1], t, 0, 0, 0);
            f32x4_t zq = *(const f32x4_t*)(ztb + (size_t)v * zsr + rb4);
#pragma unroll
            for (int reg = 0; reg < 4; ++reg)
                acc[reg] = fmaf(zq[reg], t[reg], acc[reg]);
        }

        const int w = c0 + mm;
#pragma unroll
        for (int reg = 0; reg < 4; ++reg) {
            const int ro = rb4 + reg;
            Osel[((size_t)ro << 6) + w] = (f16_t)acc[reg];
        }
    }
}

__global__ __launch_bounds__(256, 2) void fctp_stageC_mfma(
    const float* __restrict__ aggs, const float* __restrict__ aggv,
    const float* __restrict__ zt, const float* __restrict__ ztv,
    const float* __restrict__ Wl20, const float* __restrict__ Wl21,
    float* __restrict__ out, int N, int nsc)
{
    const int lane = threadIdx.x & 63;
    const int wave = threadIdx.x >> 6;
    const int c0 = wave << 4;
    const int q = lane >> 4;
    const int mm = lane & 15;
    const bool sc = (int)blockIdx.x < nsc;
    const float* W = sc ? Wl20 : Wl21;
    const float* Asel = sc ? aggs : aggv;
    const float* ztb = sc ? zt : ztv;
    const size_t zsr = sc ? (size_t)N : (size_t)3 * N;
    const int ntiles = sc ? (N >> 4) : ((3 * N) >> 4);
    const int worker = sc ? (int)blockIdx.x : ((int)blockIdx.x - nsc);
    const int nworkers = sc ? nsc : 3 * nsc;

    f16x8_t B[20];
    preload_W(W, c0, q, mm, B);

    for (int tile = worker; tile < ntiles; tile += nworkers) {
        const int r = (tile << 4) + mm;
        const float* ap = Asel + ((size_t)r << 6) + (q << 3);
        float4 l0 = *(const float4*)(ap);
        float4 l1 = *(const float4*)(ap + 4);
        float4 h0 = *(const float4*)(ap + 32);
        float4 h1 = *(const float4*)(ap + 36);
        f16x8_t xlo, xhi;
        xlo[0] = (f16_t)l0.x; xlo[1] = (f16_t)l0.y; xlo[2] = (f16_t)l0.z; xlo[3] = (f16_t)l0.w;
        xlo[4] = (f16_t)l1.x; xlo[5] = (f16_t)l1.y; xlo[6] = (f16_t)l1.z; xlo[7] = (f16_t)l1.w;
        xhi[0] = (f16_t)h0.x; xhi[1] = (f16_t)h0.y; xhi[2] = (f16_t)h0.z; xhi[3] = (f16_t)h0.w;
        xhi[4] = (f16_t)h1.x; xhi[5] = (f16_t)h1.y; xhi[6] = (f16_t)h1.z; xhi[7] = (f16_t)h1.w;
        const int rb4 = (tile << 4) + (q << 2);

        f32x4_t acc = {0.f, 0.f, 0.f, 0.f};
#pragma unroll
        for (int v = 0; v < ZDIM; ++v) {
            f32x4_t t = {0.f, 0.f, 0.f, 0.f};
            t = __builtin_amdgcn_mfma_f32_16x16x32_f16(xlo, B[2 * v], t, 0, 0, 0);
            t = __builtin_amdgcn_mfma_f32_16x16x32_f16(xhi, B[2 * v + 1], t, 0, 0, 0);
            f32x4_t zq = *(const f32x4_t*)(ztb + (size_t)v * zsr + rb4);
#pragma unroll
            for (int reg = 0; reg < 4; ++reg)
                acc[reg] = fmaf(zq[reg], t[reg], acc[reg]);
        }

        const int w = c0 + mm;
#pragma unroll
        for (int reg = 0; reg < 4; ++reg) {
            const int ro = rb4 + reg;
            size_t idx;
            if (sc) {
                idx = (size_t)ro * FEATD + w;
            } else {
                const unsigned nn = (unsigned)ro / 3u;
                const int k = ro - 3 * (int)nn;
                idx = (size_t)nn * FEATD + MULT + w * 3 + k;
            }
            out[idx] = out[idx] + acc[reg] * 0.1f;   // s staged by pass_out; /10 here
        }
    }
}

// ---------------------------------------------------------------------------
// Counting sort of edges by dst (unchanged). scatter emits perm, sperm
// (permuted src) and eattr_p (permuted edge_attr).
// ---------------------------------------------------------------------------
__global__ __launch_bounds__(256) void hist_kernel(
    const int* __restrict__ edst, int* __restrict__ cnt, int E)
{
    int e = blockIdx.x * 256 + threadIdx.x;
    if (e >= E) return;
    atomicAdd(&cnt[edst[e]], 1);
}

__global__ __launch_bounds__(1024) void scan_block(
    const int* __restrict__ cnt, int* __restrict__ off,
    int* __restrict__ bsum, int N)
{
    __shared__ int sh[1024];
    int tid = threadIdx.x;
    int i = blockIdx.x * 1024 + tid;
    int v = (i < N) ? cnt[i] : 0;
    sh[tid] = v;
    __syncthreads();
#pragma unroll
    for (int d = 1; d < 1024; d <<= 1) {
        int t = (tid >= d) ? sh[tid - d] : 0;
        __syncthreads();
        sh[tid] += t;
        __syncthreads();
    }
    if (i < N) off[i + 1] = sh[tid];
    if (tid == 1023) bsum[blockIdx.x] = sh[1023];
    if (i == 0) off[0] = 0;
}

__global__ __launch_bounds__(64) void scan_sums(int* __restrict__ bsum, int nb)
{
    int tid = threadIdx.x;
    int v = (tid < nb) ? bsum[tid] : 0;
#pragma unroll
    for (int d = 1; d < 64; d <<= 1) {
        int t = __shfl_up(v, d, 64);
        if (tid >= d) v += t;
    }
    int ex = __shfl_up(v, 1, 64);
    if (tid == 0) ex = 0;
    if (tid < nb) bsum[tid] = ex;
}

__global__ __launch_bounds__(1024) void scan_add(
    int* __restrict__ off, const int* __restrict__ bsum, int N)
{
    int i = blockIdx.x * 1024 + threadIdx.x;
    if (i < N) off[i + 1] += bsum[blockIdx.x];
}

__global__ __launch_bounds__(256) void scatter_kernel(
    const int* __restrict__ edst, const int* __restrict__ esrc,
    const float* __restrict__ eattr, const int* __restrict__ off,
    int* __restrict__ cursor, int* __restrict__ perm,
    int* __restrict__ sperm, float* __restrict__ eattr_p, int E)
{
    int e = blockIdx.x * 256 + threadIdx.x;
    if (e >= E) return;
    int d = edst[e];
    int pos = off[d] + atomicAdd(&cursor[d], 1);
    perm[pos] = e;
    sperm[pos] = esrc[e];
    float4 at = *(const float4*)(eattr + (size_t)e * 4);
    *(float4*)(eattr_p + (size_t)pos * 4) = at;
}

// ---------------------------------------------------------------------------
// wgemm: w = elem[perm[pos]] @ tpw via MFMA, for positions [lo, lo+16*ntiles).
// One wave per 16-edge tile, 16 MFMAs cover all 256 w-cols. ISQ2/ISQ3 scales
// folded into the f16 output: wbuf[(pos-lo)*64 + u][0..3] = w1',w2',w3',w4'.
// ---------------------------------------------------------------------------
__global__ __launch_bounds__(256, 2) void wgemm_kernel(
    const int* __restrict__ perm, const float* __restrict__ elem,
    const float* __restrict__ tpw, f16_t* __restrict__ wbuf,
    int lo, int ntiles)
{
    int tt = blockIdx.x * 4 + (threadIdx.x >> 6);
    if (tt >= ntiles) return;
    const int lane = threadIdx.x & 63;
    const int mm = lane & 15, q = lane >> 4;

    // B-frags: stripe s covers cols s*16 + mm, k = q*8+j
    f16x8_t B[16];
#pragma unroll
    for (int s = 0; s < 16; ++s)
#pragma unroll
        for (int j = 0; j < 8; ++j)
            B[s][j] = (f16_t)tpw[(q * 8 + j) * 256 + s * 16 + mm];

    // A-frag: edge row mm of tile, k = q*8..q*8+7 (elem row gathered via perm)
    int p = lo + tt * 16 + mm;
    int e = perm[p];
    const float* er = elem + ((size_t)e << 5) + q * 8;
    float4 ea = *(const float4*)er;
    float4 eb = *(const float4*)(er + 4);
    f16x8_t A;
    A[0] = (f16_t)ea.x; A[1] = (f16_t)ea.y; A[2] = (f16_t)ea.z; A[3] = (f16_t)ea.w;
    A[4] = (f16_t)eb.x; A[5] = (f16_t)eb.y; A[6] = (f16_t)eb.z; A[7] = (f16_t)eb.w;

    f32x4_t D[16];
#pragma unroll
    for (int s = 0; s < 16; ++s) {
        f32x4_t zer = {0.f, 0.f, 0.f, 0.f};
        D[s] = __builtin_amdgcn_mfma_f32_16x16x32_f16(A, B[s], zer, 0, 0, 0);
    }

    // store: D col = s*16+mm -> qq = s>>2, u = (s&3)*16+mm; row = q*4+reg
#pragma unroll
    for (int reg = 0; reg < 4; ++reg) {
        const int row = q * 4 + reg;
        const size_t base = ((size_t)(tt * 16 + row)) << 6;   // row in wbuf
#pragma unroll
        for (int t = 0; t < 4; ++t) {
            const int u = t * 16 + mm;
            f16x4_t wq;
            wq[0] = (f16_t)(D[0 * 4 + t][reg] * ISQ2f);
            wq[1] = (f16_t)(D[1 * 4 + t][reg] * ISQ2f);
            wq[2] = (f16_t)(D[2 * 4 + t][reg] * ISQ2f);
            wq[3] = (f16_t)(D[3 * 4 + t][reg] * (ISQ2f * ISQ3f));
            *(f16x4_t*)(wbuf + ((base + u) << 2)) = wq;
        }
    }
}

// ---------------------------------------------------------------------------
// aggregate5: 1 wave per node, chunked over edge positions [lo, hi).
// Per edge: 8B w-load (coalesced), f16 gathers of xl[src], ~14-FMA TP,
// += into aggs/aggv (zero-initialized; same wave owns node in both chunks).
// ---------------------------------------------------------------------------
__device__ __forceinline__ void agg_edge5(
    float xs, float v0, float v1, float v2, int i, int lo,
    const f16_t* __restrict__ wbuf, const float* __restrict__ eattr_p, int u,
    float& accx, float& accy, float& accz, float& accw)
{
    f16x4_t wq = *(const f16x4_t*)(wbuf + ((((size_t)(i - lo)) << 6) + u) * 4);
    float w1 = (float)wq[0], w2 = (float)wq[1], w3 = (float)wq[2], w4 = (float)wq[3];
    float4 at = *(const float4*)(eattr_p + ((size_t)i << 2));
    float dot3 = v0 * at.y + v1 * at.z + v2 * at.w;
    accx = fmaf(w1 * xs, at.x, accx);
    accx = fmaf(w4, dot3, accx);
    float w2x = w2 * xs;
    accy = fmaf(w2x, at.y, accy);
    accz = fmaf(w2x, at.z, accz);
    accw = fmaf(w2x, at.w, accw);
    float w3s = w3 * at.x;
    accy = fmaf(w3s, v0, accy);
    accz = fmaf(w3s, v1, accz);
    accw = fmaf(w3s, v2, accw);
}

__global__ __launch_bounds__(256, 8) void aggregate5(
    const int* __restrict__ off, const int* __restrict__ sperm,
    const f16_t* __restrict__ wbuf, const float* __restrict__ eattr_p,
    const f16_t* __restrict__ xls, const f16_t* __restrict__ xlv,
    float* __restrict__ aggs, float* __restrict__ aggv,
    int N, int lo, int hi)
{
    int n = (blockIdx.x * 256 + threadIdx.x) >> 6;      // one wave per node
    if (n >= N) return;
    int u = threadIdx.x & 63;

    int s0 = __builtin_amdgcn_readfirstlane(off[n]);
    int s1 = __builtin_amdgcn_readfirstlane(off[n + 1]);
    int cs0 = s0 > lo ? s0 : lo;
    int cs1 = s1 < hi ? s1 : hi;
    if (cs0 >= cs1) return;

    float accx = 0.f, accy = 0.f, accz = 0.f, accw = 0.f;
    const int last = cs1 - 1;

    // depth-2 prefetch slots for the xl gather (the HBM-latency item)
    int sa = __builtin_amdgcn_readfirstlane(sperm[cs0]);
    float a_xs = (float)xls[((size_t)sa << 6) + u];
    float a_v0 = (float)xlv[((size_t)(3 * sa + 0) << 6) + u];
    float a_v1 = (float)xlv[((size_t)(3 * sa + 1) << 6) + u];
    float a_v2 = (float)xlv[((size_t)(3 * sa + 2) << 6) + u];
    int ib = (cs0 + 1 <= last) ? cs0 + 1 : last;
    int sb = __builtin_amdgcn_readfirstlane(sperm[ib]);
    float b_xs = (float)xls[((size_t)sb << 6) + u];
    float b_v0 = (float)xlv[((size_t)(3 * sb + 0) << 6) + u];
    float b_v1 = (float)xlv[((size_t)(3 * sb + 1) << 6) + u];
    float b_v2 = (float)xlv[((size_t)(3 * sb + 2) << 6) + u];

    int i = cs0;
    while (true) {
        agg_edge5(a_xs, a_v0, a_v1, a_v2, i, lo, wbuf, eattr_p, u,
                  accx, accy, accz, accw);
        {
            int inx = (i + 2 <= last) ? i + 2 : last;
            int sn = __builtin_amdgcn_readfirstlane(sperm[inx]);
            a_xs = (float)xls[((size_t)sn << 6) + u];
            a_v0 = (float)xlv[((size_t)(3 * sn + 0) << 6) + u];
            a_v1 = (float)xlv[((size_t)(3 * sn + 1) << 6) + u];
            a_v2 = (float)xlv[((size_t)(3 * sn + 2) << 6) + u];
        }
        if (++i > last) break;
        agg_edge5(b_xs, b_v0, b_v1, b_v2, i, lo, wbuf, eattr_p, u,
                  accx, accy, accz, accw);
        {
            int inx = (i + 2 <= last) ? i + 2 : last;
            int sn = __builtin_amdgcn_readfirstlane(sperm[inx]);
            b_xs = (float)xls[((size_t)sn << 6) + u];
            b_v0 = (float)xlv[((size_t)(3 * sn + 0) << 6) + u];
            b_v1 = (float)xlv[((size_t)(3 * sn + 1) << 6) + u];
            b_v2 = (float)xlv[((size_t)(3 * sn + 2) << 6) + u];
        }
        if (++i > last) break;
    }

    aggs[((size_t)n << 6) + u] += accx;
    aggv[((size_t)(3 * n + 0) << 6) + u] += accy;
    aggv[((size_t)(3 * n + 1) << 6) + u] += accz;
    aggv[((size_t)(3 * n + 2) << 6) + u] += accw;
}

// ---------------------------------------------------------------------------
extern "C" void kernel_launch(void* const* d_in, const int* in_sizes, int n_in,
                              void* d_out, int out_size, void* d_ws, size_t ws_size,
                              hipStream_t stream)
{
    const float* x     = (const float*)d_in[0];
    const float* z     = (const float*)d_in[1];
    const int*   esrc  = (const int*)d_in[2];
    const int*   edst  = (const int*)d_in[3];
    const float* elem  = (const float*)d_in[4];
    const float* eattr = (const float*)d_in[5];
    const float* Wsi0  = (const float*)d_in[6];
    const float* Wsi1  = (const float*)d_in[7];
    const float* Wl10  = (const float*)d_in[8];
    const float* Wl11  = (const float*)d_in[9];
    const float* Wl20  = (const float*)d_in[10];
    const float* Wl21  = (const float*)d_in[11];
    const float* tpw   = (const float*)d_in[12];
    float* out = (float*)d_out;

    const int N = in_sizes[1] / ZDIM;      // 50000
    const int E = in_sizes[2];             // 500000
    const int Ehalf = E / 2;               // 250000 (divisible by 16)

    // workspace carve-up (~226 MB, under the ~230 MB proven previously):
    f16_t* xls  = (f16_t*)d_ws;                          // N*64   f16
    f16_t* xlv  = xls + (size_t)N * 64;                  // 3N*64  f16
    float* aggs = (float*)(xlv + (size_t)3 * N * 64);    // N*64   f32
    float* aggv = aggs + (size_t)N * 64;                 // 3N*64  f32
    // region R: union of {Xs,Xv} (dead after fctp passes) and wbuf (per-chunk w)
    char*  R    = (char*)(aggv + (size_t)3 * N * 64);
    f16_t* Xs   = (f16_t*)R;                             // N*64   f16
    f16_t* Xv   = Xs + (size_t)N * 64;                   // 3N*64  f16
    f16_t* wbuf = (f16_t*)R;                             // Ehalf*256 f16 = 128 MB
    size_t Rbytes = (size_t)Ehalf * 256 * sizeof(f16_t);
    float* eattr_p = (float*)(R + Rbytes);               // E*4 f32
    int*   sperm   = (int*)(eattr_p + (size_t)E * 4);    // E
    int*   perm    = sperm + E;                          // E
    int*   cnt     = perm + E;                           // N
    int*   cursor  = cnt + N;                            // N
    int*   off     = cursor + N;                         // N+1
    int*   bsum    = off + (N + 1);                      // 64
    // z transposes, 256B-aligned for float4 loads: zt (10N) + ztv (30N) f32
    size_t zoff = (((size_t)(bsum + 64) - (size_t)d_ws) + 255) & ~(size_t)255;
    float* zt  = (float*)((char*)d_ws + zoff);           // 10N f32 (2 MB)
    float* ztv = zt + (size_t)10 * N;                    // 30N f32 (6 MB)

    const int SCAN_B = 1024;
    int nb = (N + SCAN_B - 1) / SCAN_B;  // 49 (<=64 required by scan_sums)

    hipMemsetAsync(cnt, 0, 2 * (size_t)N * sizeof(int), stream);       // cnt+cursor
    hipMemsetAsync(aggs, 0, (size_t)4 * N * 64 * sizeof(float), stream); // aggs+aggv

    int g0 = (N * MULT + 255) / 256;
    hipLaunchKernelGGL(transform_x2, dim3(g0), dim3(256), 0, stream, x, Xs, Xv, N);
    int gz = (N + 255) / 256;
    hipLaunchKernelGGL(zprep_kernel, dim3(gz), dim3(256), 0, stream, z, zt, ztv, N);

    // stageA split: two single-W passes at (256,2) -> B[20] fits, no spill
    hipLaunchKernelGGL(fctp_pass_xl, dim3(768), dim3(256), 0, stream,
                       Xs, Xv, zt, ztv, Wl10, Wl11, xls, xlv, N, 192);
    hipLaunchKernelGGL(fctp_pass_out, dim3(768), dim3(256), 0, stream,
                       Xs, Xv, zt, ztv, Wsi0, Wsi1, out, N, 192);

    int geh = (E + 255) / 256;
    hipLaunchKernelGGL(hist_kernel, dim3(geh), dim3(256), 0, stream,
                       edst, cnt, E);
    hipLaunchKernelGGL(scan_block, dim3(nb), dim3(SCAN_B), 0, stream,
                       cnt, off, bsum, N);
    hipLaunchKernelGGL(scan_sums, dim3(1), dim3(64), 0, stream, bsum, nb);
    hipLaunchKernelGGL(scan_add, dim3(nb), dim3(SCAN_B), 0, stream,
                       off, bsum, N);
    hipLaunchKernelGGL(scatter_kernel, dim3(geh), dim3(256), 0, stream,
                       edst, esrc, eattr, off, cursor, perm, sperm, eattr_p, E);

    // two node-aligned edge chunks: wgemm (w via MFMA) -> aggregate (+=)
    int wt = Ehalf / 16;                       // 15625 tiles per chunk
    int gw = (wt + 3) / 4;
    int ga = (N * 64 + 255) / 256;
    for (int c = 0; c < 2; ++c) {
        int lo = c * Ehalf, hi = lo + Ehalf;
        hipLaunchKernelGGL(wgemm_kernel, dim3(gw), dim3(256), 0, stream,
                           perm, elem, tpw, wbuf, lo, wt);
        hipLaunchKernelGGL(aggregate5, dim3(ga), dim3(256), 0, stream,
                           off, sperm, wbuf, eattr_p, xls, xlv,
                           aggs, aggv, N, lo, hi);
    }

    hipLaunchKernelGGL(fctp_stageC_mfma, dim3(768), dim3(256), 0, stream,
                       aggs, aggv, zt, ztv, Wl20, Wl21, out, N, 192);
}

// Round 4
// 632.095 us; speedup vs baseline: 1.2825x; 1.0232x over previous
//
#include <hip/hip_runtime.h>

// Problem constants (from reference)
#define MULT 64
#define FEATD 256
#define ZDIM 10

#define INV640f 0.03952847075210474f   // 1/sqrt(640)
#define ISQ2f   0.7071067811865476f    // 1/sqrt(2)
#define ISQ3f   0.5773502691896258f    // 1/sqrt(3)

typedef _Float16 f16_t;
typedef f16_t f16x8_t __attribute__((ext_vector_type(8)));
typedef f16_t f16x4_t __attribute__((ext_vector_type(4)));
typedef float f32x4_t __attribute__((ext_vector_type(4)));

// ---------------------------------------------------------------------------
// K0: transform x (n,256 natural: [x0(64) | x1(64,3)]) into f16 GEMM rows:
//   Xs[n*64 + u]        = x0[n,u]        (N x 64)
//   Xv[(3n+k)*64 + u]   = x1[n,u,k]      (3N x 64)
// ---------------------------------------------------------------------------
__global__ __launch_bounds__(256) void transform_x2(
    const float* __restrict__ x, f16_t* __restrict__ Xs,
    f16_t* __restrict__ Xv, int N)
{
    int idx = blockIdx.x * 256 + threadIdx.x;     // over N*64 (n,u) pairs
    if (idx >= N * MULT) return;
    int n = idx >> 6;
    int u = idx & 63;
    const float* row = x + (size_t)n * FEATD;
    Xs[idx] = (f16_t)row[u];
    const float* x1p = row + MULT + u * 3;
    Xv[((size_t)3 * n + 0) * MULT + u] = (f16_t)x1p[0];
    Xv[((size_t)3 * n + 1) * MULT + u] = (f16_t)x1p[1];
    Xv[((size_t)3 * n + 2) * MULT + u] = (f16_t)x1p[2];
}

// ---------------------------------------------------------------------------
// zprep: transpose z with INV640 folded in, in two layouts:
//   zt [v*N + n]   = z[n,v]*INV640       (for scalar-block GEMM rows, N rows)
//   ztv[v*3N + r]  = z[r/3,v]*INV640     (row-expanded for vector rows, 3N)
// ---------------------------------------------------------------------------
__global__ __launch_bounds__(256) void zprep_kernel(
    const float* __restrict__ z, float* __restrict__ zt,
    float* __restrict__ ztv, int N)
{
    int n = blockIdx.x * 256 + threadIdx.x;
    if (n >= N) return;
    const float* zr = z + (size_t)n * ZDIM;
#pragma unroll
    for (int v = 0; v < ZDIM; ++v) {
        float val = zr[v] * INV640f;
        zt[(size_t)v * N + n] = val;
        float* p = ztv + (size_t)v * 3 * N + 3 * (size_t)n;
        p[0] = val; p[1] = val; p[2] = val;
    }
}

// ---------------------------------------------------------------------------
// tpwprep: tpwt[c*32 + k] = tpw[k*256 + c] * scale(c), f16, where scale is
// ISQ2 for cols 0..191 (w1,w2,w3) and ISQ2*ISQ3 for cols 192..255 (w4).
// Makes wgemm's B-fragment preload 16 x 16B vector loads instead of 128
// scalar dword loads, and removes the epilogue scaling.
// ---------------------------------------------------------------------------
__global__ __launch_bounds__(256) void tpwprep_kernel(
    const float* __restrict__ tpw, f16_t* __restrict__ tpwt)
{
    int idx = blockIdx.x * 256 + threadIdx.x;    // 256*32 entries
    if (idx >= 256 * 32) return;
    int c = idx >> 5, k = idx & 31;
    float s = (c < 192) ? ISQ2f : (ISQ2f * ISQ3f);
    tpwt[(size_t)c * 32 + k] = (f16_t)(tpw[(size_t)k * 256 + c] * s);
}

// ---------------------------------------------------------------------------
// MFMA fctp kernels (f16). GEMM form: o[r,w] = sum_v z[r,v] * sum_u x[r,u]W[u,v,w].
// Per v: 2 MFMAs (K=64) with RAW x fragments (loop-invariant), then z folded
// into the f32 accumulator with 4 FMAs (zq float4 = z rows q*4..q*4+3).
// REGISTER BUDGET NOTE: B[20] = 80 regs (AGPR side of the unified file) plus
// ~90 VGPRs working set. __launch_bounds__(256,2) (256-reg budget) is REQUIRED:
// (256,4) caps at 128 and spills B to scratch (round-2 lesson: FETCH 55->416MB).
// PIPELINE NOTE: 2-deep manual rotation — next tile's A-rows are issued
// before this tile's MFMA block so HBM latency hides under compute
// (round-3 lesson: without it these kernels run at ~1 TB/s, 6x under BW).
// 16x16x32 layouts: A [m=lane&15][k=q*8+j], B [k=q*8+j][n=lane&15],
// C/D col=lane&15, row=q*4+reg  (m89/m91-verified).
// ---------------------------------------------------------------------------
__device__ __forceinline__ void preload_W(
    const float* __restrict__ W, int c0, int q, int mm, f16x8_t (&B)[20])
{
    const int col = c0 + mm;
#pragma unroll
    for (int ks = 0; ks < 20; ++ks) {
        const int v = ks >> 1;
        const int ub = ((ks & 1) << 5) + (q << 3);
        const int base = v * 64 + col;
#pragma unroll
        for (int j = 0; j < 8; ++j)
            B[ks][j] = (f16_t)W[(ub + j) * 640 + base];   // W[u][v][w]
    }
}

// pass 1: s = fctp(x, z, Wsi) staged into out (natural layout)
__global__ __launch_bounds__(256, 2) void fctp_pass_out(
    const f16_t* __restrict__ Xs, const f16_t* __restrict__ Xv,
    const float* __restrict__ zt, const float* __restrict__ ztv,
    const float* __restrict__ Wsi0, const float* __restrict__ Wsi1,
    float* __restrict__ out, int N, int nsc)
{
    const int lane = threadIdx.x & 63;
    const int wave = threadIdx.x >> 6;
    const int c0 = wave << 4;            // 16-col stripe per wave
    const int q = lane >> 4;
    const int mm = lane & 15;
    const bool sc = (int)blockIdx.x < nsc;
    const float* W = sc ? Wsi0 : Wsi1;
    const f16_t* Xsel = sc ? Xs : Xv;
    const float* ztb = sc ? zt : ztv;
    const size_t zsr = sc ? (size_t)N : (size_t)3 * N;
    const int ntiles = sc ? (N >> 4) : ((3 * N) >> 4);
    const int worker = sc ? (int)blockIdx.x : ((int)blockIdx.x - nsc);
    const int nworkers = sc ? nsc : 3 * nsc;

    f16x8_t B[20];
    preload_W(W, c0, q, mm, B);

    int tile = worker;
    if (tile >= ntiles) return;
    f16x8_t cxlo = *(const f16x8_t*)(Xsel + (((size_t)((tile << 4) + mm)) << 6) + (q << 3));
    f16x8_t cxhi = *(const f16x8_t*)(Xsel + (((size_t)((tile << 4) + mm)) << 6) + 32 + (q << 3));

    for (; tile < ntiles; tile += nworkers) {
        const int nt = tile + nworkers;
        f16x8_t nxlo = cxlo, nxhi = cxhi;
        if (nt < ntiles) {
            nxlo = *(const f16x8_t*)(Xsel + (((size_t)((nt << 4) + mm)) << 6) + (q << 3));
            nxhi = *(const f16x8_t*)(Xsel + (((size_t)((nt << 4) + mm)) << 6) + 32 + (q << 3));
        }
        const int rb4 = (tile << 4) + (q << 2);   // this lane's 4 C-rows

        f32x4_t acc = {0.f, 0.f, 0.f, 0.f};
#pragma unroll
        for (int v = 0; v < ZDIM; ++v) {
            f32x4_t t = {0.f, 0.f, 0.f, 0.f};
            t = __builtin_amdgcn_mfma_f32_16x16x32_f16(cxlo, B[2 * v], t, 0, 0, 0);
            t = __builtin_amdgcn_mfma_f32_16x16x32_f16(cxhi, B[2 * v + 1], t, 0, 0, 0);
            f32x4_t zq = *(const f32x4_t*)(ztb + (size_t)v * zsr + rb4);
#pragma unroll
            for (int reg = 0; reg < 4; ++reg)
                acc[reg] = fmaf(zq[reg], t[reg], acc[reg]);
        }

        const int w = c0 + mm;
#pragma unroll
        for (int reg = 0; reg < 4; ++reg) {
            const int ro = rb4 + reg;
            if (sc) {
                out[(size_t)ro * FEATD + w] = acc[reg];               // s, scalar part
            } else {
                const unsigned nn = (unsigned)ro / 3u;
                const int k = ro - 3 * (int)nn;
                out[(size_t)nn * FEATD + MULT + w * 3 + k] = acc[reg]; // s, vec part
            }
        }
        cxlo = nxlo; cxhi = nxhi;
    }
}

// pass 2: xl = fctp(x, z, Wl1) staged as f16 GEMM rows xls / xlv
__global__ __launch_bounds__(256, 2) void fctp_pass_xl(
    const f16_t* __restrict__ Xs, const f16_t* __restrict__ Xv,
    const float* __restrict__ zt, const float* __restrict__ ztv,
    const float* __restrict__ Wl10, const float* __restrict__ Wl11,
    f16_t* __restrict__ xls, f16_t* __restrict__ xlv, int N, int nsc)
{
    const int lane = threadIdx.x & 63;
    const int wave = threadIdx.x >> 6;
    const int c0 = wave << 4;
    const int q = lane >> 4;
    const int mm = lane & 15;
    const bool sc = (int)blockIdx.x < nsc;
    const float* W = sc ? Wl10 : Wl11;
    const f16_t* Xsel = sc ? Xs : Xv;
    const float* ztb = sc ? zt : ztv;
    const size_t zsr = sc ? (size_t)N : (size_t)3 * N;
    const int ntiles = sc ? (N >> 4) : ((3 * N) >> 4);
    const int worker = sc ? (int)blockIdx.x : ((int)blockIdx.x - nsc);
    const int nworkers = sc ? nsc : 3 * nsc;

    f16x8_t B[20];
    preload_W(W, c0, q, mm, B);

    f16_t* Osel = sc ? xls : xlv;

    int tile = worker;
    if (tile >= ntiles) return;
    f16x8_t cxlo = *(const f16x8_t*)(Xsel + (((size_t)((tile << 4) + mm)) << 6) + (q << 3));
    f16x8_t cxhi = *(const f16x8_t*)(Xsel + (((size_t)((tile << 4) + mm)) << 6) + 32 + (q << 3));

    for (; tile < ntiles; tile += nworkers) {
        const int nt = tile + nworkers;
        f16x8_t nxlo = cxlo, nxhi = cxhi;
        if (nt < ntiles) {
            nxlo = *(const f16x8_t*)(Xsel + (((size_t)((nt << 4) + mm)) << 6) + (q << 3));
            nxhi = *(const f16x8_t*)(Xsel + (((size_t)((nt << 4) + mm)) << 6) + 32 + (q << 3));
        }
        const int rb4 = (tile << 4) + (q << 2);

        f32x4_t acc = {0.f, 0.f, 0.f, 0.f};
#pragma unroll
        for (int v = 0; v < ZDIM; ++v) {
            f32x4_t t = {0.f, 0.f, 0.f, 0.f};
            t = __builtin_amdgcn_mfma_f32_16x16x32_f16(cxlo, B[2 * v], t, 0, 0, 0);
            t = __builtin_amdgcn_mfma_f32_16x16x32_f16(cxhi, B[2 * v + 1], t, 0, 0, 0);
            f32x4_t zq = *(const f32x4_t*)(ztb + (size_t)v * zsr + rb4);
#pragma unroll
            for (int reg = 0; reg < 4; ++reg)
                acc[reg] = fmaf(zq[reg], t[reg], acc[reg]);
        }

        const int w = c0 + mm;
#pragma unroll
        for (int reg = 0; reg < 4; ++reg) {
            const int ro = rb4 + reg;
            Osel[((size_t)ro << 6) + w] = (f16_t)acc[reg];
        }
        cxlo = nxlo; cxhi = nxhi;
    }
}

__global__ __launch_bounds__(256, 2) void fctp_stageC_mfma(
    const float* __restrict__ aggs, const float* __restrict__ aggv,
    const float* __restrict__ zt, const float* __restrict__ ztv,
    const float* __restrict__ Wl20, const float* __restrict__ Wl21,
    float* __restrict__ out, int N, int nsc)
{
    const int lane = threadIdx.x & 63;
    const int wave = threadIdx.x >> 6;
    const int c0 = wave << 4;
    const int q = lane >> 4;
    const int mm = lane & 15;
    const bool sc = (int)blockIdx.x < nsc;
    const float* W = sc ? Wl20 : Wl21;
    const float* Asel = sc ? aggs : aggv;
    const float* ztb = sc ? zt : ztv;
    const size_t zsr = sc ? (size_t)N : (size_t)3 * N;
    const int ntiles = sc ? (N >> 4) : ((3 * N) >> 4);
    const int worker = sc ? (int)blockIdx.x : ((int)blockIdx.x - nsc);
    const int nworkers = sc ? nsc : 3 * nsc;

    f16x8_t B[20];
    preload_W(W, c0, q, mm, B);

    int tile = worker;
    if (tile >= ntiles) return;
    float4 cl0, cl1, ch0, ch1;
    {
        const float* ap = Asel + (((size_t)((tile << 4) + mm)) << 6) + (q << 3);
        cl0 = *(const float4*)(ap);
        cl1 = *(const float4*)(ap + 4);
        ch0 = *(const float4*)(ap + 32);
        ch1 = *(const float4*)(ap + 36);
    }

    for (; tile < ntiles; tile += nworkers) {
        const int nt = tile + nworkers;
        float4 nl0 = cl0, nl1 = cl1, nh0 = ch0, nh1 = ch1;
        if (nt < ntiles) {
            const float* ap = Asel + (((size_t)((nt << 4) + mm)) << 6) + (q << 3);
            nl0 = *(const float4*)(ap);
            nl1 = *(const float4*)(ap + 4);
            nh0 = *(const float4*)(ap + 32);
            nh1 = *(const float4*)(ap + 36);
        }
        const int rb4 = (tile << 4) + (q << 2);
        const int w = c0 + mm;

        // hoist the out-RMW old-value loads ahead of the MFMA block
        size_t oidx[4];
        float oold[4];
#pragma unroll
        for (int reg = 0; reg < 4; ++reg) {
            const int ro = rb4 + reg;
            if (sc) {
                oidx[reg] = (size_t)ro * FEATD + w;
            } else {
                const unsigned nn = (unsigned)ro / 3u;
                const int k = ro - 3 * (int)nn;
                oidx[reg] = (size_t)nn * FEATD + MULT + w * 3 + k;
            }
            oold[reg] = out[oidx[reg]];
        }

        f16x8_t xlo, xhi;
        xlo[0] = (f16_t)cl0.x; xlo[1] = (f16_t)cl0.y; xlo[2] = (f16_t)cl0.z; xlo[3] = (f16_t)cl0.w;
        xlo[4] = (f16_t)cl1.x; xlo[5] = (f16_t)cl1.y; xlo[6] = (f16_t)cl1.z; xlo[7] = (f16_t)cl1.w;
        xhi[0] = (f16_t)ch0.x; xhi[1] = (f16_t)ch0.y; xhi[2] = (f16_t)ch0.z; xhi[3] = (f16_t)ch0.w;
        xhi[4] = (f16_t)ch1.x; xhi[5] = (f16_t)ch1.y; xhi[6] = (f16_t)ch1.z; xhi[7] = (f16_t)ch1.w;

        f32x4_t acc = {0.f, 0.f, 0.f, 0.f};
#pragma unroll
        for (int v = 0; v < ZDIM; ++v) {
            f32x4_t t = {0.f, 0.f, 0.f, 0.f};
            t = __builtin_amdgcn_mfma_f32_16x16x32_f16(xlo, B[2 * v], t, 0, 0, 0);
            t = __builtin_amdgcn_mfma_f32_16x16x32_f16(xhi, B[2 * v + 1], t, 0, 0, 0);
            f32x4_t zq = *(const f32x4_t*)(ztb + (size_t)v * zsr + rb4);
#pragma unroll
            for (int reg = 0; reg < 4; ++reg)
                acc[reg] = fmaf(zq[reg], t[reg], acc[reg]);
        }

#pragma unroll
        for (int reg = 0; reg < 4; ++reg)
            out[oidx[reg]] = oold[reg] + acc[reg] * 0.1f;   // s staged by pass_out; /10 here

        cl0 = nl0; cl1 = nl1; ch0 = nh0; ch1 = nh1;
    }
}

// ---------------------------------------------------------------------------
// Counting sort of edges by dst (unchanged). scatter emits perm, sperm
// (permuted src) and eattr_p (permuted edge_attr).
// ---------------------------------------------------------------------------
__global__ __launch_bounds__(256) void hist_kernel(
    const int* __restrict__ edst, int* __restrict__ cnt, int E)
{
    int e = blockIdx.x * 256 + threadIdx.x;
    if (e >= E) return;
    atomicAdd(&cnt[edst[e]], 1);
}

__global__ __launch_bounds__(1024) void scan_block(
    const int* __restrict__ cnt, int* __restrict__ off,
    int* __restrict__ bsum, int N)
{
    __shared__ int sh[1024];
    int tid = threadIdx.x;
    int i = blockIdx.x * 1024 + tid;
    int v = (i < N) ? cnt[i] : 0;
    sh[tid] = v;
    __syncthreads();
#pragma unroll
    for (int d = 1; d < 1024; d <<= 1) {
        int t = (tid >= d) ? sh[tid - d] : 0;
        __syncthreads();
        sh[tid] += t;
        __syncthreads();
    }
    if (i < N) off[i + 1] = sh[tid];
    if (tid == 1023) bsum[blockIdx.x] = sh[1023];
    if (i == 0) off[0] = 0;
}

__global__ __launch_bounds__(64) void scan_sums(int* __restrict__ bsum, int nb)
{
    int tid = threadIdx.x;
    int v = (tid < nb) ? bsum[tid] : 0;
#pragma unroll
    for (int d = 1; d < 64; d <<= 1) {
        int t = __shfl_up(v, d, 64);
        if (tid >= d) v += t;
    }
    int ex = __shfl_up(v, 1, 64);
    if (tid == 0) ex = 0;
    if (tid < nb) bsum[tid] = ex;
}

__global__ __launch_bounds__(1024) void scan_add(
    int* __restrict__ off, const int* __restrict__ bsum, int N)
{
    int i = blockIdx.x * 1024 + threadIdx.x;
    if (i < N) off[i + 1] += bsum[blockIdx.x];
}

__global__ __launch_bounds__(256) void scatter_kernel(
    const int* __restrict__ edst, const int* __restrict__ esrc,
    const float* __restrict__ eattr, const int* __restrict__ off,
    int* __restrict__ cursor, int* __restrict__ perm,
    int* __restrict__ sperm, float* __restrict__ eattr_p, int E)
{
    int e = blockIdx.x * 256 + threadIdx.x;
    if (e >= E) return;
    int d = edst[e];
    int pos = off[d] + atomicAdd(&cursor[d], 1);
    perm[pos] = e;
    sperm[pos] = esrc[e];
    float4 at = *(const float4*)(eattr + (size_t)e * 4);
    *(float4*)(eattr_p + (size_t)pos * 4) = at;
}

// ---------------------------------------------------------------------------
// wgemm: w = elem[perm[pos]] @ tpwt via MFMA, for positions [lo, lo+16*ntiles).
// One wave per 16-edge tile per iteration, persistent B-frags (tpwt f16,
// scales baked in), grid-stride tile loop with depth-2 elem prefetch.
// wbuf[(pos-lo)*64 + u][0..3] = w1',w2',w3',w4'.
// ---------------------------------------------------------------------------
__global__ __launch_bounds__(256, 2) void wgemm_kernel(
    const int* __restrict__ perm, const float* __restrict__ elem,
    const f16_t* __restrict__ tpwt, f16_t* __restrict__ wbuf,
    int lo, int ntiles)
{
    const int lane = threadIdx.x & 63;
    const int mm = lane & 15, q = lane >> 4;
    int tile = blockIdx.x * 4 + (threadIdx.x >> 6);
    const int nw = gridDim.x * 4;

    // B-frags: stripe s covers cols s*16 + mm, k = q*8+j  (16 x 16B loads)
    f16x8_t B[16];
#pragma unroll
    for (int s = 0; s < 16; ++s)
        B[s] = *(const f16x8_t*)(tpwt + ((size_t)(s * 16 + mm)) * 32 + q * 8);

    if (tile >= ntiles) return;
    float4 ca, cb;
    {
        int e = perm[lo + (tile << 4) + mm];
        const float* er = elem + ((size_t)e << 5) + q * 8;
        ca = *(const float4*)er;
        cb = *(const float4*)(er + 4);
    }

    for (; tile < ntiles; tile += nw) {
        const int nt = tile + nw;
        float4 na = ca, nb = cb;
        if (nt < ntiles) {
            int e = perm[lo + (nt << 4) + mm];
            const float* er = elem + ((size_t)e << 5) + q * 8;
            na = *(const float4*)er;
            nb = *(const float4*)(er + 4);
        }

        f16x8_t A;
        A[0] = (f16_t)ca.x; A[1] = (f16_t)ca.y; A[2] = (f16_t)ca.z; A[3] = (f16_t)ca.w;
        A[4] = (f16_t)cb.x; A[5] = (f16_t)cb.y; A[6] = (f16_t)cb.z; A[7] = (f16_t)cb.w;

        f32x4_t D[16];
#pragma unroll
        for (int s = 0; s < 16; ++s) {
            f32x4_t zer = {0.f, 0.f, 0.f, 0.f};
            D[s] = __builtin_amdgcn_mfma_f32_16x16x32_f16(A, B[s], zer, 0, 0, 0);
        }

        // store: D col = s*16+mm -> u = (s&3)*16+mm; row = q*4+reg
#pragma unroll
        for (int reg = 0; reg < 4; ++reg) {
            const int row = q * 4 + reg;
            const size_t base = ((size_t)((tile << 4) + row)) << 6;   // row in wbuf
#pragma unroll
            for (int t = 0; t < 4; ++t) {
                const int u = t * 16 + mm;
                f16x4_t wq;
                wq[0] = (f16_t)D[0 * 4 + t][reg];
                wq[1] = (f16_t)D[1 * 4 + t][reg];
                wq[2] = (f16_t)D[2 * 4 + t][reg];
                wq[3] = (f16_t)D[3 * 4 + t][reg];
                *(f16x4_t*)(wbuf + ((base + u) << 2)) = wq;
            }
        }
        ca = na; cb = nb;
    }
}

// ---------------------------------------------------------------------------
// aggregate5: 1 wave per node, chunked over edge positions [lo, hi).
// Per edge: 8B w-load (coalesced), f16 gathers of xl[src], ~14-FMA TP,
// += into aggs/aggv (zero-initialized; same wave owns node in both chunks).
// ---------------------------------------------------------------------------
__device__ __forceinline__ void agg_edge5(
    float xs, float v0, float v1, float v2, int i, int lo,
    const f16_t* __restrict__ wbuf, const float* __restrict__ eattr_p, int u,
    float& accx, float& accy, float& accz, float& accw)
{
    f16x4_t wq = *(const f16x4_t*)(wbuf + ((((size_t)(i - lo)) << 6) + u) * 4);
    float w1 = (float)wq[0], w2 = (float)wq[1], w3 = (float)wq[2], w4 = (float)wq[3];
    float4 at = *(const float4*)(eattr_p + ((size_t)i << 2));
    float dot3 = v0 * at.y + v1 * at.z + v2 * at.w;
    accx = fmaf(w1 * xs, at.x, accx);
    accx = fmaf(w4, dot3, accx);
    float w2x = w2 * xs;
    accy = fmaf(w2x, at.y, accy);
    accz = fmaf(w2x, at.z, accz);
    accw = fmaf(w2x, at.w, accw);
    float w3s = w3 * at.x;
    accy = fmaf(w3s, v0, accy);
    accz = fmaf(w3s, v1, accz);
    accw = fmaf(w3s, v2, accw);
}

__global__ __launch_bounds__(256, 8) void aggregate5(
    const int* __restrict__ off, const int* __restrict__ sperm,
    const f16_t* __restrict__ wbuf, const float* __restrict__ eattr_p,
    const f16_t* __restrict__ xls, const f16_t* __restrict__ xlv,
    float* __restrict__ aggs, float* __restrict__ aggv,
    int N, int lo, int hi)
{
    int n = (blockIdx.x * 256 + threadIdx.x) >> 6;      // one wave per node
    if (n >= N) return;
    int u = threadIdx.x & 63;

    int s0 = __builtin_amdgcn_readfirstlane(off[n]);
    int s1 = __builtin_amdgcn_readfirstlane(off[n + 1]);
    int cs0 = s0 > lo ? s0 : lo;
    int cs1 = s1 < hi ? s1 : hi;
    if (cs0 >= cs1) return;

    float accx = 0.f, accy = 0.f, accz = 0.f, accw = 0.f;
    const int last = cs1 - 1;

    // depth-2 prefetch slots for the xl gather (the HBM-latency item)
    int sa = __builtin_amdgcn_readfirstlane(sperm[cs0]);
    float a_xs = (float)xls[((size_t)sa << 6) + u];
    float a_v0 = (float)xlv[((size_t)(3 * sa + 0) << 6) + u];
    float a_v1 = (float)xlv[((size_t)(3 * sa + 1) << 6) + u];
    float a_v2 = (float)xlv[((size_t)(3 * sa + 2) << 6) + u];
    int ib = (cs0 + 1 <= last) ? cs0 + 1 : last;
    int sb = __builtin_amdgcn_readfirstlane(sperm[ib]);
    float b_xs = (float)xls[((size_t)sb << 6) + u];
    float b_v0 = (float)xlv[((size_t)(3 * sb + 0) << 6) + u];
    float b_v1 = (float)xlv[((size_t)(3 * sb + 1) << 6) + u];
    float b_v2 = (float)xlv[((size_t)(3 * sb + 2) << 6) + u];

    int i = cs0;
    while (true) {
        agg_edge5(a_xs, a_v0, a_v1, a_v2, i, lo, wbuf, eattr_p, u,
                  accx, accy, accz, accw);
        {
            int inx = (i + 2 <= last) ? i + 2 : last;
            int sn = __builtin_amdgcn_readfirstlane(sperm[inx]);
            a_xs = (float)xls[((size_t)sn << 6) + u];
            a_v0 = (float)xlv[((size_t)(3 * sn + 0) << 6) + u];
            a_v1 = (float)xlv[((size_t)(3 * sn + 1) << 6) + u];
            a_v2 = (float)xlv[((size_t)(3 * sn + 2) << 6) + u];
        }
        if (++i > last) break;
        agg_edge5(b_xs, b_v0, b_v1, b_v2, i, lo, wbuf, eattr_p, u,
                  accx, accy, accz, accw);
        {
            int inx = (i + 2 <= last) ? i + 2 : last;
            int sn = __builtin_amdgcn_readfirstlane(sperm[inx]);
            b_xs = (float)xls[((size_t)sn << 6) + u];
            b_v0 = (float)xlv[((size_t)(3 * sn + 0) << 6) + u];
            b_v1 = (float)xlv[((size_t)(3 * sn + 1) << 6) + u];
            b_v2 = (float)xlv[((size_t)(3 * sn + 2) << 6) + u];
        }
        if (++i > last) break;
    }

    aggs[((size_t)n << 6) + u] += accx;
    aggv[((size_t)(3 * n + 0) << 6) + u] += accy;
    aggv[((size_t)(3 * n + 1) << 6) + u] += accz;
    aggv[((size_t)(3 * n + 2) << 6) + u] += accw;
}

// ---------------------------------------------------------------------------
extern "C" void kernel_launch(void* const* d_in, const int* in_sizes, int n_in,
                              void* d_out, int out_size, void* d_ws, size_t ws_size,
                              hipStream_t stream)
{
    const float* x     = (const float*)d_in[0];
    const float* z     = (const float*)d_in[1];
    const int*   esrc  = (const int*)d_in[2];
    const int*   edst  = (const int*)d_in[3];
    const float* elem  = (const float*)d_in[4];
    const float* eattr = (const float*)d_in[5];
    const float* Wsi0  = (const float*)d_in[6];
    const float* Wsi1  = (const float*)d_in[7];
    const float* Wl10  = (const float*)d_in[8];
    const float* Wl11  = (const float*)d_in[9];
    const float* Wl20  = (const float*)d_in[10];
    const float* Wl21  = (const float*)d_in[11];
    const float* tpw   = (const float*)d_in[12];
    float* out = (float*)d_out;

    const int N = in_sizes[1] / ZDIM;      // 50000
    const int E = in_sizes[2];             // 500000
    const int Ehalf = E / 2;               // 250000 (divisible by 16)

    // workspace carve-up (~226 MB, under the ~230 MB proven previously):
    f16_t* xls  = (f16_t*)d_ws;                          // N*64   f16
    f16_t* xlv  = xls + (size_t)N * 64;                  // 3N*64  f16
    float* aggs = (float*)(xlv + (size_t)3 * N * 64);    // N*64   f32
    float* aggv = aggs + (size_t)N * 64;                 // 3N*64  f32
    // region R: union of {Xs,Xv} (dead after fctp passes) and wbuf (per-chunk w)
    char*  R    = (char*)(aggv + (size_t)3 * N * 64);
    f16_t* Xs   = (f16_t*)R;                             // N*64   f16
    f16_t* Xv   = Xs + (size_t)N * 64;                   // 3N*64  f16
    f16_t* wbuf = (f16_t*)R;                             // Ehalf*256 f16 = 128 MB
    size_t Rbytes = (size_t)Ehalf * 256 * sizeof(f16_t);
    float* eattr_p = (float*)(R + Rbytes);               // E*4 f32
    int*   sperm   = (int*)(eattr_p + (size_t)E * 4);    // E
    int*   perm    = sperm + E;                          // E
    int*   cnt     = perm + E;                           // N
    int*   cursor  = cnt + N;                            // N
    int*   off     = cursor + N;                         // N+1
    int*   bsum    = off + (N + 1);                      // 64
    // z transposes, 256B-aligned for float4 loads: zt (10N) + ztv (30N) f32
    size_t zoff = (((size_t)(bsum + 64) - (size_t)d_ws) + 255) & ~(size_t)255;
    float* zt  = (float*)((char*)d_ws + zoff);           // 10N f32 (2 MB)
    float* ztv = zt + (size_t)10 * N;                    // 30N f32 (6 MB)
    f16_t* tpwt = (f16_t*)(ztv + (size_t)30 * N);        // 256*32 f16 (16 KB)

    const int SCAN_B = 1024;
    int nb = (N + SCAN_B - 1) / SCAN_B;  // 49 (<=64 required by scan_sums)

    hipMemsetAsync(cnt, 0, 2 * (size_t)N * sizeof(int), stream);       // cnt+cursor
    hipMemsetAsync(aggs, 0, (size_t)4 * N * 64 * sizeof(float), stream); // aggs+aggv

    int g0 = (N * MULT + 255) / 256;
    hipLaunchKernelGGL(transform_x2, dim3(g0), dim3(256), 0, stream, x, Xs, Xv, N);
    int gz = (N + 255) / 256;
    hipLaunchKernelGGL(zprep_kernel, dim3(gz), dim3(256), 0, stream, z, zt, ztv, N);
    hipLaunchKernelGGL(tpwprep_kernel, dim3(32), dim3(256), 0, stream, tpw, tpwt);

    // stageA split: two single-W passes at (256,2) -> B[20] fits, no spill
    hipLaunchKernelGGL(fctp_pass_xl, dim3(512), dim3(256), 0, stream,
                       Xs, Xv, zt, ztv, Wl10, Wl11, xls, xlv, N, 128);
    hipLaunchKernelGGL(fctp_pass_out, dim3(512), dim3(256), 0, stream,
                       Xs, Xv, zt, ztv, Wsi0, Wsi1, out, N, 128);

    int geh = (E + 255) / 256;
    hipLaunchKernelGGL(hist_kernel, dim3(geh), dim3(256), 0, stream,
                       edst, cnt, E);
    hipLaunchKernelGGL(scan_block, dim3(nb), dim3(SCAN_B), 0, stream,
                       cnt, off, bsum, N);
    hipLaunchKernelGGL(scan_sums, dim3(1), dim3(64), 0, stream, bsum, nb);
    hipLaunchKernelGGL(scan_add, dim3(nb), dim3(SCAN_B), 0, stream,
                       off, bsum, N);
    hipLaunchKernelGGL(scatter_kernel, dim3(geh), dim3(256), 0, stream,
                       edst, esrc, eattr, off, cursor, perm, sperm, eattr_p, E);

    // two node-aligned edge chunks: wgemm (w via MFMA) -> aggregate (+=)
    int wt = Ehalf / 16;                       // 15625 tiles per chunk
    int ga = (N * 64 + 255) / 256;
    for (int c = 0; c < 2; ++c) {
        int lo = c * Ehalf, hi = lo + Ehalf;
        hipLaunchKernelGGL(wgemm_kernel, dim3(512), dim3(256), 0, stream,
                           perm, elem, tpwt, wbuf, lo, wt);
        hipLaunchKernelGGL(aggregate5, dim3(ga), dim3(256), 0, stream,
                           off, sperm, wbuf, eattr_p, xls, xlv,
                           aggs, aggv, N, lo, hi);
    }

    hipLaunchKernelGGL(fctp_stageC_mfma, dim3(512), dim3(256), 0, stream,
                       aggs, aggv, zt, ztv, Wl20, Wl21, out, N, 128);
}

// Round 5
// 582.497 us; speedup vs baseline: 1.3917x; 1.0851x over previous
//
#include <hip/hip_runtime.h>

// Problem constants (from reference)
#define MULT 64
#define FEATD 256
#define ZDIM 10

#define INV640f 0.03952847075210474f   // 1/sqrt(640)
#define ISQ2f   0.7071067811865476f    // 1/sqrt(2)
#define ISQ3f   0.5773502691896258f    // 1/sqrt(3)

typedef _Float16 f16_t;
typedef f16_t f16x8_t __attribute__((ext_vector_type(8)));
typedef f16_t f16x4_t __attribute__((ext_vector_type(4)));
typedef float f32x4_t __attribute__((ext_vector_type(4)));

// ---------------------------------------------------------------------------
// K0: transform x (n,256 natural: [x0(64) | x1(64,3)]) into f16 GEMM rows:
//   Xs[n*64 + u]        = x0[n,u]        (N x 64)
//   Xv[(3n+k)*64 + u]   = x1[n,u,k]      (3N x 64)
// ---------------------------------------------------------------------------
__global__ __launch_bounds__(256) void transform_x2(
    const float* __restrict__ x, f16_t* __restrict__ Xs,
    f16_t* __restrict__ Xv, int N)
{
    int idx = blockIdx.x * 256 + threadIdx.x;     // over N*64 (n,u) pairs
    if (idx >= N * MULT) return;
    int n = idx >> 6;
    int u = idx & 63;
    const float* row = x + (size_t)n * FEATD;
    Xs[idx] = (f16_t)row[u];
    const float* x1p = row + MULT + u * 3;
    Xv[((size_t)3 * n + 0) * MULT + u] = (f16_t)x1p[0];
    Xv[((size_t)3 * n + 1) * MULT + u] = (f16_t)x1p[1];
    Xv[((size_t)3 * n + 2) * MULT + u] = (f16_t)x1p[2];
}

// ---------------------------------------------------------------------------
// zprep: transpose z with INV640 folded in, in two layouts:
//   zt [v*N + n]   = z[n,v]*INV640       (for scalar-block GEMM rows, N rows)
//   ztv[v*3N + r]  = z[r/3,v]*INV640     (row-expanded for vector rows, 3N)
// ---------------------------------------------------------------------------
__global__ __launch_bounds__(256) void zprep_kernel(
    const float* __restrict__ z, float* __restrict__ zt,
    float* __restrict__ ztv, int N)
{
    int n = blockIdx.x * 256 + threadIdx.x;
    if (n >= N) return;
    const float* zr = z + (size_t)n * ZDIM;
#pragma unroll
    for (int v = 0; v < ZDIM; ++v) {
        float val = zr[v] * INV640f;
        zt[(size_t)v * N + n] = val;
        float* p = ztv + (size_t)v * 3 * N + 3 * (size_t)n;
        p[0] = val; p[1] = val; p[2] = val;
    }
}

// ---------------------------------------------------------------------------
// tpwprep: tpwt[c*32 + k] = tpw[k*256 + c] * scale(c), f16  (scales baked in)
// ---------------------------------------------------------------------------
__global__ __launch_bounds__(256) void tpwprep_kernel(
    const float* __restrict__ tpw, f16_t* __restrict__ tpwt)
{
    int idx = blockIdx.x * 256 + threadIdx.x;    // 256*32 entries
    if (idx >= 256 * 32) return;
    int c = idx >> 5, k = idx & 31;
    float s = (c < 192) ? ISQ2f : (ISQ2f * ISQ3f);
    tpwt[(size_t)c * 32 + k] = (f16_t)(tpw[(size_t)k * 256 + c] * s);
}

// ---------------------------------------------------------------------------
// MFMA fctp kernels (f16). GEMM form: o[r,w] = sum_v z[r,v] * sum_u x[r,u]W[u,v,w].
// Per v: 2 MFMAs (K=64) with RAW x fragments, z folded on f32 accumulators.
// REGISTER BUDGET: B[20]=80 AGPR-side regs; (256,2) REQUIRED (round-2: (256,4)
// caps at 128 and spills B, FETCH 55->416MB).
// LOAD-BATCHING (round-4 lesson): all rounds pinned at ~1 TB/s = ~1 load in
// flight per wave. Each iteration now issues ALL its loads up front —
// A-rows(t+1), zqa[10] (explicit array, full unroll), out-old — before the
// register-only MFMA block, so one latency burst covers the iteration.
// 16x16x32 layouts: A [m=lane&15][k=q*8+j], B [k=q*8+j][n=lane&15],
// C/D col=lane&15, row=q*4+reg  (m89/m91-verified).
// ---------------------------------------------------------------------------
__device__ __forceinline__ void preload_W(
    const float* __restrict__ W, int c0, int q, int mm, f16x8_t (&B)[20])
{
    const int col = c0 + mm;
#pragma unroll
    for (int ks = 0; ks < 20; ++ks) {
        const int v = ks >> 1;
        const int ub = ((ks & 1) << 5) + (q << 3);
        const int base = v * 64 + col;
#pragma unroll
        for (int j = 0; j < 8; ++j)
            B[ks][j] = (f16_t)W[(ub + j) * 640 + base];   // W[u][v][w]
    }
}

// pass 1: s = fctp(x, z, Wsi) staged into out (natural layout)
__global__ __launch_bounds__(256, 2) void fctp_pass_out(
    const f16_t* __restrict__ Xs, const f16_t* __restrict__ Xv,
    const float* __restrict__ zt, const float* __restrict__ ztv,
    const float* __restrict__ Wsi0, const float* __restrict__ Wsi1,
    float* __restrict__ out, int N, int nsc)
{
    const int lane = threadIdx.x & 63;
    const int wave = threadIdx.x >> 6;
    const int c0 = wave << 4;            // 16-col stripe per wave
    const int q = lane >> 4;
    const int mm = lane & 15;
    const bool sc = (int)blockIdx.x < nsc;
    const float* W = sc ? Wsi0 : Wsi1;
    const f16_t* Xsel = sc ? Xs : Xv;
    const float* ztb = sc ? zt : ztv;
    const size_t zsr = sc ? (size_t)N : (size_t)3 * N;
    const int ntiles = sc ? (N >> 4) : ((3 * N) >> 4);
    const int worker = sc ? (int)blockIdx.x : ((int)blockIdx.x - nsc);
    const int nworkers = sc ? nsc : 3 * nsc;

    f16x8_t B[20];
    preload_W(W, c0, q, mm, B);

    int tile = worker;
    if (tile >= ntiles) return;
    f16x8_t cxlo = *(const f16x8_t*)(Xsel + (((size_t)((tile << 4) + mm)) << 6) + (q << 3));
    f16x8_t cxhi = *(const f16x8_t*)(Xsel + (((size_t)((tile << 4) + mm)) << 6) + 32 + (q << 3));

    for (; tile < ntiles; tile += nworkers) {
        // ---- phase 1: issue ALL loads for this iteration ----
        const int nt = tile + nworkers;
        f16x8_t nxlo = cxlo, nxhi = cxhi;
        if (nt < ntiles) {
            nxlo = *(const f16x8_t*)(Xsel + (((size_t)((nt << 4) + mm)) << 6) + (q << 3));
            nxhi = *(const f16x8_t*)(Xsel + (((size_t)((nt << 4) + mm)) << 6) + 32 + (q << 3));
        }
        const int rb4 = (tile << 4) + (q << 2);   // this lane's 4 C-rows
        f32x4_t zqa[ZDIM];
#pragma unroll
        for (int v = 0; v < ZDIM; ++v)
            zqa[v] = *(const f32x4_t*)(ztb + (size_t)v * zsr + rb4);

        // ---- phase 2: register-only compute ----
        f32x4_t acc = {0.f, 0.f, 0.f, 0.f};
#pragma unroll
        for (int v = 0; v < ZDIM; ++v) {
            f32x4_t t = {0.f, 0.f, 0.f, 0.f};
            t = __builtin_amdgcn_mfma_f32_16x16x32_f16(cxlo, B[2 * v], t, 0, 0, 0);
            t = __builtin_amdgcn_mfma_f32_16x16x32_f16(cxhi, B[2 * v + 1], t, 0, 0, 0);
#pragma unroll
            for (int reg = 0; reg < 4; ++reg)
                acc[reg] = fmaf(zqa[v][reg], t[reg], acc[reg]);
        }

        // ---- phase 3: stores ----
        const int w = c0 + mm;
#pragma unroll
        for (int reg = 0; reg < 4; ++reg) {
            const int ro = rb4 + reg;
            if (sc) {
                out[(size_t)ro * FEATD + w] = acc[reg];               // s, scalar part
            } else {
                const unsigned nn = (unsigned)ro / 3u;
                const int k = ro - 3 * (int)nn;
                out[(size_t)nn * FEATD + MULT + w * 3 + k] = acc[reg]; // s, vec part
            }
        }
        cxlo = nxlo; cxhi = nxhi;
    }
}

// pass 2: xl = fctp(x, z, Wl1) staged as f16 GEMM rows xls / xlv
__global__ __launch_bounds__(256, 2) void fctp_pass_xl(
    const f16_t* __restrict__ Xs, const f16_t* __restrict__ Xv,
    const float* __restrict__ zt, const float* __restrict__ ztv,
    const float* __restrict__ Wl10, const float* __restrict__ Wl11,
    f16_t* __restrict__ xls, f16_t* __restrict__ xlv, int N, int nsc)
{
    const int lane = threadIdx.x & 63;
    const int wave = threadIdx.x >> 6;
    const int c0 = wave << 4;
    const int q = lane >> 4;
    const int mm = lane & 15;
    const bool sc = (int)blockIdx.x < nsc;
    const float* W = sc ? Wl10 : Wl11;
    const f16_t* Xsel = sc ? Xs : Xv;
    const float* ztb = sc ? zt : ztv;
    const size_t zsr = sc ? (size_t)N : (size_t)3 * N;
    const int ntiles = sc ? (N >> 4) : ((3 * N) >> 4);
    const int worker = sc ? (int)blockIdx.x : ((int)blockIdx.x - nsc);
    const int nworkers = sc ? nsc : 3 * nsc;

    f16x8_t B[20];
    preload_W(W, c0, q, mm, B);

    f16_t* Osel = sc ? xls : xlv;

    int tile = worker;
    if (tile >= ntiles) return;
    f16x8_t cxlo = *(const f16x8_t*)(Xsel + (((size_t)((tile << 4) + mm)) << 6) + (q << 3));
    f16x8_t cxhi = *(const f16x8_t*)(Xsel + (((size_t)((tile << 4) + mm)) << 6) + 32 + (q << 3));

    for (; tile < ntiles; tile += nworkers) {
        // ---- phase 1: issue ALL loads ----
        const int nt = tile + nworkers;
        f16x8_t nxlo = cxlo, nxhi = cxhi;
        if (nt < ntiles) {
            nxlo = *(const f16x8_t*)(Xsel + (((size_t)((nt << 4) + mm)) << 6) + (q << 3));
            nxhi = *(const f16x8_t*)(Xsel + (((size_t)((nt << 4) + mm)) << 6) + 32 + (q << 3));
        }
        const int rb4 = (tile << 4) + (q << 2);
        f32x4_t zqa[ZDIM];
#pragma unroll
        for (int v = 0; v < ZDIM; ++v)
            zqa[v] = *(const f32x4_t*)(ztb + (size_t)v * zsr + rb4);

        // ---- phase 2: register-only compute ----
        f32x4_t acc = {0.f, 0.f, 0.f, 0.f};
#pragma unroll
        for (int v = 0; v < ZDIM; ++v) {
            f32x4_t t = {0.f, 0.f, 0.f, 0.f};
            t = __builtin_amdgcn_mfma_f32_16x16x32_f16(cxlo, B[2 * v], t, 0, 0, 0);
            t = __builtin_amdgcn_mfma_f32_16x16x32_f16(cxhi, B[2 * v + 1], t, 0, 0, 0);
#pragma unroll
            for (int reg = 0; reg < 4; ++reg)
                acc[reg] = fmaf(zqa[v][reg], t[reg], acc[reg]);
        }

        // ---- phase 3: stores ----
        const int w = c0 + mm;
#pragma unroll
        for (int reg = 0; reg < 4; ++reg) {
            const int ro = rb4 + reg;
            Osel[((size_t)ro << 6) + w] = (f16_t)acc[reg];
        }
        cxlo = nxlo; cxhi = nxhi;
    }
}

__global__ __launch_bounds__(256, 2) void fctp_stageC_mfma(
    const float* __restrict__ aggs, const float* __restrict__ aggv,
    const float* __restrict__ zt, const float* __restrict__ ztv,
    const float* __restrict__ Wl20, const float* __restrict__ Wl21,
    float* __restrict__ out, int N, int nsc)
{
    const int lane = threadIdx.x & 63;
    const int wave = threadIdx.x >> 6;
    const int c0 = wave << 4;
    const int q = lane >> 4;
    const int mm = lane & 15;
    const bool sc = (int)blockIdx.x < nsc;
    const float* W = sc ? Wl20 : Wl21;
    const float* Asel = sc ? aggs : aggv;
    const float* ztb = sc ? zt : ztv;
    const size_t zsr = sc ? (size_t)N : (size_t)3 * N;
    const int ntiles = sc ? (N >> 4) : ((3 * N) >> 4);
    const int worker = sc ? (int)blockIdx.x : ((int)blockIdx.x - nsc);
    const int nworkers = sc ? nsc : 3 * nsc;

    f16x8_t B[20];
    preload_W(W, c0, q, mm, B);

    int tile = worker;
    if (tile >= ntiles) return;
    float4 cl0, cl1, ch0, ch1;
    {
        const float* ap = Asel + (((size_t)((tile << 4) + mm)) << 6) + (q << 3);
        cl0 = *(const float4*)(ap);
        cl1 = *(const float4*)(ap + 4);
        ch0 = *(const float4*)(ap + 32);
        ch1 = *(const float4*)(ap + 36);
    }

    for (; tile < ntiles; tile += nworkers) {
        // ---- phase 1: issue ALL loads for this iteration ----
        const int nt = tile + nworkers;
        float4 nl0 = cl0, nl1 = cl1, nh0 = ch0, nh1 = ch1;
        if (nt < ntiles) {
            const float* ap = Asel + (((size_t)((nt << 4) + mm)) << 6) + (q << 3);
            nl0 = *(const float4*)(ap);
            nl1 = *(const float4*)(ap + 4);
            nh0 = *(const float4*)(ap + 32);
            nh1 = *(const float4*)(ap + 36);
        }
        const int rb4 = (tile << 4) + (q << 2);
        const int w = c0 + mm;

        f32x4_t zqa[ZDIM];
#pragma unroll
        for (int v = 0; v < ZDIM; ++v)
            zqa[v] = *(const f32x4_t*)(ztb + (size_t)v * zsr + rb4);

        size_t oidx[4];
        float oold[4];
#pragma unroll
        for (int reg = 0; reg < 4; ++reg) {
            const int ro = rb4 + reg;
            if (sc) {
                oidx[reg] = (size_t)ro * FEATD + w;
            } else {
                const unsigned nn = (unsigned)ro / 3u;
                const int k = ro - 3 * (int)nn;
                oidx[reg] = (size_t)nn * FEATD + MULT + w * 3 + k;
            }
            oold[reg] = out[oidx[reg]];
        }

        // ---- phase 2: register-only compute ----
        f16x8_t xlo, xhi;
        xlo[0] = (f16_t)cl0.x; xlo[1] = (f16_t)cl0.y; xlo[2] = (f16_t)cl0.z; xlo[3] = (f16_t)cl0.w;
        xlo[4] = (f16_t)cl1.x; xlo[5] = (f16_t)cl1.y; xlo[6] = (f16_t)cl1.z; xlo[7] = (f16_t)cl1.w;
        xhi[0] = (f16_t)ch0.x; xhi[1] = (f16_t)ch0.y; xhi[2] = (f16_t)ch0.z; xhi[3] = (f16_t)ch0.w;
        xhi[4] = (f16_t)ch1.x; xhi[5] = (f16_t)ch1.y; xhi[6] = (f16_t)ch1.z; xhi[7] = (f16_t)ch1.w;

        f32x4_t acc = {0.f, 0.f, 0.f, 0.f};
#pragma unroll
        for (int v = 0; v < ZDIM; ++v) {
            f32x4_t t = {0.f, 0.f, 0.f, 0.f};
            t = __builtin_amdgcn_mfma_f32_16x16x32_f16(xlo, B[2 * v], t, 0, 0, 0);
            t = __builtin_amdgcn_mfma_f32_16x16x32_f16(xhi, B[2 * v + 1], t, 0, 0, 0);
#pragma unroll
            for (int reg = 0; reg < 4; ++reg)
                acc[reg] = fmaf(zqa[v][reg], t[reg], acc[reg]);
        }

        // ---- phase 3: stores ----
#pragma unroll
        for (int reg = 0; reg < 4; ++reg)
            out[oidx[reg]] = oold[reg] + acc[reg] * 0.1f;   // s staged by pass_out; /10 here

        cl0 = nl0; cl1 = nl1; ch0 = nh0; ch1 = nh1;
    }
}

// ---------------------------------------------------------------------------
// Counting sort of edges by dst (unchanged). scatter emits perm, sperm
// (permuted src) and eattr_p (permuted edge_attr).
// ---------------------------------------------------------------------------
__global__ __launch_bounds__(256) void hist_kernel(
    const int* __restrict__ edst, int* __restrict__ cnt, int E)
{
    int e = blockIdx.x * 256 + threadIdx.x;
    if (e >= E) return;
    atomicAdd(&cnt[edst[e]], 1);
}

__global__ __launch_bounds__(1024) void scan_block(
    const int* __restrict__ cnt, int* __restrict__ off,
    int* __restrict__ bsum, int N)
{
    __shared__ int sh[1024];
    int tid = threadIdx.x;
    int i = blockIdx.x * 1024 + tid;
    int v = (i < N) ? cnt[i] : 0;
    sh[tid] = v;
    __syncthreads();
#pragma unroll
    for (int d = 1; d < 1024; d <<= 1) {
        int t = (tid >= d) ? sh[tid - d] : 0;
        __syncthreads();
        sh[tid] += t;
        __syncthreads();
    }
    if (i < N) off[i + 1] = sh[tid];
    if (tid == 1023) bsum[blockIdx.x] = sh[1023];
    if (i == 0) off[0] = 0;
}

__global__ __launch_bounds__(64) void scan_sums(int* __restrict__ bsum, int nb)
{
    int tid = threadIdx.x;
    int v = (tid < nb) ? bsum[tid] : 0;
#pragma unroll
    for (int d = 1; d < 64; d <<= 1) {
        int t = __shfl_up(v, d, 64);
        if (tid >= d) v += t;
    }
    int ex = __shfl_up(v, 1, 64);
    if (tid == 0) ex = 0;
    if (tid < nb) bsum[tid] = ex;
}

__global__ __launch_bounds__(1024) void scan_add(
    int* __restrict__ off, const int* __restrict__ bsum, int N)
{
    int i = blockIdx.x * 1024 + threadIdx.x;
    if (i < N) off[i + 1] += bsum[blockIdx.x];
}

__global__ __launch_bounds__(256) void scatter_kernel(
    const int* __restrict__ edst, const int* __restrict__ esrc,
    const float* __restrict__ eattr, const int* __restrict__ off,
    int* __restrict__ cursor, int* __restrict__ perm,
    int* __restrict__ sperm, float* __restrict__ eattr_p, int E)
{
    int e = blockIdx.x * 256 + threadIdx.x;
    if (e >= E) return;
    int d = edst[e];
    int pos = off[d] + atomicAdd(&cursor[d], 1);
    perm[pos] = e;
    sperm[pos] = esrc[e];
    float4 at = *(const float4*)(eattr + (size_t)e * 4);
    *(float4*)(eattr_p + (size_t)pos * 4) = at;
}

// ---------------------------------------------------------------------------
// wgemm: w = elem[perm[pos]] @ tpwt via MFMA, for positions [lo, lo+16*ntiles).
// Persistent B-frags (tpwt f16, scales baked in), grid-stride tile loop with
// depth-2 elem prefetch. wbuf[(pos-lo)*64 + u][0..3] = w1',w2',w3',w4'.
// ---------------------------------------------------------------------------
__global__ __launch_bounds__(256, 2) void wgemm_kernel(
    const int* __restrict__ perm, const float* __restrict__ elem,
    const f16_t* __restrict__ tpwt, f16_t* __restrict__ wbuf,
    int lo, int ntiles)
{
    const int lane = threadIdx.x & 63;
    const int mm = lane & 15, q = lane >> 4;
    int tile = blockIdx.x * 4 + (threadIdx.x >> 6);
    const int nw = gridDim.x * 4;

    // B-frags: stripe s covers cols s*16 + mm, k = q*8+j  (16 x 16B loads)
    f16x8_t B[16];
#pragma unroll
    for (int s = 0; s < 16; ++s)
        B[s] = *(const f16x8_t*)(tpwt + ((size_t)(s * 16 + mm)) * 32 + q * 8);

    if (tile >= ntiles) return;
    float4 ca, cb;
    {
        int e = perm[lo + (tile << 4) + mm];
        const float* er = elem + ((size_t)e << 5) + q * 8;
        ca = *(const float4*)er;
        cb = *(const float4*)(er + 4);
    }

    for (; tile < ntiles; tile += nw) {
        const int nt = tile + nw;
        float4 na = ca, nb = cb;
        if (nt < ntiles) {
            int e = perm[lo + (nt << 4) + mm];
            const float* er = elem + ((size_t)e << 5) + q * 8;
            na = *(const float4*)er;
            nb = *(const float4*)(er + 4);
        }

        f16x8_t A;
        A[0] = (f16_t)ca.x; A[1] = (f16_t)ca.y; A[2] = (f16_t)ca.z; A[3] = (f16_t)ca.w;
        A[4] = (f16_t)cb.x; A[5] = (f16_t)cb.y; A[6] = (f16_t)cb.z; A[7] = (f16_t)cb.w;

        f32x4_t D[16];
#pragma unroll
        for (int s = 0; s < 16; ++s) {
            f32x4_t zer = {0.f, 0.f, 0.f, 0.f};
            D[s] = __builtin_amdgcn_mfma_f32_16x16x32_f16(A, B[s], zer, 0, 0, 0);
        }

        // store: D col = s*16+mm -> u = (s&3)*16+mm; row = q*4+reg
#pragma unroll
        for (int reg = 0; reg < 4; ++reg) {
            const int row = q * 4 + reg;
            const size_t base = ((size_t)((tile << 4) + row)) << 6;   // row in wbuf
#pragma unroll
            for (int t = 0; t < 4; ++t) {
                const int u = t * 16 + mm;
                f16x4_t wq;
                wq[0] = (f16_t)D[0 * 4 + t][reg];
                wq[1] = (f16_t)D[1 * 4 + t][reg];
                wq[2] = (f16_t)D[2 * 4 + t][reg];
                wq[3] = (f16_t)D[3 * 4 + t][reg];
                *(f16x4_t*)(wbuf + ((base + u) << 2)) = wq;
            }
        }
        ca = na; cb = nb;
    }
}

// ---------------------------------------------------------------------------
// aggregate5: 1 wave per node, chunked over edge positions [lo, hi).
// Per edge: 8B w-load (coalesced), f16 gathers of xl[src], ~14-FMA TP,
// += into aggs/aggv (zero-initialized; same wave owns node in both chunks).
// ---------------------------------------------------------------------------
__device__ __forceinline__ void agg_edge5(
    float xs, float v0, float v1, float v2, int i, int lo,
    const f16_t* __restrict__ wbuf, const float* __restrict__ eattr_p, int u,
    float& accx, float& accy, float& accz, float& accw)
{
    f16x4_t wq = *(const f16x4_t*)(wbuf + ((((size_t)(i - lo)) << 6) + u) * 4);
    float w1 = (float)wq[0], w2 = (float)wq[1], w3 = (float)wq[2], w4 = (float)wq[3];
    float4 at = *(const float4*)(eattr_p + ((size_t)i << 2));
    float dot3 = v0 * at.y + v1 * at.z + v2 * at.w;
    accx = fmaf(w1 * xs, at.x, accx);
    accx = fmaf(w4, dot3, accx);
    float w2x = w2 * xs;
    accy = fmaf(w2x, at.y, accy);
    accz = fmaf(w2x, at.z, accz);
    accw = fmaf(w2x, at.w, accw);
    float w3s = w3 * at.x;
    accy = fmaf(w3s, v0, accy);
    accz = fmaf(w3s, v1, accz);
    accw = fmaf(w3s, v2, accw);
}

__global__ __launch_bounds__(256, 8) void aggregate5(
    const int* __restrict__ off, const int* __restrict__ sperm,
    const f16_t* __restrict__ wbuf, const float* __restrict__ eattr_p,
    const f16_t* __restrict__ xls, const f16_t* __restrict__ xlv,
    float* __restrict__ aggs, float* __restrict__ aggv,
    int N, int lo, int hi)
{
    int n = (blockIdx.x * 256 + threadIdx.x) >> 6;      // one wave per node
    if (n >= N) return;
    int u = threadIdx.x & 63;

    int s0 = __builtin_amdgcn_readfirstlane(off[n]);
    int s1 = __builtin_amdgcn_readfirstlane(off[n + 1]);
    int cs0 = s0 > lo ? s0 : lo;
    int cs1 = s1 < hi ? s1 : hi;
    if (cs0 >= cs1) return;

    float accx = 0.f, accy = 0.f, accz = 0.f, accw = 0.f;
    const int last = cs1 - 1;

    // depth-2 prefetch slots for the xl gather (the HBM-latency item)
    int sa = __builtin_amdgcn_readfirstlane(sperm[cs0]);
    float a_xs = (float)xls[((size_t)sa << 6) + u];
    float a_v0 = (float)xlv[((size_t)(3 * sa + 0) << 6) + u];
    float a_v1 = (float)xlv[((size_t)(3 * sa + 1) << 6) + u];
    float a_v2 = (float)xlv[((size_t)(3 * sa + 2) << 6) + u];
    int ib = (cs0 + 1 <= last) ? cs0 + 1 : last;
    int sb = __builtin_amdgcn_readfirstlane(sperm[ib]);
    float b_xs = (float)xls[((size_t)sb << 6) + u];
    float b_v0 = (float)xlv[((size_t)(3 * sb + 0) << 6) + u];
    float b_v1 = (float)xlv[((size_t)(3 * sb + 1) << 6) + u];
    float b_v2 = (float)xlv[((size_t)(3 * sb + 2) << 6) + u];

    int i = cs0;
    while (true) {
        agg_edge5(a_xs, a_v0, a_v1, a_v2, i, lo, wbuf, eattr_p, u,
                  accx, accy, accz, accw);
        {
            int inx = (i + 2 <= last) ? i + 2 : last;
            int sn = __builtin_amdgcn_readfirstlane(sperm[inx]);
            a_xs = (float)xls[((size_t)sn << 6) + u];
            a_v0 = (float)xlv[((size_t)(3 * sn + 0) << 6) + u];
            a_v1 = (float)xlv[((size_t)(3 * sn + 1) << 6) + u];
            a_v2 = (float)xlv[((size_t)(3 * sn + 2) << 6) + u];
        }
        if (++i > last) break;
        agg_edge5(b_xs, b_v0, b_v1, b_v2, i, lo, wbuf, eattr_p, u,
                  accx, accy, accz, accw);
        {
            int inx = (i + 2 <= last) ? i + 2 : last;
            int sn = __builtin_amdgcn_readfirstlane(sperm[inx]);
            b_xs = (float)xls[((size_t)sn << 6) + u];
            b_v0 = (float)xlv[((size_t)(3 * sn + 0) << 6) + u];
            b_v1 = (float)xlv[((size_t)(3 * sn + 1) << 6) + u];
            b_v2 = (float)xlv[((size_t)(3 * sn + 2) << 6) + u];
        }
        if (++i > last) break;
    }

    aggs[((size_t)n << 6) + u] += accx;
    aggv[((size_t)(3 * n + 0) << 6) + u] += accy;
    aggv[((size_t)(3 * n + 1) << 6) + u] += accz;
    aggv[((size_t)(3 * n + 2) << 6) + u] += accw;
}

// ---------------------------------------------------------------------------
extern "C" void kernel_launch(void* const* d_in, const int* in_sizes, int n_in,
                              void* d_out, int out_size, void* d_ws, size_t ws_size,
                              hipStream_t stream)
{
    const float* x     = (const float*)d_in[0];
    const float* z     = (const float*)d_in[1];
    const int*   esrc  = (const int*)d_in[2];
    const int*   edst  = (const int*)d_in[3];
    const float* elem  = (const float*)d_in[4];
    const float* eattr = (const float*)d_in[5];
    const float* Wsi0  = (const float*)d_in[6];
    const float* Wsi1  = (const float*)d_in[7];
    const float* Wl10  = (const float*)d_in[8];
    const float* Wl11  = (const float*)d_in[9];
    const float* Wl20  = (const float*)d_in[10];
    const float* Wl21  = (const float*)d_in[11];
    const float* tpw   = (const float*)d_in[12];
    float* out = (float*)d_out;

    const int N = in_sizes[1] / ZDIM;      // 50000
    const int E = in_sizes[2];             // 500000
    const int Ehalf = E / 2;               // 250000 (divisible by 16)

    // workspace carve-up (~226 MB, under the ~230 MB proven previously):
    f16_t* xls  = (f16_t*)d_ws;                          // N*64   f16
    f16_t* xlv  = xls + (size_t)N * 64;                  // 3N*64  f16
    float* aggs = (float*)(xlv + (size_t)3 * N * 64);    // N*64   f32
    float* aggv = aggs + (size_t)N * 64;                 // 3N*64  f32
    // region R: union of {Xs,Xv} (dead after fctp passes) and wbuf (per-chunk w)
    char*  R    = (char*)(aggv + (size_t)3 * N * 64);
    f16_t* Xs   = (f16_t*)R;                             // N*64   f16
    f16_t* Xv   = Xs + (size_t)N * 64;                   // 3N*64  f16
    f16_t* wbuf = (f16_t*)R;                             // Ehalf*256 f16 = 128 MB
    size_t Rbytes = (size_t)Ehalf * 256 * sizeof(f16_t);
    float* eattr_p = (float*)(R + Rbytes);               // E*4 f32
    int*   sperm   = (int*)(eattr_p + (size_t)E * 4);    // E
    int*   perm    = sperm + E;                          // E
    int*   cnt     = perm + E;                           // N
    int*   cursor  = cnt + N;                            // N
    int*   off     = cursor + N;                         // N+1
    int*   bsum    = off + (N + 1);                      // 64
    // z transposes, 256B-aligned for float4 loads: zt (10N) + ztv (30N) f32
    size_t zoff = (((size_t)(bsum + 64) - (size_t)d_ws) + 255) & ~(size_t)255;
    float* zt  = (float*)((char*)d_ws + zoff);           // 10N f32 (2 MB)
    float* ztv = zt + (size_t)10 * N;                    // 30N f32 (6 MB)
    f16_t* tpwt = (f16_t*)(ztv + (size_t)30 * N);        // 256*32 f16 (16 KB)

    const int SCAN_B = 1024;
    int nb = (N + SCAN_B - 1) / SCAN_B;  // 49 (<=64 required by scan_sums)

    hipMemsetAsync(cnt, 0, 2 * (size_t)N * sizeof(int), stream);       // cnt+cursor
    hipMemsetAsync(aggs, 0, (size_t)4 * N * 64 * sizeof(float), stream); // aggs+aggv

    int g0 = (N * MULT + 255) / 256;
    hipLaunchKernelGGL(transform_x2, dim3(g0), dim3(256), 0, stream, x, Xs, Xv, N);
    int gz = (N + 255) / 256;
    hipLaunchKernelGGL(zprep_kernel, dim3(gz), dim3(256), 0, stream, z, zt, ztv, N);
    hipLaunchKernelGGL(tpwprep_kernel, dim3(32), dim3(256), 0, stream, tpw, tpwt);

    // stageA split: two single-W passes at (256,2) -> B[20] fits, no spill
    hipLaunchKernelGGL(fctp_pass_xl, dim3(512), dim3(256), 0, stream,
                       Xs, Xv, zt, ztv, Wl10, Wl11, xls, xlv, N, 128);
    hipLaunchKernelGGL(fctp_pass_out, dim3(512), dim3(256), 0, stream,
                       Xs, Xv, zt, ztv, Wsi0, Wsi1, out, N, 128);

    int geh = (E + 255) / 256;
    hipLaunchKernelGGL(hist_kernel, dim3(geh), dim3(256), 0, stream,
                       edst, cnt, E);
    hipLaunchKernelGGL(scan_block, dim3(nb), dim3(SCAN_B), 0, stream,
                       cnt, off, bsum, N);
    hipLaunchKernelGGL(scan_sums, dim3(1), dim3(64), 0, stream, bsum, nb);
    hipLaunchKernelGGL(scan_add, dim3(nb), dim3(SCAN_B), 0, stream,
                       off, bsum, N);
    hipLaunchKernelGGL(scatter_kernel, dim3(geh), dim3(256), 0, stream,
                       edst, esrc, eattr, off, cursor, perm, sperm, eattr_p, E);

    // two node-aligned edge chunks: wgemm (w via MFMA) -> aggregate (+=)
    int wt = Ehalf / 16;                       // 15625 tiles per chunk
    int ga = (N * 64 + 255) / 256;
    for (int c = 0; c < 2; ++c) {
        int lo = c * Ehalf, hi = lo + Ehalf;
        hipLaunchKernelGGL(wgemm_kernel, dim3(512), dim3(256), 0, stream,
                           perm, elem, tpwt, wbuf, lo, wt);
        hipLaunchKernelGGL(aggregate5, dim3(ga), dim3(256), 0, stream,
                           off, sperm, wbuf, eattr_p, xls, xlv,
                           aggs, aggv, N, lo, hi);
    }

    hipLaunchKernelGGL(fctp_stageC_mfma, dim3(512), dim3(256), 0, stream,
                       aggs, aggv, zt, ztv, Wl20, Wl21, out, N, 128);
}

// Round 7
// 553.022 us; speedup vs baseline: 1.4659x; 1.0533x over previous
//
#include <hip/hip_runtime.h>

// Problem constants (from reference)
#define MULT 64
#define FEATD 256
#define ZDIM 10

#define INV640f 0.03952847075210474f   // 1/sqrt(640)
#define ISQ2f   0.7071067811865476f    // 1/sqrt(2)
#define ISQ3f   0.5773502691896258f    // 1/sqrt(3)

typedef _Float16 f16_t;
typedef f16_t f16x8_t __attribute__((ext_vector_type(8)));
typedef f16_t f16x4_t __attribute__((ext_vector_type(4)));
typedef float f32x4_t __attribute__((ext_vector_type(4)));

// ---------------------------------------------------------------------------
// K0: transform x (n,256 natural: [x0(64) | x1(64,3)]) into f16 GEMM rows:
//   Xs[n*64 + u]        = x0[n,u]        (N x 64)
//   Xv[(3n+k)*64 + u]   = x1[n,u,k]      (3N x 64)
// ---------------------------------------------------------------------------
__global__ __launch_bounds__(256) void transform_x2(
    const float* __restrict__ x, f16_t* __restrict__ Xs,
    f16_t* __restrict__ Xv, int N)
{
    int idx = blockIdx.x * 256 + threadIdx.x;     // over N*64 (n,u) pairs
    if (idx >= N * MULT) return;
    int n = idx >> 6;
    int u = idx & 63;
    const float* row = x + (size_t)n * FEATD;
    Xs[idx] = (f16_t)row[u];
    const float* x1p = row + MULT + u * 3;
    Xv[((size_t)3 * n + 0) * MULT + u] = (f16_t)x1p[0];
    Xv[((size_t)3 * n + 1) * MULT + u] = (f16_t)x1p[1];
    Xv[((size_t)3 * n + 2) * MULT + u] = (f16_t)x1p[2];
}

// ---------------------------------------------------------------------------
// zprep: transpose z with INV640 folded in, in two layouts:
//   zt [v*N + n]   = z[n,v]*INV640       (scalar-block GEMM rows, N rows)
//   ztv[v*3N + r]  = z[r/3,v]*INV640     (row-expanded for vector rows, 3N)
// ---------------------------------------------------------------------------
__global__ __launch_bounds__(256) void zprep_kernel(
    const float* __restrict__ z, float* __restrict__ zt,
    float* __restrict__ ztv, int N)
{
    int n = blockIdx.x * 256 + threadIdx.x;
    if (n >= N) return;
    const float* zr = z + (size_t)n * ZDIM;
#pragma unroll
    for (int v = 0; v < ZDIM; ++v) {
        float val = zr[v] * INV640f;
        zt[(size_t)v * N + n] = val;
        float* p = ztv + (size_t)v * 3 * N + 3 * (size_t)n;
        p[0] = val; p[1] = val; p[2] = val;
    }
}

// ---------------------------------------------------------------------------
// tpwprep: tpwt[c*32 + k] = tpw[k*256 + c] * scale(c), f16  (scales baked in)
// ---------------------------------------------------------------------------
__global__ __launch_bounds__(256) void tpwprep_kernel(
    const float* __restrict__ tpw, f16_t* __restrict__ tpwt)
{
    int idx = blockIdx.x * 256 + threadIdx.x;    // 256*32 entries
    if (idx >= 256 * 32) return;
    int c = idx >> 5, k = idx & 31;
    float s = (c < 192) ? ISQ2f : (ISQ2f * ISQ3f);
    tpwt[(size_t)c * 32 + k] = (f16_t)(tpw[(size_t)k * 256 + c] * s);
}

// ---------------------------------------------------------------------------
// aggcvt: agg f32 -> f16 (stageC converts to f16 for MFMA anyway; this is
// numerically identical and halves stageC's A-traffic + register footprint).
// ---------------------------------------------------------------------------
__global__ __launch_bounds__(256) void aggcvt_kernel(
    const float* __restrict__ a, f16_t* __restrict__ h, int n4)
{
    int i = blockIdx.x * 256 + threadIdx.x;      // one float4 per thread
    if (i >= n4) return;
    float4 v = *(const float4*)(a + (size_t)i * 4);
    f16x4_t o;
    o[0] = (f16_t)v.x; o[1] = (f16_t)v.y; o[2] = (f16_t)v.z; o[3] = (f16_t)v.w;
    *(f16x4_t*)(h + (size_t)i * 4) = o;
}

// ---------------------------------------------------------------------------
// MFMA fctp kernels (f16). GEMM form: o[r,w] = sum_v z[r,v] * sum_u x[r,u]W[u,v,w].
// Per v: 2 MFMAs (K=64) with RAW x fragments, z folded on f32 accumulators.
// REGISTER BUDGET: B[20]=80 AGPR-side regs; (256,2) REQUIRED (round-2: (256,4)
// caps at 128 and spills B, FETCH 55->416MB).
// SCHEDULE (round-5 lesson): the compiler SINKS batched loads back into the
// consume loop (VGPR=72 proved zqa never lived whole; per-iter = ~10 serial
// latency bursts = 7.9k cyc). Fix: 2-deep rotation of ALL per-tile loads
// (A-rows AND zqa) + ONE sched_barrier(0) per iteration pinning the
// load-issue phase above the compute phase.
// 16x16x32 layouts: A [m=lane&15][k=q*8+j], B [k=q*8+j][n=lane&15],
// C/D col=lane&15, row=q*4+reg  (m89/m91-verified).
// ---------------------------------------------------------------------------
__device__ __forceinline__ void preload_W(
    const float* __restrict__ W, int c0, int q, int mm, f16x8_t (&B)[20])
{
    const int col = c0 + mm;
#pragma unroll
    for (int ks = 0; ks < 20; ++ks) {
        const int v = ks >> 1;
        const int ub = ((ks & 1) << 5) + (q << 3);
        const int base = v * 64 + col;
#pragma unroll
        for (int j = 0; j < 8; ++j)
            B[ks][j] = (f16_t)W[(ub + j) * 640 + base];   // W[u][v][w]
    }
}

// pass 1: s = fctp(x, z, Wsi) staged into out (natural layout)
__global__ __launch_bounds__(256, 2) void fctp_pass_out(
    const f16_t* __restrict__ Xs, const f16_t* __restrict__ Xv,
    const float* __restrict__ zt, const float* __restrict__ ztv,
    const float* __restrict__ Wsi0, const float* __restrict__ Wsi1,
    float* __restrict__ out, int N, int nsc)
{
    const int lane = threadIdx.x & 63;
    const int wave = threadIdx.x >> 6;
    const int c0 = wave << 4;            // 16-col stripe per wave
    const int q = lane >> 4;
    const int mm = lane & 15;
    const bool sc = (int)blockIdx.x < nsc;
    const float* W = sc ? Wsi0 : Wsi1;
    const f16_t* Xsel = sc ? Xs : Xv;
    const float* ztb = sc ? zt : ztv;
    const size_t zsr = sc ? (size_t)N : (size_t)3 * N;
    const int ntiles = sc ? (N >> 4) : ((3 * N) >> 4);
    const int worker = sc ? (int)blockIdx.x : ((int)blockIdx.x - nsc);
    const int nworkers = sc ? nsc : 3 * nsc;

    f16x8_t B[20];
    preload_W(W, c0, q, mm, B);

    int tile = worker;
    if (tile >= ntiles) return;
    f16x8_t cxlo, cxhi;
    f32x4_t czq[ZDIM];
    {
        const int r = (tile << 4) + mm;
        cxlo = *(const f16x8_t*)(Xsel + ((size_t)r << 6) + (q << 3));
        cxhi = *(const f16x8_t*)(Xsel + ((size_t)r << 6) + 32 + (q << 3));
        const int rb4 = (tile << 4) + (q << 2);
#pragma unroll
        for (int v = 0; v < ZDIM; ++v)
            czq[v] = *(const f32x4_t*)(ztb + (size_t)v * zsr + rb4);
    }

    for (; tile < ntiles; tile += nworkers) {
        // ---- phase 1: issue ALL of next tile's loads ----
        const int nt = tile + nworkers;
        f16x8_t nxlo = cxlo, nxhi = cxhi;
        f32x4_t nzq[ZDIM];
#pragma unroll
        for (int v = 0; v < ZDIM; ++v) nzq[v] = czq[v];
        if (nt < ntiles) {
            const int r = (nt << 4) + mm;
            nxlo = *(const f16x8_t*)(Xsel + ((size_t)r << 6) + (q << 3));
            nxhi = *(const f16x8_t*)(Xsel + ((size_t)r << 6) + 32 + (q << 3));
            const int nrb4 = (nt << 4) + (q << 2);
#pragma unroll
            for (int v = 0; v < ZDIM; ++v)
                nzq[v] = *(const f32x4_t*)(ztb + (size_t)v * zsr + nrb4);
        }
        __builtin_amdgcn_sched_barrier(0);   // pin loads above compute

        // ---- phase 2: register-only compute on current tile ----
        const int rb4 = (tile << 4) + (q << 2);
        f32x4_t acc = {0.f, 0.f, 0.f, 0.f};
#pragma unroll
        for (int v = 0; v < ZDIM; ++v) {
            f32x4_t t = {0.f, 0.f, 0.f, 0.f};
            t = __builtin_amdgcn_mfma_f32_16x16x32_f16(cxlo, B[2 * v], t, 0, 0, 0);
            t = __builtin_amdgcn_mfma_f32_16x16x32_f16(cxhi, B[2 * v + 1], t, 0, 0, 0);
#pragma unroll
            for (int reg = 0; reg < 4; ++reg)
                acc[reg] = fmaf(czq[v][reg], t[reg], acc[reg]);
        }

        // ---- phase 3: stores ----
        const int w = c0 + mm;
#pragma unroll
        for (int reg = 0; reg < 4; ++reg) {
            const int ro = rb4 + reg;
            if (sc) {
                out[(size_t)ro * FEATD + w] = acc[reg];               // s, scalar part
            } else {
                const unsigned nn = (unsigned)ro / 3u;
                const int k = ro - 3 * (int)nn;
                out[(size_t)nn * FEATD + MULT + w * 3 + k] = acc[reg]; // s, vec part
            }
        }
        cxlo = nxlo; cxhi = nxhi;
#pragma unroll
        for (int v = 0; v < ZDIM; ++v) czq[v] = nzq[v];
    }
}

// pass 2: xl = fctp(x, z, Wl1) staged as f16 GEMM rows xls / xlv
__global__ __launch_bounds__(256, 2) void fctp_pass_xl(
    const f16_t* __restrict__ Xs, const f16_t* __restrict__ Xv,
    const float* __restrict__ zt, const float* __restrict__ ztv,
    const float* __restrict__ Wl10, const float* __restrict__ Wl11,
    f16_t* __restrict__ xls, f16_t* __restrict__ xlv, int N, int nsc)
{
    const int lane = threadIdx.x & 63;
    const int wave = threadIdx.x >> 6;
    const int c0 = wave << 4;
    const int q = lane >> 4;
    const int mm = lane & 15;
    const bool sc = (int)blockIdx.x < nsc;
    const float* W = sc ? Wl10 : Wl11;
    const f16_t* Xsel = sc ? Xs : Xv;
    const float* ztb = sc ? zt : ztv;
    const size_t zsr = sc ? (size_t)N : (size_t)3 * N;
    const int ntiles = sc ? (N >> 4) : ((3 * N) >> 4);
    const int worker = sc ? (int)blockIdx.x : ((int)blockIdx.x - nsc);
    const int nworkers = sc ? nsc : 3 * nsc;

    f16x8_t B[20];
    preload_W(W, c0, q, mm, B);

    f16_t* Osel = sc ? xls : xlv;

    int tile = worker;
    if (tile >= ntiles) return;
    f16x8_t cxlo, cxhi;
    f32x4_t czq[ZDIM];
    {
        const int r = (tile << 4) + mm;
        cxlo = *(const f16x8_t*)(Xsel + ((size_t)r << 6) + (q << 3));
        cxhi = *(const f16x8_t*)(Xsel + ((size_t)r << 6) + 32 + (q << 3));
        const int rb4 = (tile << 4) + (q << 2);
#pragma unroll
        for (int v = 0; v < ZDIM; ++v)
            czq[v] = *(const f32x4_t*)(ztb + (size_t)v * zsr + rb4);
    }

    for (; tile < ntiles; tile += nworkers) {
        // ---- phase 1: issue ALL of next tile's loads ----
        const int nt = tile + nworkers;
        f16x8_t nxlo = cxlo, nxhi = cxhi;
        f32x4_t nzq[ZDIM];
#pragma unroll
        for (int v = 0; v < ZDIM; ++v) nzq[v] = czq[v];
        if (nt < ntiles) {
            const int r = (nt << 4) + mm;
            nxlo = *(const f16x8_t*)(Xsel + ((size_t)r << 6) + (q << 3));
            nxhi = *(const f16x8_t*)(Xsel + ((size_t)r << 6) + 32 + (q << 3));
            const int nrb4 = (nt << 4) + (q << 2);
#pragma unroll
            for (int v = 0; v < ZDIM; ++v)
                nzq[v] = *(const f32x4_t*)(ztb + (size_t)v * zsr + nrb4);
        }
        __builtin_amdgcn_sched_barrier(0);   // pin loads above compute

        // ---- phase 2: register-only compute on current tile ----
        const int rb4 = (tile << 4) + (q << 2);
        f32x4_t acc = {0.f, 0.f, 0.f, 0.f};
#pragma unroll
        for (int v = 0; v < ZDIM; ++v) {
            f32x4_t t = {0.f, 0.f, 0.f, 0.f};
            t = __builtin_amdgcn_mfma_f32_16x16x32_f16(cxlo, B[2 * v], t, 0, 0, 0);
            t = __builtin_amdgcn_mfma_f32_16x16x32_f16(cxhi, B[2 * v + 1], t, 0, 0, 0);
#pragma unroll
            for (int reg = 0; reg < 4; ++reg)
                acc[reg] = fmaf(czq[v][reg], t[reg], acc[reg]);
        }

        // ---- phase 3: stores ----
        const int w = c0 + mm;
#pragma unroll
        for (int reg = 0; reg < 4; ++reg) {
            const int ro = rb4 + reg;
            Osel[((size_t)ro << 6) + w] = (f16_t)acc[reg];
        }
        cxlo = nxlo; cxhi = nxhi;
#pragma unroll
        for (int v = 0; v < ZDIM; ++v) czq[v] = nzq[v];
    }
}

// stage C: reads f16 agg rows (aggsh/aggvh via aggcvt), RMW on out.
__global__ __launch_bounds__(256, 2) void fctp_stageC_mfma(
    const f16_t* __restrict__ aggsh, const f16_t* __restrict__ aggvh,
    const float* __restrict__ zt, const float* __restrict__ ztv,
    const float* __restrict__ Wl20, const float* __restrict__ Wl21,
    float* __restrict__ out, int N, int nsc)
{
    const int lane = threadIdx.x & 63;
    const int wave = threadIdx.x >> 6;
    const int c0 = wave << 4;
    const int q = lane >> 4;
    const int mm = lane & 15;
    const bool sc = (int)blockIdx.x < nsc;
    const float* W = sc ? Wl20 : Wl21;
    const f16_t* Asel = sc ? aggsh : aggvh;
    const float* ztb = sc ? zt : ztv;
    const size_t zsr = sc ? (size_t)N : (size_t)3 * N;
    const int ntiles = sc ? (N >> 4) : ((3 * N) >> 4);
    const int worker = sc ? (int)blockIdx.x : ((int)blockIdx.x - nsc);
    const int nworkers = sc ? nsc : 3 * nsc;

    f16x8_t B[20];
    preload_W(W, c0, q, mm, B);

    int tile = worker;
    if (tile >= ntiles) return;
    f16x8_t cxlo, cxhi;
    f32x4_t czq[ZDIM];
    {
        const int r = (tile << 4) + mm;
        cxlo = *(const f16x8_t*)(Asel + ((size_t)r << 6) + (q << 3));
        cxhi = *(const f16x8_t*)(Asel + ((size_t)r << 6) + 32 + (q << 3));
        const int rb4 = (tile << 4) + (q << 2);
#pragma unroll
        for (int v = 0; v < ZDIM; ++v)
            czq[v] = *(const f32x4_t*)(ztb + (size_t)v * zsr + rb4);
    }

    for (; tile < ntiles; tile += nworkers) {
        // ---- phase 1: next tile's A+zq loads, and CURRENT out-old loads ----
        const int nt = tile + nworkers;
        f16x8_t nxlo = cxlo, nxhi = cxhi;
        f32x4_t nzq[ZDIM];
#pragma unroll
        for (int v = 0; v < ZDIM; ++v) nzq[v] = czq[v];
        if (nt < ntiles) {
            const int r = (nt << 4) + mm;
            nxlo = *(const f16x8_t*)(Asel + ((size_t)r << 6) + (q << 3));
            nxhi = *(const f16x8_t*)(Asel + ((size_t)r << 6) + 32 + (q << 3));
            const int nrb4 = (nt << 4) + (q << 2);
#pragma unroll
            for (int v = 0; v < ZDIM; ++v)
                nzq[v] = *(const f32x4_t*)(ztb + (size_t)v * zsr + nrb4);
        }
        const int rb4 = (tile << 4) + (q << 2);
        const int w = c0 + mm;
        size_t oidx[4];
        float oold[4];
#pragma unroll
        for (int reg = 0; reg < 4; ++reg) {
            const int ro = rb4 + reg;
            if (sc) {
                oidx[reg] = (size_t)ro * FEATD + w;
            } else {
                const unsigned nn = (unsigned)ro / 3u;
                const int k = ro - 3 * (int)nn;
                oidx[reg] = (size_t)nn * FEATD + MULT + w * 3 + k;
            }
            oold[reg] = out[oidx[reg]];
        }
        __builtin_amdgcn_sched_barrier(0);   // pin loads above compute

        // ---- phase 2: register-only compute ----
        f32x4_t acc = {0.f, 0.f, 0.f, 0.f};
#pragma unroll
        for (int v = 0; v < ZDIM; ++v) {
            f32x4_t t = {0.f, 0.f, 0.f, 0.f};
            t = __builtin_amdgcn_mfma_f32_16x16x32_f16(cxlo, B[2 * v], t, 0, 0, 0);
            t = __builtin_amdgcn_mfma_f32_16x16x32_f16(cxhi, B[2 * v + 1], t, 0, 0, 0);
#pragma unroll
            for (int reg = 0; reg < 4; ++reg)
                acc[reg] = fmaf(czq[v][reg], t[reg], acc[reg]);
        }

        // ---- phase 3: stores ----
#pragma unroll
        for (int reg = 0; reg < 4; ++reg)
            out[oidx[reg]] = oold[reg] + acc[reg] * 0.1f;   // s staged by pass_out; /10 here

        cxlo = nxlo; cxhi = nxhi;
#pragma unroll
        for (int v = 0; v < ZDIM; ++v) czq[v] = nzq[v];
    }
}

// ---------------------------------------------------------------------------
// Counting sort of edges by dst (unchanged). scatter emits perm, sperm
// (permuted src) and eattr_p (permuted edge_attr).
// ---------------------------------------------------------------------------
__global__ __launch_bounds__(256) void hist_kernel(
    const int* __restrict__ edst, int* __restrict__ cnt, int E)
{
    int e = blockIdx.x * 256 + threadIdx.x;
    if (e >= E) return;
    atomicAdd(&cnt[edst[e]], 1);
}

__global__ __launch_bounds__(1024) void scan_block(
    const int* __restrict__ cnt, int* __restrict__ off,
    int* __restrict__ bsum, int N)
{
    __shared__ int sh[1024];
    int tid = threadIdx.x;
    int i = blockIdx.x * 1024 + tid;
    int v = (i < N) ? cnt[i] : 0;
    sh[tid] = v;
    __syncthreads();
#pragma unroll
    for (int d = 1; d < 1024; d <<= 1) {
        int t = (tid >= d) ? sh[tid - d] : 0;
        __syncthreads();
        sh[tid] += t;
        __syncthreads();
    }
    if (i < N) off[i + 1] = sh[tid];
    if (tid == 1023) bsum[blockIdx.x] = sh[1023];
    if (i == 0) off[0] = 0;
}

__global__ __launch_bounds__(64) void scan_sums(int* __restrict__ bsum, int nb)
{
    int tid = threadIdx.x;
    int v = (tid < nb) ? bsum[tid] : 0;
#pragma unroll
    for (int d = 1; d < 64; d <<= 1) {
        int t = __shfl_up(v, d, 64);
        if (tid >= d) v += t;
    }
    int ex = __shfl_up(v, 1, 64);
    if (tid == 0) ex = 0;
    if (tid < nb) bsum[tid] = ex;
}

__global__ __launch_bounds__(1024) void scan_add(
    int* __restrict__ off, const int* __restrict__ bsum, int N)
{
    int i = blockIdx.x * 1024 + threadIdx.x;
    if (i < N) off[i + 1] += bsum[blockIdx.x];
}

__global__ __launch_bounds__(256) void scatter_kernel(
    const int* __restrict__ edst, const int* __restrict__ esrc,
    const float* __restrict__ eattr, const int* __restrict__ off,
    int* __restrict__ cursor, int* __restrict__ perm,
    int* __restrict__ sperm, float* __restrict__ eattr_p, int E)
{
    int e = blockIdx.x * 256 + threadIdx.x;
    if (e >= E) return;
    int d = edst[e];
    int pos = off[d] + atomicAdd(&cursor[d], 1);
    perm[pos] = e;
    sperm[pos] = esrc[e];
    float4 at = *(const float4*)(eattr + (size_t)e * 4);
    *(float4*)(eattr_p + (size_t)pos * 4) = at;
}

// ---------------------------------------------------------------------------
// wgemm: w = elem[perm[pos]] @ tpwt via MFMA, for positions [lo, lo+16*ntiles).
// Persistent B-frags (tpwt f16, scales baked in), grid-stride tile loop with
// depth-2 elem prefetch. wbuf[(pos-lo)*64 + u][0..3] = w1',w2',w3',w4'.
// ---------------------------------------------------------------------------
__global__ __launch_bounds__(256, 2) void wgemm_kernel(
    const int* __restrict__ perm, const float* __restrict__ elem,
    const f16_t* __restrict__ tpwt, f16_t* __restrict__ wbuf,
    int lo, int ntiles)
{
    const int lane = threadIdx.x & 63;
    const int mm = lane & 15, q = lane >> 4;
    int tile = blockIdx.x * 4 + (threadIdx.x >> 6);
    const int nw = gridDim.x * 4;

    // B-frags: stripe s covers cols s*16 + mm, k = q*8+j  (16 x 16B loads)
    f16x8_t B[16];
#pragma unroll
    for (int s = 0; s < 16; ++s)
        B[s] = *(const f16x8_t*)(tpwt + ((size_t)(s * 16 + mm)) * 32 + q * 8);

    if (tile >= ntiles) return;
    float4 ca, cb;
    {
        int e = perm[lo + (tile << 4) + mm];
        const float* er = elem + ((size_t)e << 5) + q * 8;
        ca = *(const float4*)er;
        cb = *(const float4*)(er + 4);
    }

    for (; tile < ntiles; tile += nw) {
        const int nt = tile + nw;
        float4 na = ca, nb = cb;
        if (nt < ntiles) {
            int e = perm[lo + (nt << 4) + mm];
            const float* er = elem + ((size_t)e << 5) + q * 8;
            na = *(const float4*)er;
            nb = *(const float4*)(er + 4);
        }

        f16x8_t A;
        A[0] = (f16_t)ca.x; A[1] = (f16_t)ca.y; A[2] = (f16_t)ca.z; A[3] = (f16_t)ca.w;
        A[4] = (f16_t)cb.x; A[5] = (f16_t)cb.y; A[6] = (f16_t)cb.z; A[7] = (f16_t)cb.w;

        f32x4_t D[16];
#pragma unroll
        for (int s = 0; s < 16; ++s) {
            f32x4_t zer = {0.f, 0.f, 0.f, 0.f};
            D[s] = __builtin_amdgcn_mfma_f32_16x16x32_f16(A, B[s], zer, 0, 0, 0);
        }

        // store: D col = s*16+mm -> u = (s&3)*16+mm; row = q*4+reg
#pragma unroll
        for (int reg = 0; reg < 4; ++reg) {
            const int row = q * 4 + reg;
            const size_t base = ((size_t)((tile << 4) + row)) << 6;   // row in wbuf
#pragma unroll
            for (int t = 0; t < 4; ++t) {
                const int u = t * 16 + mm;
                f16x4_t wq;
                wq[0] = (f16_t)D[0 * 4 + t][reg];
                wq[1] = (f16_t)D[1 * 4 + t][reg];
                wq[2] = (f16_t)D[2 * 4 + t][reg];
                wq[3] = (f16_t)D[3 * 4 + t][reg];
                *(f16x4_t*)(wbuf + ((base + u) << 2)) = wq;
            }
        }
        ca = na; cb = nb;
    }
}

// ---------------------------------------------------------------------------
// aggregate5: 1 wave per node, chunked over edge positions [lo, hi).
// Per edge: 8B w-load (coalesced), f16 gathers of xl[src], ~14-FMA TP,
// += into aggs/aggv (zero-initialized; same wave owns node in both chunks).
// ---------------------------------------------------------------------------
__device__ __forceinline__ void agg_edge5(
    float xs, float v0, float v1, float v2, int i, int lo,
    const f16_t* __restrict__ wbuf, const float* __restrict__ eattr_p, int u,
    float& accx, float& accy, float& accz, float& accw)
{
    f16x4_t wq = *(const f16x4_t*)(wbuf + ((((size_t)(i - lo)) << 6) + u) * 4);
    float w1 = (float)wq[0], w2 = (float)wq[1], w3 = (float)wq[2], w4 = (float)wq[3];
    float4 at = *(const float4*)(eattr_p + ((size_t)i << 2));
    float dot3 = v0 * at.y + v1 * at.z + v2 * at.w;
    accx = fmaf(w1 * xs, at.x, accx);
    accx = fmaf(w4, dot3, accx);
    float w2x = w2 * xs;
    accy = fmaf(w2x, at.y, accy);
    accz = fmaf(w2x, at.z, accz);
    accw = fmaf(w2x, at.w, accw);
    float w3s = w3 * at.x;
    accy = fmaf(w3s, v0, accy);
    accz = fmaf(w3s, v1, accz);
    accw = fmaf(w3s, v2, accw);
}

__global__ __launch_bounds__(256, 8) void aggregate5(
    const int* __restrict__ off, const int* __restrict__ sperm,
    const f16_t* __restrict__ wbuf, const float* __restrict__ eattr_p,
    const f16_t* __restrict__ xls, const f16_t* __restrict__ xlv,
    float* __restrict__ aggs, float* __restrict__ aggv,
    int N, int lo, int hi)
{
    int n = (blockIdx.x * 256 + threadIdx.x) >> 6;      // one wave per node
    if (n >= N) return;
    int u = threadIdx.x & 63;

    int s0 = __builtin_amdgcn_readfirstlane(off[n]);
    int s1 = __builtin_amdgcn_readfirstlane(off[n + 1]);
    int cs0 = s0 > lo ? s0 : lo;
    int cs1 = s1 < hi ? s1 : hi;
    if (cs0 >= cs1) return;

    float accx = 0.f, accy = 0.f, accz = 0.f, accw = 0.f;
    const int last = cs1 - 1;

    // depth-2 prefetch slots for the xl gather (the HBM-latency item)
    int sa = __builtin_amdgcn_readfirstlane(sperm[cs0]);
    float a_xs = (float)xls[((size_t)sa << 6) + u];
    float a_v0 = (float)xlv[((size_t)(3 * sa + 0) << 6) + u];
    float a_v1 = (float)xlv[((size_t)(3 * sa + 1) << 6) + u];
    float a_v2 = (float)xlv[((size_t)(3 * sa + 2) << 6) + u];
    int ib = (cs0 + 1 <= last) ? cs0 + 1 : last;
    int sb = __builtin_amdgcn_readfirstlane(sperm[ib]);
    float b_xs = (float)xls[((size_t)sb << 6) + u];
    float b_v0 = (float)xlv[((size_t)(3 * sb + 0) << 6) + u];
    float b_v1 = (float)xlv[((size_t)(3 * sb + 1) << 6) + u];
    float b_v2 = (float)xlv[((size_t)(3 * sb + 2) << 6) + u];

    int i = cs0;
    while (true) {
        agg_edge5(a_xs, a_v0, a_v1, a_v2, i, lo, wbuf, eattr_p, u,
                  accx, accy, accz, accw);
        {
            int inx = (i + 2 <= last) ? i + 2 : last;
            int sn = __builtin_amdgcn_readfirstlane(sperm[inx]);
            a_xs = (float)xls[((size_t)sn << 6) + u];
            a_v0 = (float)xlv[((size_t)(3 * sn + 0) << 6) + u];
            a_v1 = (float)xlv[((size_t)(3 * sn + 1) << 6) + u];
            a_v2 = (float)xlv[((size_t)(3 * sn + 2) << 6) + u];
        }
        if (++i > last) break;
        agg_edge5(b_xs, b_v0, b_v1, b_v2, i, lo, wbuf, eattr_p, u,
                  accx, accy, accz, accw);
        {
            int inx = (i + 2 <= last) ? i + 2 : last;
            int sn = __builtin_amdgcn_readfirstlane(sperm[inx]);
            b_xs = (float)xls[((size_t)sn << 6) + u];
            b_v0 = (float)xlv[((size_t)(3 * sn + 0) << 6) + u];
            b_v1 = (float)xlv[((size_t)(3 * sn + 1) << 6) + u];
            b_v2 = (float)xlv[((size_t)(3 * sn + 2) << 6) + u];
        }
        if (++i > last) break;
    }

    aggs[((size_t)n << 6) + u] += accx;
    aggv[((size_t)(3 * n + 0) << 6) + u] += accy;
    aggv[((size_t)(3 * n + 1) << 6) + u] += accz;
    aggv[((size_t)(3 * n + 2) << 6) + u] += accw;
}

// ---------------------------------------------------------------------------
extern "C" void kernel_launch(void* const* d_in, const int* in_sizes, int n_in,
                              void* d_out, int out_size, void* d_ws, size_t ws_size,
                              hipStream_t stream)
{
    const float* x     = (const float*)d_in[0];
    const float* z     = (const float*)d_in[1];
    const int*   esrc  = (const int*)d_in[2];
    const int*   edst  = (const int*)d_in[3];
    const float* elem  = (const float*)d_in[4];
    const float* eattr = (const float*)d_in[5];
    const float* Wsi0  = (const float*)d_in[6];
    const float* Wsi1  = (const float*)d_in[7];
    const float* Wl10  = (const float*)d_in[8];
    const float* Wl11  = (const float*)d_in[9];
    const float* Wl20  = (const float*)d_in[10];
    const float* Wl21  = (const float*)d_in[11];
    const float* tpw   = (const float*)d_in[12];
    float* out = (float*)d_out;

    const int N = in_sizes[1] / ZDIM;      // 50000
    const int E = in_sizes[2];             // 500000
    const int Ehalf = E / 2;               // 250000 (divisible by 16)

    // workspace carve-up (~226 MB, under the ~230 MB proven previously):
    f16_t* xls  = (f16_t*)d_ws;                          // N*64   f16
    f16_t* xlv  = xls + (size_t)N * 64;                  // 3N*64  f16
    float* aggs = (float*)(xlv + (size_t)3 * N * 64);    // N*64   f32
    float* aggv = aggs + (size_t)N * 64;                 // 3N*64  f32
    // region R: union of {Xs,Xv} (dead after fctp passes), wbuf (chunks),
    // and aggh (f16 agg rows, alive only for aggcvt->stageC at the end)
    char*  R    = (char*)(aggv + (size_t)3 * N * 64);
    f16_t* Xs   = (f16_t*)R;                             // N*64   f16
    f16_t* Xv   = Xs + (size_t)N * 64;                   // 3N*64  f16
    f16_t* wbuf = (f16_t*)R;                             // Ehalf*256 f16 = 128 MB
    f16_t* aggh = (f16_t*)R;                             // 4N*64 f16 (25.6 MB)
    size_t Rbytes = (size_t)Ehalf * 256 * sizeof(f16_t);
    float* eattr_p = (float*)(R + Rbytes);               // E*4 f32
    int*   sperm   = (int*)(eattr_p + (size_t)E * 4);    // E
    int*   perm    = sperm + E;                          // E
    int*   cnt     = perm + E;                           // N
    int*   cursor  = cnt + N;                            // N
    int*   off     = cursor + N;                         // N+1
    int*   bsum    = off + (N + 1);                      // 64
    // z transposes, 256B-aligned for float4 loads: zt (10N) + ztv (30N) f32
    size_t zoff = (((size_t)(bsum + 64) - (size_t)d_ws) + 255) & ~(size_t)255;
    float* zt  = (float*)((char*)d_ws + zoff);           // 10N f32 (2 MB)
    float* ztv = zt + (size_t)10 * N;                    // 30N f32 (6 MB)
    f16_t* tpwt = (f16_t*)(ztv + (size_t)30 * N);        // 256*32 f16 (16 KB)

    const int SCAN_B = 1024;
    int nb = (N + SCAN_B - 1) / SCAN_B;  // 49 (<=64 required by scan_sums)

    hipMemsetAsync(cnt, 0, 2 * (size_t)N * sizeof(int), stream);       // cnt+cursor
    hipMemsetAsync(aggs, 0, (size_t)4 * N * 64 * sizeof(float), stream); // aggs+aggv

    int g0 = (N * MULT + 255) / 256;
    hipLaunchKernelGGL(transform_x2, dim3(g0), dim3(256), 0, stream, x, Xs, Xv, N);
    int gz = (N + 255) / 256;
    hipLaunchKernelGGL(zprep_kernel, dim3(gz), dim3(256), 0, stream, z, zt, ztv, N);
    hipLaunchKernelGGL(tpwprep_kernel, dim3(32), dim3(256), 0, stream, tpw, tpwt);

    // stageA split: two single-W passes at (256,2) -> B[20] fits, no spill
    hipLaunchKernelGGL(fctp_pass_xl, dim3(512), dim3(256), 0, stream,
                       Xs, Xv, zt, ztv, Wl10, Wl11, xls, xlv, N, 128);
    hipLaunchKernelGGL(fctp_pass_out, dim3(512), dim3(256), 0, stream,
                       Xs, Xv, zt, ztv, Wsi0, Wsi1, out, N, 128);

    int geh = (E + 255) / 256;
    hipLaunchKernelGGL(hist_kernel, dim3(geh), dim3(256), 0, stream,
                       edst, cnt, E);
    hipLaunchKernelGGL(scan_block, dim3(nb), dim3(SCAN_B), 0, stream,
                       cnt, off, bsum, N);
    hipLaunchKernelGGL(scan_sums, dim3(1), dim3(64), 0, stream, bsum, nb);
    hipLaunchKernelGGL(scan_add, dim3(nb), dim3(SCAN_B), 0, stream,
                       off, bsum, N);
    hipLaunchKernelGGL(scatter_kernel, dim3(geh), dim3(256), 0, stream,
                       edst, esrc, eattr, off, cursor, perm, sperm, eattr_p, E);

    // two node-aligned edge chunks: wgemm (w via MFMA) -> aggregate (+=)
    int wt = Ehalf / 16;                       // 15625 tiles per chunk
    int ga = (N * 64 + 255) / 256;
    for (int c = 0; c < 2; ++c) {
        int lo = c * Ehalf, hi = lo + Ehalf;
        hipLaunchKernelGGL(wgemm_kernel, dim3(512), dim3(256), 0, stream,
                           perm, elem, tpwt, wbuf, lo, wt);
        hipLaunchKernelGGL(aggregate5, dim3(ga), dim3(256), 0, stream,
                           off, sperm, wbuf, eattr_p, xls, xlv,
                           aggs, aggv, N, lo, hi);
    }

    // agg f32 -> f16 (wbuf dead now; aggh aliases R), then stage C
    int n4 = N * 64;                           // (4N*64)/4 float4 groups
    int gc = (n4 + 255) / 256;
    hipLaunchKernelGGL(aggcvt_kernel, dim3(gc), dim3(256), 0, stream,
                       aggs, aggh, n4);
    hipLaunchKernelGGL(fctp_stageC_mfma, dim3(512), dim3(256), 0, stream,
                       aggh, aggh + (size_t)N * 64, zt, ztv, Wl20, Wl21,
                       out, N, 128);
}

// Round 8
// 508.672 us; speedup vs baseline: 1.5937x; 1.0872x over previous
//
#include <hip/hip_runtime.h>

// Problem constants (from reference)
#define MULT 64
#define FEATD 256
#define ZDIM 10

#define INV640f 0.03952847075210474f   // 1/sqrt(640)
#define ISQ2f   0.7071067811865476f    // 1/sqrt(2)
#define ISQ3f   0.5773502691896258f    // 1/sqrt(3)

typedef _Float16 f16_t;
typedef f16_t f16x8_t __attribute__((ext_vector_type(8)));
typedef f16_t f16x4_t __attribute__((ext_vector_type(4)));
typedef float f32x4_t __attribute__((ext_vector_type(4)));

// ---------------------------------------------------------------------------
// K0: transform x (n,256 natural: [x0(64) | x1(64,3)]) into f16 GEMM rows:
//   Xs[n*64 + u]        = x0[n,u]        (N x 64)
//   Xv[(3n+k)*64 + u]   = x1[n,u,k]      (3N x 64)
// ---------------------------------------------------------------------------
__global__ __launch_bounds__(256) void transform_x2(
    const float* __restrict__ x, f16_t* __restrict__ Xs,
    f16_t* __restrict__ Xv, int N)
{
    int idx = blockIdx.x * 256 + threadIdx.x;     // over N*64 (n,u) pairs
    if (idx >= N * MULT) return;
    int n = idx >> 6;
    int u = idx & 63;
    const float* row = x + (size_t)n * FEATD;
    Xs[idx] = (f16_t)row[u];
    const float* x1p = row + MULT + u * 3;
    Xv[((size_t)3 * n + 0) * MULT + u] = (f16_t)x1p[0];
    Xv[((size_t)3 * n + 1) * MULT + u] = (f16_t)x1p[1];
    Xv[((size_t)3 * n + 2) * MULT + u] = (f16_t)x1p[2];
}

// ---------------------------------------------------------------------------
// zprep: transpose z with INV640 folded in, in two layouts:
//   zt [v*N + n]   = z[n,v]*INV640       (scalar-block GEMM rows, N rows)
//   ztv[v*3N + r]  = z[r/3,v]*INV640     (row-expanded for vector rows, 3N)
// ---------------------------------------------------------------------------
__global__ __launch_bounds__(256) void zprep_kernel(
    const float* __restrict__ z, float* __restrict__ zt,
    float* __restrict__ ztv, int N)
{
    int n = blockIdx.x * 256 + threadIdx.x;
    if (n >= N) return;
    const float* zr = z + (size_t)n * ZDIM;
#pragma unroll
    for (int v = 0; v < ZDIM; ++v) {
        float val = zr[v] * INV640f;
        zt[(size_t)v * N + n] = val;
        float* p = ztv + (size_t)v * 3 * N + 3 * (size_t)n;
        p[0] = val; p[1] = val; p[2] = val;
    }
}

// ---------------------------------------------------------------------------
// tpwprep: tpwt[c*32 + k] = tpw[k*256 + c] * scale(c), f16  (scales baked in)
// ---------------------------------------------------------------------------
__global__ __launch_bounds__(256) void tpwprep_kernel(
    const float* __restrict__ tpw, f16_t* __restrict__ tpwt)
{
    int idx = blockIdx.x * 256 + threadIdx.x;    // 256*32 entries
    if (idx >= 256 * 32) return;
    int c = idx >> 5, k = idx & 31;
    float s = (c < 192) ? ISQ2f : (ISQ2f * ISQ3f);
    tpwt[(size_t)c * 32 + k] = (f16_t)(tpw[(size_t)k * 256 + c] * s);
}

// ---------------------------------------------------------------------------
// aggcvt: agg f32 -> f16 (stageC converts to f16 for MFMA anyway; this is
// numerically identical and halves stageC's A-traffic + register footprint).
// ---------------------------------------------------------------------------
__global__ __launch_bounds__(256) void aggcvt_kernel(
    const float* __restrict__ a, f16_t* __restrict__ h, int n4)
{
    int i = blockIdx.x * 256 + threadIdx.x;      // one float4 per thread
    if (i >= n4) return;
    float4 v = *(const float4*)(a + (size_t)i * 4);
    f16x4_t o;
    o[0] = (f16_t)v.x; o[1] = (f16_t)v.y; o[2] = (f16_t)v.z; o[3] = (f16_t)v.w;
    *(f16x4_t*)(h + (size_t)i * 4) = o;
}

// ---------------------------------------------------------------------------
// MFMA fctp kernels (f16). GEMM form: o[r,w] = sum_v z[r,v] * sum_u x[r,u]W[u,v,w].
// Per v: 2 MFMAs (K=64) with RAW x fragments, z folded on f32 accumulators.
// REGISTER BUDGET: B[20]=80 AGPR-side regs; (256,2) REQUIRED (round-2: (256,4)
// caps at 128 and spills B, FETCH 55->416MB).
// SCHEDULE (round-5/7 lesson, VERIFIED): 2-deep rotation of ALL per-tile loads
// (A-rows AND zqa) + ONE sched_barrier(0) per iteration. stageC 119->62us,
// 1.0->1.7 TB/s.
// 16x16x32 layouts: A [m=lane&15][k=q*8+j], B [k=q*8+j][n=lane&15],
// C/D col=lane&15, row=q*4+reg  (m89/m91-verified).
// ---------------------------------------------------------------------------
__device__ __forceinline__ void preload_W(
    const float* __restrict__ W, int c0, int q, int mm, f16x8_t (&B)[20])
{
    const int col = c0 + mm;
#pragma unroll
    for (int ks = 0; ks < 20; ++ks) {
        const int v = ks >> 1;
        const int ub = ((ks & 1) << 5) + (q << 3);
        const int base = v * 64 + col;
#pragma unroll
        for (int j = 0; j < 8; ++j)
            B[ks][j] = (f16_t)W[(ub + j) * 640 + base];   // W[u][v][w]
    }
}

// pass 1: s = fctp(x, z, Wsi) staged into out (natural layout)
__global__ __launch_bounds__(256, 2) void fctp_pass_out(
    const f16_t* __restrict__ Xs, const f16_t* __restrict__ Xv,
    const float* __restrict__ zt, const float* __restrict__ ztv,
    const float* __restrict__ Wsi0, const float* __restrict__ Wsi1,
    float* __restrict__ out, int N, int nsc)
{
    const int lane = threadIdx.x & 63;
    const int wave = threadIdx.x >> 6;
    const int c0 = wave << 4;            // 16-col stripe per wave
    const int q = lane >> 4;
    const int mm = lane & 15;
    const bool sc = (int)blockIdx.x < nsc;
    const float* W = sc ? Wsi0 : Wsi1;
    const f16_t* Xsel = sc ? Xs : Xv;
    const float* ztb = sc ? zt : ztv;
    const size_t zsr = sc ? (size_t)N : (size_t)3 * N;
    const int ntiles = sc ? (N >> 4) : ((3 * N) >> 4);
    const int worker = sc ? (int)blockIdx.x : ((int)blockIdx.x - nsc);
    const int nworkers = sc ? nsc : 3 * nsc;

    f16x8_t B[20];
    preload_W(W, c0, q, mm, B);

    int tile = worker;
    if (tile >= ntiles) return;
    f16x8_t cxlo, cxhi;
    f32x4_t czq[ZDIM];
    {
        const int r = (tile << 4) + mm;
        cxlo = *(const f16x8_t*)(Xsel + ((size_t)r << 6) + (q << 3));
        cxhi = *(const f16x8_t*)(Xsel + ((size_t)r << 6) + 32 + (q << 3));
        const int rb4 = (tile << 4) + (q << 2);
#pragma unroll
        for (int v = 0; v < ZDIM; ++v)
            czq[v] = *(const f32x4_t*)(ztb + (size_t)v * zsr + rb4);
    }

    for (; tile < ntiles; tile += nworkers) {
        // ---- phase 1: issue ALL of next tile's loads ----
        const int nt = tile + nworkers;
        f16x8_t nxlo = cxlo, nxhi = cxhi;
        f32x4_t nzq[ZDIM];
#pragma unroll
        for (int v = 0; v < ZDIM; ++v) nzq[v] = czq[v];
        if (nt < ntiles) {
            const int r = (nt << 4) + mm;
            nxlo = *(const f16x8_t*)(Xsel + ((size_t)r << 6) + (q << 3));
            nxhi = *(const f16x8_t*)(Xsel + ((size_t)r << 6) + 32 + (q << 3));
            const int nrb4 = (nt << 4) + (q << 2);
#pragma unroll
            for (int v = 0; v < ZDIM; ++v)
                nzq[v] = *(const f32x4_t*)(ztb + (size_t)v * zsr + nrb4);
        }
        __builtin_amdgcn_sched_barrier(0);   // pin loads above compute

        // ---- phase 2: register-only compute on current tile ----
        const int rb4 = (tile << 4) + (q << 2);
        f32x4_t acc = {0.f, 0.f, 0.f, 0.f};
#pragma unroll
        for (int v = 0; v < ZDIM; ++v) {
            f32x4_t t = {0.f, 0.f, 0.f, 0.f};
            t = __builtin_amdgcn_mfma_f32_16x16x32_f16(cxlo, B[2 * v], t, 0, 0, 0);
            t = __builtin_amdgcn_mfma_f32_16x16x32_f16(cxhi, B[2 * v + 1], t, 0, 0, 0);
#pragma unroll
            for (int reg = 0; reg < 4; ++reg)
                acc[reg] = fmaf(czq[v][reg], t[reg], acc[reg]);
        }

        // ---- phase 3: stores ----
        const int w = c0 + mm;
#pragma unroll
        for (int reg = 0; reg < 4; ++reg) {
            const int ro = rb4 + reg;
            if (sc) {
                out[(size_t)ro * FEATD + w] = acc[reg];               // s, scalar part
            } else {
                const unsigned nn = (unsigned)ro / 3u;
                const int k = ro - 3 * (int)nn;
                out[(size_t)nn * FEATD + MULT + w * 3 + k] = acc[reg]; // s, vec part
            }
        }
        cxlo = nxlo; cxhi = nxhi;
#pragma unroll
        for (int v = 0; v < ZDIM; ++v) czq[v] = nzq[v];
    }
}

// pass 2: xl = fctp(x, z, Wl1) staged as f16 GEMM rows xls / xlv
__global__ __launch_bounds__(256, 2) void fctp_pass_xl(
    const f16_t* __restrict__ Xs, const f16_t* __restrict__ Xv,
    const float* __restrict__ zt, const float* __restrict__ ztv,
    const float* __restrict__ Wl10, const float* __restrict__ Wl11,
    f16_t* __restrict__ xls, f16_t* __restrict__ xlv, int N, int nsc)
{
    const int lane = threadIdx.x & 63;
    const int wave = threadIdx.x >> 6;
    const int c0 = wave << 4;
    const int q = lane >> 4;
    const int mm = lane & 15;
    const bool sc = (int)blockIdx.x < nsc;
    const float* W = sc ? Wl10 : Wl11;
    const f16_t* Xsel = sc ? Xs : Xv;
    const float* ztb = sc ? zt : ztv;
    const size_t zsr = sc ? (size_t)N : (size_t)3 * N;
    const int ntiles = sc ? (N >> 4) : ((3 * N) >> 4);
    const int worker = sc ? (int)blockIdx.x : ((int)blockIdx.x - nsc);
    const int nworkers = sc ? nsc : 3 * nsc;

    f16x8_t B[20];
    preload_W(W, c0, q, mm, B);

    f16_t* Osel = sc ? xls : xlv;

    int tile = worker;
    if (tile >= ntiles) return;
    f16x8_t cxlo, cxhi;
    f32x4_t czq[ZDIM];
    {
        const int r = (tile << 4) + mm;
        cxlo = *(const f16x8_t*)(Xsel + ((size_t)r << 6) + (q << 3));
        cxhi = *(const f16x8_t*)(Xsel + ((size_t)r << 6) + 32 + (q << 3));
        const int rb4 = (tile << 4) + (q << 2);
#pragma unroll
        for (int v = 0; v < ZDIM; ++v)
            czq[v] = *(const f32x4_t*)(ztb + (size_t)v * zsr + rb4);
    }

    for (; tile < ntiles; tile += nworkers) {
        // ---- phase 1: issue ALL of next tile's loads ----
        const int nt = tile + nworkers;
        f16x8_t nxlo = cxlo, nxhi = cxhi;
        f32x4_t nzq[ZDIM];
#pragma unroll
        for (int v = 0; v < ZDIM; ++v) nzq[v] = czq[v];
        if (nt < ntiles) {
            const int r = (nt << 4) + mm;
            nxlo = *(const f16x8_t*)(Xsel + ((size_t)r << 6) + (q << 3));
            nxhi = *(const f16x8_t*)(Xsel + ((size_t)r << 6) + 32 + (q << 3));
            const int nrb4 = (nt << 4) + (q << 2);
#pragma unroll
            for (int v = 0; v < ZDIM; ++v)
                nzq[v] = *(const f32x4_t*)(ztb + (size_t)v * zsr + nrb4);
        }
        __builtin_amdgcn_sched_barrier(0);   // pin loads above compute

        // ---- phase 2: register-only compute on current tile ----
        const int rb4 = (tile << 4) + (q << 2);
        f32x4_t acc = {0.f, 0.f, 0.f, 0.f};
#pragma unroll
        for (int v = 0; v < ZDIM; ++v) {
            f32x4_t t = {0.f, 0.f, 0.f, 0.f};
            t = __builtin_amdgcn_mfma_f32_16x16x32_f16(cxlo, B[2 * v], t, 0, 0, 0);
            t = __builtin_amdgcn_mfma_f32_16x16x32_f16(cxhi, B[2 * v + 1], t, 0, 0, 0);
#pragma unroll
            for (int reg = 0; reg < 4; ++reg)
                acc[reg] = fmaf(czq[v][reg], t[reg], acc[reg]);
        }

        // ---- phase 3: stores ----
        const int w = c0 + mm;
#pragma unroll
        for (int reg = 0; reg < 4; ++reg) {
            const int ro = rb4 + reg;
            Osel[((size_t)ro << 6) + w] = (f16_t)acc[reg];
        }
        cxlo = nxlo; cxhi = nxhi;
#pragma unroll
        for (int v = 0; v < ZDIM; ++v) czq[v] = nzq[v];
    }
}

// stage C: reads f16 agg rows (aggsh/aggvh via aggcvt), RMW on out.
__global__ __launch_bounds__(256, 2) void fctp_stageC_mfma(
    const f16_t* __restrict__ aggsh, const f16_t* __restrict__ aggvh,
    const float* __restrict__ zt, const float* __restrict__ ztv,
    const float* __restrict__ Wl20, const float* __restrict__ Wl21,
    float* __restrict__ out, int N, int nsc)
{
    const int lane = threadIdx.x & 63;
    const int wave = threadIdx.x >> 6;
    const int c0 = wave << 4;
    const int q = lane >> 4;
    const int mm = lane & 15;
    const bool sc = (int)blockIdx.x < nsc;
    const float* W = sc ? Wl20 : Wl21;
    const f16_t* Asel = sc ? aggsh : aggvh;
    const float* ztb = sc ? zt : ztv;
    const size_t zsr = sc ? (size_t)N : (size_t)3 * N;
    const int ntiles = sc ? (N >> 4) : ((3 * N) >> 4);
    const int worker = sc ? (int)blockIdx.x : ((int)blockIdx.x - nsc);
    const int nworkers = sc ? nsc : 3 * nsc;

    f16x8_t B[20];
    preload_W(W, c0, q, mm, B);

    int tile = worker;
    if (tile >= ntiles) return;
    f16x8_t cxlo, cxhi;
    f32x4_t czq[ZDIM];
    {
        const int r = (tile << 4) + mm;
        cxlo = *(const f16x8_t*)(Asel + ((size_t)r << 6) + (q << 3));
        cxhi = *(const f16x8_t*)(Asel + ((size_t)r << 6) + 32 + (q << 3));
        const int rb4 = (tile << 4) + (q << 2);
#pragma unroll
        for (int v = 0; v < ZDIM; ++v)
            czq[v] = *(const f32x4_t*)(ztb + (size_t)v * zsr + rb4);
    }

    for (; tile < ntiles; tile += nworkers) {
        // ---- phase 1: next tile's A+zq loads, and CURRENT out-old loads ----
        const int nt = tile + nworkers;
        f16x8_t nxlo = cxlo, nxhi = cxhi;
        f32x4_t nzq[ZDIM];
#pragma unroll
        for (int v = 0; v < ZDIM; ++v) nzq[v] = czq[v];
        if (nt < ntiles) {
            const int r = (nt << 4) + mm;
            nxlo = *(const f16x8_t*)(Asel + ((size_t)r << 6) + (q << 3));
            nxhi = *(const f16x8_t*)(Asel + ((size_t)r << 6) + 32 + (q << 3));
            const int nrb4 = (nt << 4) + (q << 2);
#pragma unroll
            for (int v = 0; v < ZDIM; ++v)
                nzq[v] = *(const f32x4_t*)(ztb + (size_t)v * zsr + nrb4);
        }
        const int rb4 = (tile << 4) + (q << 2);
        const int w = c0 + mm;
        size_t oidx[4];
        float oold[4];
#pragma unroll
        for (int reg = 0; reg < 4; ++reg) {
            const int ro = rb4 + reg;
            if (sc) {
                oidx[reg] = (size_t)ro * FEATD + w;
            } else {
                const unsigned nn = (unsigned)ro / 3u;
                const int k = ro - 3 * (int)nn;
                oidx[reg] = (size_t)nn * FEATD + MULT + w * 3 + k;
            }
            oold[reg] = out[oidx[reg]];
        }
        __builtin_amdgcn_sched_barrier(0);   // pin loads above compute

        // ---- phase 2: register-only compute ----
        f32x4_t acc = {0.f, 0.f, 0.f, 0.f};
#pragma unroll
        for (int v = 0; v < ZDIM; ++v) {
            f32x4_t t = {0.f, 0.f, 0.f, 0.f};
            t = __builtin_amdgcn_mfma_f32_16x16x32_f16(cxlo, B[2 * v], t, 0, 0, 0);
            t = __builtin_amdgcn_mfma_f32_16x16x32_f16(cxhi, B[2 * v + 1], t, 0, 0, 0);
#pragma unroll
            for (int reg = 0; reg < 4; ++reg)
                acc[reg] = fmaf(czq[v][reg], t[reg], acc[reg]);
        }

        // ---- phase 3: stores ----
#pragma unroll
        for (int reg = 0; reg < 4; ++reg)
            out[oidx[reg]] = oold[reg] + acc[reg] * 0.1f;   // s staged by pass_out; /10 here

        cxlo = nxlo; cxhi = nxhi;
#pragma unroll
        for (int v = 0; v < ZDIM; ++v) czq[v] = nzq[v];
    }
}

// ---------------------------------------------------------------------------
// Counting sort of edges by dst (unchanged). scatter emits perm, sperm
// (permuted src) and eattr_p (permuted edge_attr).
// ---------------------------------------------------------------------------
__global__ __launch_bounds__(256) void hist_kernel(
    const int* __restrict__ edst, int* __restrict__ cnt, int E)
{
    int e = blockIdx.x * 256 + threadIdx.x;
    if (e >= E) return;
    atomicAdd(&cnt[edst[e]], 1);
}

__global__ __launch_bounds__(1024) void scan_block(
    const int* __restrict__ cnt, int* __restrict__ off,
    int* __restrict__ bsum, int N)
{
    __shared__ int sh[1024];
    int tid = threadIdx.x;
    int i = blockIdx.x * 1024 + tid;
    int v = (i < N) ? cnt[i] : 0;
    sh[tid] = v;
    __syncthreads();
#pragma unroll
    for (int d = 1; d < 1024; d <<= 1) {
        int t = (tid >= d) ? sh[tid - d] : 0;
        __syncthreads();
        sh[tid] += t;
        __syncthreads();
    }
    if (i < N) off[i + 1] = sh[tid];
    if (tid == 1023) bsum[blockIdx.x] = sh[1023];
    if (i == 0) off[0] = 0;
}

__global__ __launch_bounds__(64) void scan_sums(int* __restrict__ bsum, int nb)
{
    int tid = threadIdx.x;
    int v = (tid < nb) ? bsum[tid] : 0;
#pragma unroll
    for (int d = 1; d < 64; d <<= 1) {
        int t = __shfl_up(v, d, 64);
        if (tid >= d) v += t;
    }
    int ex = __shfl_up(v, 1, 64);
    if (tid == 0) ex = 0;
    if (tid < nb) bsum[tid] = ex;
}

__global__ __launch_bounds__(1024) void scan_add(
    int* __restrict__ off, const int* __restrict__ bsum, int N)
{
    int i = blockIdx.x * 1024 + threadIdx.x;
    if (i < N) off[i + 1] += bsum[blockIdx.x];
}

__global__ __launch_bounds__(256) void scatter_kernel(
    const int* __restrict__ edst, const int* __restrict__ esrc,
    const float* __restrict__ eattr, const int* __restrict__ off,
    int* __restrict__ cursor, int* __restrict__ perm,
    int* __restrict__ sperm, float* __restrict__ eattr_p, int E)
{
    int e = blockIdx.x * 256 + threadIdx.x;
    if (e >= E) return;
    int d = edst[e];
    int pos = off[d] + atomicAdd(&cursor[d], 1);
    perm[pos] = e;
    sperm[pos] = esrc[e];
    float4 at = *(const float4*)(eattr + (size_t)e * 4);
    *(float4*)(eattr_p + (size_t)pos * 4) = at;
}

// ---------------------------------------------------------------------------
// aggregate6: FUSED wgemm + aggregate. One wave per node. Per 16-edge group:
// gather elem rows -> 16 MFMAs vs persistent tpwt B-frags -> w-tile staged in
// LDS (8KB/wave, wave-synchronous: per-wave in-order LDS pipeline + compiler
// aliasing keeps write->read ordered; NO __syncthreads — waves have different
// trip counts). Per edge: 8B LDS wq read + eattr + xl gathers (depth-2
// prefetch) -> ~14-FMA TP -> register accumulate. Replaces the 512 MB
// wbuf HBM round-trip (round-7 arithmetic: ~81 us at BW ceiling) and the
// aggs/aggv memset (each node written exactly once with '=').
// w-tile layout check (same mapping as old wgemm store): component j of
// feature u lives in D[j*4+t][reg], t=u>>4, col=s*16+mm, row=q*4+reg=edge
// offset in group. t-chunked so only 4 f32x4 D regs live at once.
// ---------------------------------------------------------------------------
__global__ __launch_bounds__(256, 3) void aggregate6(
    const int* __restrict__ off, const int* __restrict__ sperm,
    const int* __restrict__ perm, const float* __restrict__ elem,
    const f16_t* __restrict__ tpwt, const float* __restrict__ eattr_p,
    const f16_t* __restrict__ xls, const f16_t* __restrict__ xlv,
    float* __restrict__ aggs, float* __restrict__ aggv, int N)
{
    __shared__ f16_t wtile[4][16 * 256];     // 4 waves x 8KB
    int n = (blockIdx.x * 256 + threadIdx.x) >> 6;      // one wave per node
    if (n >= N) return;
    const int u = threadIdx.x & 63;
    const int wid = threadIdx.x >> 6;
    const int mm = u & 15, q = u >> 4;
    f16_t* wt = &wtile[wid][0];

    // persistent B-frags: stripe s covers cols s*16+mm, k = q*8+j
    f16x8_t B[16];
#pragma unroll
    for (int s = 0; s < 16; ++s)
        B[s] = *(const f16x8_t*)(tpwt + ((size_t)(s * 16 + mm)) * 32 + q * 8);

    int cs0 = __builtin_amdgcn_readfirstlane(off[n]);
    int cs1 = __builtin_amdgcn_readfirstlane(off[n + 1]);

    float accx = 0.f, accy = 0.f, accz = 0.f, accw = 0.f;

    if (cs0 < cs1) {
        const int last = cs1 - 1;

        // depth-2 prefetch slots for the xl gather (the HBM/L3-latency item)
        int sa = __builtin_amdgcn_readfirstlane(sperm[cs0]);
        float a_xs = (float)xls[((size_t)sa << 6) + u];
        float a_v0 = (float)xlv[((size_t)(3 * sa + 0) << 6) + u];
        float a_v1 = (float)xlv[((size_t)(3 * sa + 1) << 6) + u];
        float a_v2 = (float)xlv[((size_t)(3 * sa + 2) << 6) + u];
        int ib = (cs0 + 1 <= last) ? cs0 + 1 : last;
        int sb = __builtin_amdgcn_readfirstlane(sperm[ib]);
        float b_xs = (float)xls[((size_t)sb << 6) + u];
        float b_v0 = (float)xlv[((size_t)(3 * sb + 0) << 6) + u];
        float b_v1 = (float)xlv[((size_t)(3 * sb + 1) << 6) + u];
        float b_v2 = (float)xlv[((size_t)(3 * sb + 2) << 6) + u];

        int i = cs0;
        for (int g = cs0; g < cs1; g += 16) {
            const int gend = (g + 16 < cs1) ? g + 16 : cs1;

            // ---- w-tile phase: elem gather + 16 MFMA + LDS stage ----
            int pos = g + mm; if (pos > last) pos = last;   // pad w/ last edge
            int e = perm[pos];
            const float* er = elem + ((size_t)e << 5) + q * 8;
            float4 ea = *(const float4*)er;
            float4 eb = *(const float4*)(er + 4);
            f16x8_t A;
            A[0] = (f16_t)ea.x; A[1] = (f16_t)ea.y; A[2] = (f16_t)ea.z; A[3] = (f16_t)ea.w;
            A[4] = (f16_t)eb.x; A[5] = (f16_t)eb.y; A[6] = (f16_t)eb.z; A[7] = (f16_t)eb.w;

#pragma unroll
            for (int t = 0; t < 4; ++t) {
                f32x4_t D0 = {0.f, 0.f, 0.f, 0.f}, D1 = {0.f, 0.f, 0.f, 0.f};
                f32x4_t D2 = {0.f, 0.f, 0.f, 0.f}, D3 = {0.f, 0.f, 0.f, 0.f};
                D0 = __builtin_amdgcn_mfma_f32_16x16x32_f16(A, B[t],      D0, 0, 0, 0);
                D1 = __builtin_amdgcn_mfma_f32_16x16x32_f16(A, B[4 + t],  D1, 0, 0, 0);
                D2 = __builtin_amdgcn_mfma_f32_16x16x32_f16(A, B[8 + t],  D2, 0, 0, 0);
                D3 = __builtin_amdgcn_mfma_f32_16x16x32_f16(A, B[12 + t], D3, 0, 0, 0);
#pragma unroll
                for (int reg = 0; reg < 4; ++reg) {
                    const int row = (q << 2) + reg;          // edge offset in group
                    f16x4_t wq;
                    wq[0] = (f16_t)D0[reg];   // w1 (col u)
                    wq[1] = (f16_t)D1[reg];   // w2 (col 64+u)
                    wq[2] = (f16_t)D2[reg];   // w3 (col 128+u)
                    wq[3] = (f16_t)D3[reg];   // w4 (col 192+u, ISQ3 baked in tpwt)
                    *(f16x4_t*)(wt + ((size_t)(row * 64 + (t * 16 + mm)) << 2)) = wq;
                }
            }

            // ---- aggregate edges [i, gend), a/b slot rotation ----
            while (i < gend) {
                {   // consume a (edge i)
                    f16x4_t wq = *(const f16x4_t*)(wt + ((size_t)((i - g) * 64 + u) << 2));
                    float w1 = (float)wq[0], w2 = (float)wq[1], w3 = (float)wq[2], w4 = (float)wq[3];
                    float4 at = *(const float4*)(eattr_p + ((size_t)i << 2));
                    float dot3 = a_v0 * at.y + a_v1 * at.z + a_v2 * at.w;
                    accx = fmaf(w1 * a_xs, at.x, accx);
                    accx = fmaf(w4, dot3, accx);
                    float w2x = w2 * a_xs;
                    accy = fmaf(w2x, at.y, accy);
                    accz = fmaf(w2x, at.z, accz);
                    accw = fmaf(w2x, at.w, accw);
                    float w3s = w3 * at.x;
                    accy = fmaf(w3s, a_v0, accy);
                    accz = fmaf(w3s, a_v1, accz);
                    accw = fmaf(w3s, a_v2, accw);
                }
                {   // refill a with edge i+2 (clamped; crosses groups freely)
                    int inx = (i + 2 <= last) ? i + 2 : last;
                    int sn = __builtin_amdgcn_readfirstlane(sperm[inx]);
                    a_xs = (float)xls[((size_t)sn << 6) + u];
                    a_v0 = (float)xlv[((size_t)(3 * sn + 0) << 6) + u];
                    a_v1 = (float)xlv[((size_t)(3 * sn + 1) << 6) + u];
                    a_v2 = (float)xlv[((size_t)(3 * sn + 2) << 6) + u];
                }
                if (++i >= gend) break;
                {   // consume b (edge i)
                    f16x4_t wq = *(const f16x4_t*)(wt + ((size_t)((i - g) * 64 + u) << 2));
                    float w1 = (float)wq[0], w2 = (float)wq[1], w3 = (float)wq[2], w4 = (float)wq[3];
                    float4 at = *(const float4*)(eattr_p + ((size_t)i << 2));
                    float dot3 = b_v0 * at.y + b_v1 * at.z + b_v2 * at.w;
                    accx = fmaf(w1 * b_xs, at.x, accx);
                    accx = fmaf(w4, dot3, accx);
                    float w2x = w2 * b_xs;
                    accy = fmaf(w2x, at.y, accy);
                    accz = fmaf(w2x, at.z, accz);
                    accw = fmaf(w2x, at.w, accw);
                    float w3s = w3 * at.x;
                    accy = fmaf(w3s, b_v0, accy);
                    accz = fmaf(w3s, b_v1, accz);
                    accw = fmaf(w3s, b_v2, accw);
                }
                {   // refill b with edge i+2
                    int inx = (i + 2 <= last) ? i + 2 : last;
                    int sn = __builtin_amdgcn_readfirstlane(sperm[inx]);
                    b_xs = (float)xls[((size_t)sn << 6) + u];
                    b_v0 = (float)xlv[((size_t)(3 * sn + 0) << 6) + u];
                    b_v1 = (float)xlv[((size_t)(3 * sn + 1) << 6) + u];
                    b_v2 = (float)xlv[((size_t)(3 * sn + 2) << 6) + u];
                }
                ++i;
            }
        }
    }

    // single owner per node: plain store (replaces memset + '+=')
    aggs[((size_t)n << 6) + u] = accx;
    aggv[((size_t)(3 * n + 0) << 6) + u] = accy;
    aggv[((size_t)(3 * n + 1) << 6) + u] = accz;
    aggv[((size_t)(3 * n + 2) << 6) + u] = accw;
}

// ---------------------------------------------------------------------------
extern "C" void kernel_launch(void* const* d_in, const int* in_sizes, int n_in,
                              void* d_out, int out_size, void* d_ws, size_t ws_size,
                              hipStream_t stream)
{
    const float* x     = (const float*)d_in[0];
    const float* z     = (const float*)d_in[1];
    const int*   esrc  = (const int*)d_in[2];
    const int*   edst  = (const int*)d_in[3];
    const float* elem  = (const float*)d_in[4];
    const float* eattr = (const float*)d_in[5];
    const float* Wsi0  = (const float*)d_in[6];
    const float* Wsi1  = (const float*)d_in[7];
    const float* Wl10  = (const float*)d_in[8];
    const float* Wl11  = (const float*)d_in[9];
    const float* Wl20  = (const float*)d_in[10];
    const float* Wl21  = (const float*)d_in[11];
    const float* tpw   = (const float*)d_in[12];
    float* out = (float*)d_out;

    const int N = in_sizes[1] / ZDIM;      // 50000
    const int E = in_sizes[2];             // 500000
    const int Ehalf = E / 2;               // 250000 (layout constant, kept)

    // workspace carve-up (layout kept from round 7; wbuf no longer used but
    // region R keeps its size so downstream offsets are unchanged):
    f16_t* xls  = (f16_t*)d_ws;                          // N*64   f16
    f16_t* xlv  = xls + (size_t)N * 64;                  // 3N*64  f16
    float* aggs = (float*)(xlv + (size_t)3 * N * 64);    // N*64   f32
    float* aggv = aggs + (size_t)N * 64;                 // 3N*64  f32
    // region R: union of {Xs,Xv} (dead after fctp passes) and aggh (f16 agg)
    char*  R    = (char*)(aggv + (size_t)3 * N * 64);
    f16_t* Xs   = (f16_t*)R;                             // N*64   f16
    f16_t* Xv   = Xs + (size_t)N * 64;                   // 3N*64  f16
    f16_t* aggh = (f16_t*)R;                             // 4N*64 f16 (25.6 MB)
    size_t Rbytes = (size_t)Ehalf * 256 * sizeof(f16_t); // 128 MB (kept)
    float* eattr_p = (float*)(R + Rbytes);               // E*4 f32
    int*   sperm   = (int*)(eattr_p + (size_t)E * 4);    // E
    int*   perm    = sperm + E;                          // E
    int*   cnt     = perm + E;                           // N
    int*   cursor  = cnt + N;                            // N
    int*   off     = cursor + N;                         // N+1
    int*   bsum    = off + (N + 1);                      // 64
    // z transposes, 256B-aligned for float4 loads: zt (10N) + ztv (30N) f32
    size_t zoff = (((size_t)(bsum + 64) - (size_t)d_ws) + 255) & ~(size_t)255;
    float* zt  = (float*)((char*)d_ws + zoff);           // 10N f32 (2 MB)
    float* ztv = zt + (size_t)10 * N;                    // 30N f32 (6 MB)
    f16_t* tpwt = (f16_t*)(ztv + (size_t)30 * N);        // 256*32 f16 (16 KB)

    const int SCAN_B = 1024;
    int nb = (N + SCAN_B - 1) / SCAN_B;  // 49 (<=64 required by scan_sums)

    hipMemsetAsync(cnt, 0, 2 * (size_t)N * sizeof(int), stream);   // cnt+cursor
    // NOTE: no aggs/aggv memset — aggregate6 writes every node exactly once.

    int g0 = (N * MULT + 255) / 256;
    hipLaunchKernelGGL(transform_x2, dim3(g0), dim3(256), 0, stream, x, Xs, Xv, N);
    int gz = (N + 255) / 256;
    hipLaunchKernelGGL(zprep_kernel, dim3(gz), dim3(256), 0, stream, z, zt, ztv, N);
    hipLaunchKernelGGL(tpwprep_kernel, dim3(32), dim3(256), 0, stream, tpw, tpwt);

    // stageA split: two single-W passes at (256,2) -> B[20] fits, no spill
    hipLaunchKernelGGL(fctp_pass_xl, dim3(512), dim3(256), 0, stream,
                       Xs, Xv, zt, ztv, Wl10, Wl11, xls, xlv, N, 128);
    hipLaunchKernelGGL(fctp_pass_out, dim3(512), dim3(256), 0, stream,
                       Xs, Xv, zt, ztv, Wsi0, Wsi1, out, N, 128);

    int geh = (E + 255) / 256;
    hipLaunchKernelGGL(hist_kernel, dim3(geh), dim3(256), 0, stream,
                       edst, cnt, E);
    hipLaunchKernelGGL(scan_block, dim3(nb), dim3(SCAN_B), 0, stream,
                       cnt, off, bsum, N);
    hipLaunchKernelGGL(scan_sums, dim3(1), dim3(64), 0, stream, bsum, nb);
    hipLaunchKernelGGL(scan_add, dim3(nb), dim3(SCAN_B), 0, stream,
                       off, bsum, N);
    hipLaunchKernelGGL(scatter_kernel, dim3(geh), dim3(256), 0, stream,
                       edst, esrc, eattr, off, cursor, perm, sperm, eattr_p, E);

    // fused w-gemm + aggregate: single pass over all edges, w staged in LDS
    int ga = (N * 64 + 255) / 256;
    hipLaunchKernelGGL(aggregate6, dim3(ga), dim3(256), 0, stream,
                       off, sperm, perm, elem, tpwt, eattr_p, xls, xlv,
                       aggs, aggv, N);

    // agg f32 -> f16 (aggh aliases R; Xs/Xv dead), then stage C
    int n4 = N * 64;                           // (4N*64)/4 float4 groups
    int gc = (n4 + 255) / 256;
    hipLaunchKernelGGL(aggcvt_kernel, dim3(gc), dim3(256), 0, stream,
                       aggs, aggh, n4);
    hipLaunchKernelGGL(fctp_stageC_mfma, dim3(512), dim3(256), 0, stream,
                       aggh, aggh + (size_t)N * 64, zt, ztv, Wl20, Wl21,
                       out, N, 128);
}

// Round 9
// 505.806 us; speedup vs baseline: 1.6027x; 1.0057x over previous
//
#include <hip/hip_runtime.h>

// Problem constants (from reference)
#define MULT 64
#define FEATD 256
#define ZDIM 10

#define INV640f 0.03952847075210474f   // 1/sqrt(640)
#define ISQ2f   0.7071067811865476f    // 1/sqrt(2)
#define ISQ3f   0.5773502691896258f    // 1/sqrt(3)

typedef _Float16 f16_t;
typedef f16_t f16x8_t __attribute__((ext_vector_type(8)));
typedef f16_t f16x4_t __attribute__((ext_vector_type(4)));
typedef float f32x4_t __attribute__((ext_vector_type(4)));

// ---------------------------------------------------------------------------
// K0: transform x (n,256 natural: [x0(64) | x1(64,3)]) into f16 GEMM rows:
//   Xs[n*64 + u]        = x0[n,u]        (N x 64)
//   Xv[(3n+k)*64 + u]   = x1[n,u,k]      (3N x 64)
// ---------------------------------------------------------------------------
__global__ __launch_bounds__(256) void transform_x2(
    const float* __restrict__ x, f16_t* __restrict__ Xs,
    f16_t* __restrict__ Xv, int N)
{
    int idx = blockIdx.x * 256 + threadIdx.x;     // over N*64 (n,u) pairs
    if (idx >= N * MULT) return;
    int n = idx >> 6;
    int u = idx & 63;
    const float* row = x + (size_t)n * FEATD;
    Xs[idx] = (f16_t)row[u];
    const float* x1p = row + MULT + u * 3;
    Xv[((size_t)3 * n + 0) * MULT + u] = (f16_t)x1p[0];
    Xv[((size_t)3 * n + 1) * MULT + u] = (f16_t)x1p[1];
    Xv[((size_t)3 * n + 2) * MULT + u] = (f16_t)x1p[2];
}

// ---------------------------------------------------------------------------
// zprep: transpose z with INV640 folded in, in two layouts:
//   zt [v*N + n]   = z[n,v]*INV640       (scalar-block GEMM rows, N rows)
//   ztv[v*3N + r]  = z[r/3,v]*INV640     (row-expanded for vector rows, 3N)
// ---------------------------------------------------------------------------
__global__ __launch_bounds__(256) void zprep_kernel(
    const float* __restrict__ z, float* __restrict__ zt,
    float* __restrict__ ztv, int N)
{
    int n = blockIdx.x * 256 + threadIdx.x;
    if (n >= N) return;
    const float* zr = z + (size_t)n * ZDIM;
#pragma unroll
    for (int v = 0; v < ZDIM; ++v) {
        float val = zr[v] * INV640f;
        zt[(size_t)v * N + n] = val;
        float* p = ztv + (size_t)v * 3 * N + 3 * (size_t)n;
        p[0] = val; p[1] = val; p[2] = val;
    }
}

// ---------------------------------------------------------------------------
// tpwprep: tpwt[c*32 + k] = tpw[k*256 + c] * scale(c), f16  (scales baked in)
// ---------------------------------------------------------------------------
__global__ __launch_bounds__(256) void tpwprep_kernel(
    const float* __restrict__ tpw, f16_t* __restrict__ tpwt)
{
    int idx = blockIdx.x * 256 + threadIdx.x;    // 256*32 entries
    if (idx >= 256 * 32) return;
    int c = idx >> 5, k = idx & 31;
    float s = (c < 192) ? ISQ2f : (ISQ2f * ISQ3f);
    tpwt[(size_t)c * 32 + k] = (f16_t)(tpw[(size_t)k * 256 + c] * s);
}

// ---------------------------------------------------------------------------
// aggcvt: agg f32 -> f16 (stageC converts to f16 for MFMA anyway; this is
// numerically identical and halves stageC's A-traffic + register footprint).
// ---------------------------------------------------------------------------
__global__ __launch_bounds__(256) void aggcvt_kernel(
    const float* __restrict__ a, f16_t* __restrict__ h, int n4)
{
    int i = blockIdx.x * 256 + threadIdx.x;      // one float4 per thread
    if (i >= n4) return;
    float4 v = *(const float4*)(a + (size_t)i * 4);
    f16x4_t o;
    o[0] = (f16_t)v.x; o[1] = (f16_t)v.y; o[2] = (f16_t)v.z; o[3] = (f16_t)v.w;
    *(f16x4_t*)(h + (size_t)i * 4) = o;
}

// ---------------------------------------------------------------------------
// MFMA fctp kernels (f16). GEMM form: o[r,w] = sum_v z[r,v] * sum_u x[r,u]W[u,v,w].
// Per v: 2 MFMAs (K=64) with RAW x fragments, z folded on f32 accumulators.
// REGISTER BUDGET: B[20]=80 AGPR-side regs; (256,2) REQUIRED (round-2: (256,4)
// caps at 128 and spills B, FETCH 55->416MB).
// SCHEDULE (round-5/7 lesson, VERIFIED): 2-deep rotation of ALL per-tile loads
// (A-rows AND zqa) + ONE sched_barrier(0) per iteration. stageC 119->62us,
// 1.0->1.7 TB/s.
// 16x16x32 layouts: A [m=lane&15][k=q*8+j], B [k=q*8+j][n=lane&15],
// C/D col=lane&15, row=q*4+reg  (m89/m91-verified).
// ---------------------------------------------------------------------------
__device__ __forceinline__ void preload_W(
    const float* __restrict__ W, int c0, int q, int mm, f16x8_t (&B)[20])
{
    const int col = c0 + mm;
#pragma unroll
    for (int ks = 0; ks < 20; ++ks) {
        const int v = ks >> 1;
        const int ub = ((ks & 1) << 5) + (q << 3);
        const int base = v * 64 + col;
#pragma unroll
        for (int j = 0; j < 8; ++j)
            B[ks][j] = (f16_t)W[(ub + j) * 640 + base];   // W[u][v][w]
    }
}

// pass 1: s = fctp(x, z, Wsi) staged into out (natural layout)
__global__ __launch_bounds__(256, 2) void fctp_pass_out(
    const f16_t* __restrict__ Xs, const f16_t* __restrict__ Xv,
    const float* __restrict__ zt, const float* __restrict__ ztv,
    const float* __restrict__ Wsi0, const float* __restrict__ Wsi1,
    float* __restrict__ out, int N, int nsc)
{
    const int lane = threadIdx.x & 63;
    const int wave = threadIdx.x >> 6;
    const int c0 = wave << 4;            // 16-col stripe per wave
    const int q = lane >> 4;
    const int mm = lane & 15;
    const bool sc = (int)blockIdx.x < nsc;
    const float* W = sc ? Wsi0 : Wsi1;
    const f16_t* Xsel = sc ? Xs : Xv;
    const float* ztb = sc ? zt : ztv;
    const size_t zsr = sc ? (size_t)N : (size_t)3 * N;
    const int ntiles = sc ? (N >> 4) : ((3 * N) >> 4);
    const int worker = sc ? (int)blockIdx.x : ((int)blockIdx.x - nsc);
    const int nworkers = sc ? nsc : 3 * nsc;

    f16x8_t B[20];
    preload_W(W, c0, q, mm, B);

    int tile = worker;
    if (tile >= ntiles) return;
    f16x8_t cxlo, cxhi;
    f32x4_t czq[ZDIM];
    {
        const int r = (tile << 4) + mm;
        cxlo = *(const f16x8_t*)(Xsel + ((size_t)r << 6) + (q << 3));
        cxhi = *(const f16x8_t*)(Xsel + ((size_t)r << 6) + 32 + (q << 3));
        const int rb4 = (tile << 4) + (q << 2);
#pragma unroll
        for (int v = 0; v < ZDIM; ++v)
            czq[v] = *(const f32x4_t*)(ztb + (size_t)v * zsr + rb4);
    }

    for (; tile < ntiles; tile += nworkers) {
        // ---- phase 1: issue ALL of next tile's loads ----
        const int nt = tile + nworkers;
        f16x8_t nxlo = cxlo, nxhi = cxhi;
        f32x4_t nzq[ZDIM];
#pragma unroll
        for (int v = 0; v < ZDIM; ++v) nzq[v] = czq[v];
        if (nt < ntiles) {
            const int r = (nt << 4) + mm;
            nxlo = *(const f16x8_t*)(Xsel + ((size_t)r << 6) + (q << 3));
            nxhi = *(const f16x8_t*)(Xsel + ((size_t)r << 6) + 32 + (q << 3));
            const int nrb4 = (nt << 4) + (q << 2);
#pragma unroll
            for (int v = 0; v < ZDIM; ++v)
                nzq[v] = *(const f32x4_t*)(ztb + (size_t)v * zsr + nrb4);
        }
        __builtin_amdgcn_sched_barrier(0);   // pin loads above compute

        // ---- phase 2: register-only compute on current tile ----
        const int rb4 = (tile << 4) + (q << 2);
        f32x4_t acc = {0.f, 0.f, 0.f, 0.f};
#pragma unroll
        for (int v = 0; v < ZDIM; ++v) {
            f32x4_t t = {0.f, 0.f, 0.f, 0.f};
            t = __builtin_amdgcn_mfma_f32_16x16x32_f16(cxlo, B[2 * v], t, 0, 0, 0);
            t = __builtin_amdgcn_mfma_f32_16x16x32_f16(cxhi, B[2 * v + 1], t, 0, 0, 0);
#pragma unroll
            for (int reg = 0; reg < 4; ++reg)
                acc[reg] = fmaf(czq[v][reg], t[reg], acc[reg]);
        }

        // ---- phase 3: stores ----
        const int w = c0 + mm;
#pragma unroll
        for (int reg = 0; reg < 4; ++reg) {
            const int ro = rb4 + reg;
            if (sc) {
                out[(size_t)ro * FEATD + w] = acc[reg];               // s, scalar part
            } else {
                const unsigned nn = (unsigned)ro / 3u;
                const int k = ro - 3 * (int)nn;
                out[(size_t)nn * FEATD + MULT + w * 3 + k] = acc[reg]; // s, vec part
            }
        }
        cxlo = nxlo; cxhi = nxhi;
#pragma unroll
        for (int v = 0; v < ZDIM; ++v) czq[v] = nzq[v];
    }
}

// pass 2: xl = fctp(x, z, Wl1) staged INTERLEAVED: xli[n][u][4]={xs,v0,v1,v2}
// (round-8 lesson: aggregate's 4-scattered-row gather was the latency chain;
// interleaving makes the per-edge gather ONE f16x4 load per lane.)
__global__ __launch_bounds__(256, 2) void fctp_pass_xl(
    const f16_t* __restrict__ Xs, const f16_t* __restrict__ Xv,
    const float* __restrict__ zt, const float* __restrict__ ztv,
    const float* __restrict__ Wl10, const float* __restrict__ Wl11,
    f16_t* __restrict__ xli, int N, int nsc)
{
    const int lane = threadIdx.x & 63;
    const int wave = threadIdx.x >> 6;
    const int c0 = wave << 4;
    const int q = lane >> 4;
    const int mm = lane & 15;
    const bool sc = (int)blockIdx.x < nsc;
    const float* W = sc ? Wl10 : Wl11;
    const f16_t* Xsel = sc ? Xs : Xv;
    const float* ztb = sc ? zt : ztv;
    const size_t zsr = sc ? (size_t)N : (size_t)3 * N;
    const int ntiles = sc ? (N >> 4) : ((3 * N) >> 4);
    const int worker = sc ? (int)blockIdx.x : ((int)blockIdx.x - nsc);
    const int nworkers = sc ? nsc : 3 * nsc;

    f16x8_t B[20];
    preload_W(W, c0, q, mm, B);

    int tile = worker;
    if (tile >= ntiles) return;
    f16x8_t cxlo, cxhi;
    f32x4_t czq[ZDIM];
    {
        const int r = (tile << 4) + mm;
        cxlo = *(const f16x8_t*)(Xsel + ((size_t)r << 6) + (q << 3));
        cxhi = *(const f16x8_t*)(Xsel + ((size_t)r << 6) + 32 + (q << 3));
        const int rb4 = (tile << 4) + (q << 2);
#pragma unroll
        for (int v = 0; v < ZDIM; ++v)
            czq[v] = *(const f32x4_t*)(ztb + (size_t)v * zsr + rb4);
    }

    for (; tile < ntiles; tile += nworkers) {
        // ---- phase 1: issue ALL of next tile's loads ----
        const int nt = tile + nworkers;
        f16x8_t nxlo = cxlo, nxhi = cxhi;
        f32x4_t nzq[ZDIM];
#pragma unroll
        for (int v = 0; v < ZDIM; ++v) nzq[v] = czq[v];
        if (nt < ntiles) {
            const int r = (nt << 4) + mm;
            nxlo = *(const f16x8_t*)(Xsel + ((size_t)r << 6) + (q << 3));
            nxhi = *(const f16x8_t*)(Xsel + ((size_t)r << 6) + 32 + (q << 3));
            const int nrb4 = (nt << 4) + (q << 2);
#pragma unroll
            for (int v = 0; v < ZDIM; ++v)
                nzq[v] = *(const f32x4_t*)(ztb + (size_t)v * zsr + nrb4);
        }
        __builtin_amdgcn_sched_barrier(0);   // pin loads above compute

        // ---- phase 2: register-only compute on current tile ----
        const int rb4 = (tile << 4) + (q << 2);
        f32x4_t acc = {0.f, 0.f, 0.f, 0.f};
#pragma unroll
        for (int v = 0; v < ZDIM; ++v) {
            f32x4_t t = {0.f, 0.f, 0.f, 0.f};
            t = __builtin_amdgcn_mfma_f32_16x16x32_f16(cxlo, B[2 * v], t, 0, 0, 0);
            t = __builtin_amdgcn_mfma_f32_16x16x32_f16(cxhi, B[2 * v + 1], t, 0, 0, 0);
#pragma unroll
            for (int reg = 0; reg < 4; ++reg)
                acc[reg] = fmaf(czq[v][reg], t[reg], acc[reg]);
        }

        // ---- phase 3: stores (interleaved xli) ----
        const int w = c0 + mm;
#pragma unroll
        for (int reg = 0; reg < 4; ++reg) {
            const int ro = rb4 + reg;
            if (sc) {
                xli[((size_t)ro * 64 + w) * 4 + 0] = (f16_t)acc[reg];        // xs
            } else {
                const unsigned nn = (unsigned)ro / 3u;
                const int k = ro - 3 * (int)nn;
                xli[((size_t)nn * 64 + w) * 4 + 1 + k] = (f16_t)acc[reg];    // v_k
            }
        }
        cxlo = nxlo; cxhi = nxhi;
#pragma unroll
        for (int v = 0; v < ZDIM; ++v) czq[v] = nzq[v];
    }
}

// stage C: reads f16 agg rows (aggsh/aggvh via aggcvt), RMW on out.
__global__ __launch_bounds__(256, 2) void fctp_stageC_mfma(
    const f16_t* __restrict__ aggsh, const f16_t* __restrict__ aggvh,
    const float* __restrict__ zt, const float* __restrict__ ztv,
    const float* __restrict__ Wl20, const float* __restrict__ Wl21,
    float* __restrict__ out, int N, int nsc)
{
    const int lane = threadIdx.x & 63;
    const int wave = threadIdx.x >> 6;
    const int c0 = wave << 4;
    const int q = lane >> 4;
    const int mm = lane & 15;
    const bool sc = (int)blockIdx.x < nsc;
    const float* W = sc ? Wl20 : Wl21;
    const f16_t* Asel = sc ? aggsh : aggvh;
    const float* ztb = sc ? zt : ztv;
    const size_t zsr = sc ? (size_t)N : (size_t)3 * N;
    const int ntiles = sc ? (N >> 4) : ((3 * N) >> 4);
    const int worker = sc ? (int)blockIdx.x : ((int)blockIdx.x - nsc);
    const int nworkers = sc ? nsc : 3 * nsc;

    f16x8_t B[20];
    preload_W(W, c0, q, mm, B);

    int tile = worker;
    if (tile >= ntiles) return;
    f16x8_t cxlo, cxhi;
    f32x4_t czq[ZDIM];
    {
        const int r = (tile << 4) + mm;
        cxlo = *(const f16x8_t*)(Asel + ((size_t)r << 6) + (q << 3));
        cxhi = *(const f16x8_t*)(Asel + ((size_t)r << 6) + 32 + (q << 3));
        const int rb4 = (tile << 4) + (q << 2);
#pragma unroll
        for (int v = 0; v < ZDIM; ++v)
            czq[v] = *(const f32x4_t*)(ztb + (size_t)v * zsr + rb4);
    }

    for (; tile < ntiles; tile += nworkers) {
        // ---- phase 1: next tile's A+zq loads, and CURRENT out-old loads ----
        const int nt = tile + nworkers;
        f16x8_t nxlo = cxlo, nxhi = cxhi;
        f32x4_t nzq[ZDIM];
#pragma unroll
        for (int v = 0; v < ZDIM; ++v) nzq[v] = czq[v];
        if (nt < ntiles) {
            const int r = (nt << 4) + mm;
            nxlo = *(const f16x8_t*)(Asel + ((size_t)r << 6) + (q << 3));
            nxhi = *(const f16x8_t*)(Asel + ((size_t)r << 6) + 32 + (q << 3));
            const int nrb4 = (nt << 4) + (q << 2);
#pragma unroll
            for (int v = 0; v < ZDIM; ++v)
                nzq[v] = *(const f32x4_t*)(ztb + (size_t)v * zsr + nrb4);
        }
        const int rb4 = (tile << 4) + (q << 2);
        const int w = c0 + mm;
        size_t oidx[4];
        float oold[4];
#pragma unroll
        for (int reg = 0; reg < 4; ++reg) {
            const int ro = rb4 + reg;
            if (sc) {
                oidx[reg] = (size_t)ro * FEATD + w;
            } else {
                const unsigned nn = (unsigned)ro / 3u;
                const int k = ro - 3 * (int)nn;
                oidx[reg] = (size_t)nn * FEATD + MULT + w * 3 + k;
            }
            oold[reg] = out[oidx[reg]];
        }
        __builtin_amdgcn_sched_barrier(0);   // pin loads above compute

        // ---- phase 2: register-only compute ----
        f32x4_t acc = {0.f, 0.f, 0.f, 0.f};
#pragma unroll
        for (int v = 0; v < ZDIM; ++v) {
            f32x4_t t = {0.f, 0.f, 0.f, 0.f};
            t = __builtin_amdgcn_mfma_f32_16x16x32_f16(cxlo, B[2 * v], t, 0, 0, 0);
            t = __builtin_amdgcn_mfma_f32_16x16x32_f16(cxhi, B[2 * v + 1], t, 0, 0, 0);
#pragma unroll
            for (int reg = 0; reg < 4; ++reg)
                acc[reg] = fmaf(czq[v][reg], t[reg], acc[reg]);
        }

        // ---- phase 3: stores ----
#pragma unroll
        for (int reg = 0; reg < 4; ++reg)
            out[oidx[reg]] = oold[reg] + acc[reg] * 0.1f;   // s staged by pass_out; /10 here

        cxlo = nxlo; cxhi = nxhi;
#pragma unroll
        for (int v = 0; v < ZDIM; ++v) czq[v] = nzq[v];
    }
}

// ---------------------------------------------------------------------------
// Counting sort of edges by dst (unchanged). scatter emits perm, sperm
// (permuted src) and eattr_p (permuted edge_attr).
// ---------------------------------------------------------------------------
__global__ __launch_bounds__(256) void hist_kernel(
    const int* __restrict__ edst, int* __restrict__ cnt, int E)
{
    int e = blockIdx.x * 256 + threadIdx.x;
    if (e >= E) return;
    atomicAdd(&cnt[edst[e]], 1);
}

__global__ __launch_bounds__(1024) void scan_block(
    const int* __restrict__ cnt, int* __restrict__ off,
    int* __restrict__ bsum, int N)
{
    __shared__ int sh[1024];
    int tid = threadIdx.x;
    int i = blockIdx.x * 1024 + tid;
    int v = (i < N) ? cnt[i] : 0;
    sh[tid] = v;
    __syncthreads();
#pragma unroll
    for (int d = 1; d < 1024; d <<= 1) {
        int t = (tid >= d) ? sh[tid - d] : 0;
        __syncthreads();
        sh[tid] += t;
        __syncthreads();
    }
    if (i < N) off[i + 1] = sh[tid];
    if (tid == 1023) bsum[blockIdx.x] = sh[1023];
    if (i == 0) off[0] = 0;
}

__global__ __launch_bounds__(64) void scan_sums(int* __restrict__ bsum, int nb)
{
    int tid = threadIdx.x;
    int v = (tid < nb) ? bsum[tid] : 0;
#pragma unroll
    for (int d = 1; d < 64; d <<= 1) {
        int t = __shfl_up(v, d, 64);
        if (tid >= d) v += t;
    }
    int ex = __shfl_up(v, 1, 64);
    if (tid == 0) ex = 0;
    if (tid < nb) bsum[tid] = ex;
}

__global__ __launch_bounds__(1024) void scan_add(
    int* __restrict__ off, const int* __restrict__ bsum, int N)
{
    int i = blockIdx.x * 1024 + threadIdx.x;
    if (i < N) off[i + 1] += bsum[blockIdx.x];
}

__global__ __launch_bounds__(256) void scatter_kernel(
    const int* __restrict__ edst, const int* __restrict__ esrc,
    const float* __restrict__ eattr, const int* __restrict__ off,
    int* __restrict__ cursor, int* __restrict__ perm,
    int* __restrict__ sperm, float* __restrict__ eattr_p, int E)
{
    int e = blockIdx.x * 256 + threadIdx.x;
    if (e >= E) return;
    int d = edst[e];
    int pos = off[d] + atomicAdd(&cursor[d], 1);
    perm[pos] = e;
    sperm[pos] = esrc[e];
    float4 at = *(const float4*)(eattr + (size_t)e * 4);
    *(float4*)(eattr_p + (size_t)pos * 4) = at;
}

// ---------------------------------------------------------------------------
// aggregate6: FUSED wgemm + aggregate. One wave per node. Per 16-edge group:
// gather elem rows -> 16 MFMAs vs persistent tpwt B-frags -> w-tile staged in
// LDS (8KB/wave, wave-synchronous, NO __syncthreads). Per edge: 8B LDS wq
// read + eattr + ONE f16x4 xli gather (interleaved layout, round-8 lesson:
// was 4 scattered rows = the latency chain) with DEPTH-4 named-slot prefetch
// (rule #20: no runtime-indexed slot arrays). Single owner per node: plain
// stores, no memset.
// w-tile layout (validated round 8): component j of feature u = D[j*4+t][reg],
// t=u>>4, row=q*4+reg = edge offset in group.
// ---------------------------------------------------------------------------
__global__ __launch_bounds__(256, 3) void aggregate6(
    const int* __restrict__ off, const int* __restrict__ sperm,
    const int* __restrict__ perm, const float* __restrict__ elem,
    const f16_t* __restrict__ tpwt, const float* __restrict__ eattr_p,
    const f16_t* __restrict__ xli,
    float* __restrict__ aggs, float* __restrict__ aggv, int N)
{
    __shared__ f16_t wtile[4][16 * 256];     // 4 waves x 8KB
    int n = (blockIdx.x * 256 + threadIdx.x) >> 6;      // one wave per node
    if (n >= N) return;
    const int u = threadIdx.x & 63;
    const int wid = threadIdx.x >> 6;
    const int mm = u & 15, q = u >> 4;
    f16_t* wt = &wtile[wid][0];

    // persistent B-frags: stripe s covers cols s*16+mm, k = q*8+j
    f16x8_t B[16];
#pragma unroll
    for (int s = 0; s < 16; ++s)
        B[s] = *(const f16x8_t*)(tpwt + ((size_t)(s * 16 + mm)) * 32 + q * 8);

    int cs0 = __builtin_amdgcn_readfirstlane(off[n]);
    int cs1 = __builtin_amdgcn_readfirstlane(off[n + 1]);

    float accx = 0.f, accy = 0.f, accz = 0.f, accw = 0.f;

    if (cs0 < cs1) {
        const int last = cs1 - 1;

        // depth-4 prefetch: one 8B xli gather per slot (named slots, unrolled)
        f16x4_t xa, xb, xc, xd;
        {
            int i1 = (cs0 + 1 <= last) ? cs0 + 1 : last;
            int i2 = (cs0 + 2 <= last) ? cs0 + 2 : last;
            int i3 = (cs0 + 3 <= last) ? cs0 + 3 : last;
            int s0 = __builtin_amdgcn_readfirstlane(sperm[cs0]);
            int s1 = __builtin_amdgcn_readfirstlane(sperm[i1]);
            int s2 = __builtin_amdgcn_readfirstlane(sperm[i2]);
            int s3 = __builtin_amdgcn_readfirstlane(sperm[i3]);
            xa = *(const f16x4_t*)(xli + (((size_t)s0 << 6) + u) * 4);
            xb = *(const f16x4_t*)(xli + (((size_t)s1 << 6) + u) * 4);
            xc = *(const f16x4_t*)(xli + (((size_t)s2 << 6) + u) * 4);
            xd = *(const f16x4_t*)(xli + (((size_t)s3 << 6) + u) * 4);
        }

#define CONSUME_TP(X) { \
        f16x4_t wq = *(const f16x4_t*)(wt + ((size_t)((i - g) * 64 + u) << 2)); \
        float w1 = (float)wq[0], w2 = (float)wq[1], w3 = (float)wq[2], w4 = (float)wq[3]; \
        float4 at = *(const float4*)(eattr_p + ((size_t)i << 2)); \
        float xs = (float)X[0], v0 = (float)X[1], v1 = (float)X[2], v2 = (float)X[3]; \
        float dot3 = v0 * at.y + v1 * at.z + v2 * at.w; \
        accx = fmaf(w1 * xs, at.x, accx); \
        accx = fmaf(w4, dot3, accx); \
        float w2x = w2 * xs; \
        accy = fmaf(w2x, at.y, accy); \
        accz = fmaf(w2x, at.z, accz); \
        accw = fmaf(w2x, at.w, accw); \
        float w3s = w3 * at.x; \
        accy = fmaf(w3s, v0, accy); \
        accz = fmaf(w3s, v1, accz); \
        accw = fmaf(w3s, v2, accw); }

#define REFILL_TP(X) { \
        int inx = (i + 4 <= last) ? i + 4 : last; \
        int sn = __builtin_amdgcn_readfirstlane(sperm[inx]); \
        X = *(const f16x4_t*)(xli + (((size_t)sn << 6) + u) * 4); }

        int i = cs0;
        for (int g = cs0; g < cs1; g += 16) {
            const int gend = (g + 16 < cs1) ? g + 16 : cs1;

            // ---- w-tile phase: elem gather + 16 MFMA + LDS stage ----
            int pos = g + mm; if (pos > last) pos = last;   // pad w/ last edge
            int e = perm[pos];
            const float* er = elem + ((size_t)e << 5) + q * 8;
            float4 ea = *(const float4*)er;
            float4 eb = *(const float4*)(er + 4);
            f16x8_t A;
            A[0] = (f16_t)ea.x; A[1] = (f16_t)ea.y; A[2] = (f16_t)ea.z; A[3] = (f16_t)ea.w;
            A[4] = (f16_t)eb.x; A[5] = (f16_t)eb.y; A[6] = (f16_t)eb.z; A[7] = (f16_t)eb.w;

#pragma unroll
            for (int t = 0; t < 4; ++t) {
                f32x4_t D0 = {0.f, 0.f, 0.f, 0.f}, D1 = {0.f, 0.f, 0.f, 0.f};
                f32x4_t D2 = {0.f, 0.f, 0.f, 0.f}, D3 = {0.f, 0.f, 0.f, 0.f};
                D0 = __builtin_amdgcn_mfma_f32_16x16x32_f16(A, B[t],      D0, 0, 0, 0);
                D1 = __builtin_amdgcn_mfma_f32_16x16x32_f16(A, B[4 + t],  D1, 0, 0, 0);
                D2 = __builtin_amdgcn_mfma_f32_16x16x32_f16(A, B[8 + t],  D2, 0, 0, 0);
                D3 = __builtin_amdgcn_mfma_f32_16x16x32_f16(A, B[12 + t], D3, 0, 0, 0);
#pragma unroll
                for (int reg = 0; reg < 4; ++reg) {
                    const int row = (q << 2) + reg;          // edge offset in group
                    f16x4_t wq;
                    wq[0] = (f16_t)D0[reg];   // w1
                    wq[1] = (f16_t)D1[reg];   // w2
                    wq[2] = (f16_t)D2[reg];   // w3
                    wq[3] = (f16_t)D3[reg];   // w4 (ISQ3 baked in tpwt)
                    *(f16x4_t*)(wt + ((size_t)(row * 64 + (t * 16 + mm)) << 2)) = wq;
                }
            }

            // ---- aggregate edges [i, gend), 4-slot rotation ----
            // group size 16 divisible by 4 -> slot alignment holds across
            // groups; breaks only happen in the final group.
            while (i < gend) {
                CONSUME_TP(xa); REFILL_TP(xa); if (++i >= gend) break;
                CONSUME_TP(xb); REFILL_TP(xb); if (++i >= gend) break;
                CONSUME_TP(xc); REFILL_TP(xc); if (++i >= gend) break;
                CONSUME_TP(xd); REFILL_TP(xd); ++i;
            }
        }
#undef CONSUME_TP
#undef REFILL_TP
    }

    // single owner per node: plain store (replaces memset + '+=')
    aggs[((size_t)n << 6) + u] = accx;
    aggv[((size_t)(3 * n + 0) << 6) + u] = accy;
    aggv[((size_t)(3 * n + 1) << 6) + u] = accz;
    aggv[((size_t)(3 * n + 2) << 6) + u] = accw;
}

// ---------------------------------------------------------------------------
extern "C" void kernel_launch(void* const* d_in, const int* in_sizes, int n_in,
                              void* d_out, int out_size, void* d_ws, size_t ws_size,
                              hipStream_t stream)
{
    const float* x     = (const float*)d_in[0];
    const float* z     = (const float*)d_in[1];
    const int*   esrc  = (const int*)d_in[2];
    const int*   edst  = (const int*)d_in[3];
    const float* elem  = (const float*)d_in[4];
    const float* eattr = (const float*)d_in[5];
    const float* Wsi0  = (const float*)d_in[6];
    const float* Wsi1  = (const float*)d_in[7];
    const float* Wl10  = (const float*)d_in[8];
    const float* Wl11  = (const float*)d_in[9];
    const float* Wl20  = (const float*)d_in[10];
    const float* Wl21  = (const float*)d_in[11];
    const float* tpw   = (const float*)d_in[12];
    float* out = (float*)d_out;

    const int N = in_sizes[1] / ZDIM;      // 50000
    const int E = in_sizes[2];             // 500000
    const int Ehalf = E / 2;               // 250000 (layout constant, kept)

    // workspace carve-up (layout kept; xli replaces xls+xlv, same 4N*64 f16):
    f16_t* xli  = (f16_t*)d_ws;                          // 4N*64  f16 (interleaved)
    float* aggs = (float*)(xli + (size_t)4 * N * 64);    // N*64   f32
    float* aggv = aggs + (size_t)N * 64;                 // 3N*64  f32
    // region R: union of {Xs,Xv} (dead after fctp passes) and aggh (f16 agg)
    char*  R    = (char*)(aggv + (size_t)3 * N * 64);
    f16_t* Xs   = (f16_t*)R;                             // N*64   f16
    f16_t* Xv   = Xs + (size_t)N * 64;                   // 3N*64  f16
    f16_t* aggh = (f16_t*)R;                             // 4N*64 f16 (25.6 MB)
    size_t Rbytes = (size_t)Ehalf * 256 * sizeof(f16_t); // 128 MB (kept)
    float* eattr_p = (float*)(R + Rbytes);               // E*4 f32
    int*   sperm   = (int*)(eattr_p + (size_t)E * 4);    // E
    int*   perm    = sperm + E;                          // E
    int*   cnt     = perm + E;                           // N
    int*   cursor  = cnt + N;                            // N
    int*   off     = cursor + N;                         // N+1
    int*   bsum    = off + (N + 1);                      // 64
    // z transposes, 256B-aligned for float4 loads: zt (10N) + ztv (30N) f32
    size_t zoff = (((size_t)(bsum + 64) - (size_t)d_ws) + 255) & ~(size_t)255;
    float* zt  = (float*)((char*)d_ws + zoff);           // 10N f32 (2 MB)
    float* ztv = zt + (size_t)10 * N;                    // 30N f32 (6 MB)
    f16_t* tpwt = (f16_t*)(ztv + (size_t)30 * N);        // 256*32 f16 (16 KB)

    const int SCAN_B = 1024;
    int nb = (N + SCAN_B - 1) / SCAN_B;  // 49 (<=64 required by scan_sums)

    hipMemsetAsync(cnt, 0, 2 * (size_t)N * sizeof(int), stream);   // cnt+cursor
    // NOTE: no aggs/aggv memset — aggregate6 writes every node exactly once.

    int g0 = (N * MULT + 255) / 256;
    hipLaunchKernelGGL(transform_x2, dim3(g0), dim3(256), 0, stream, x, Xs, Xv, N);
    int gz = (N + 255) / 256;
    hipLaunchKernelGGL(zprep_kernel, dim3(gz), dim3(256), 0, stream, z, zt, ztv, N);
    hipLaunchKernelGGL(tpwprep_kernel, dim3(32), dim3(256), 0, stream, tpw, tpwt);

    // stageA split: two single-W passes at (256,2) -> B[20] fits, no spill
    hipLaunchKernelGGL(fctp_pass_xl, dim3(512), dim3(256), 0, stream,
                       Xs, Xv, zt, ztv, Wl10, Wl11, xli, N, 128);
    hipLaunchKernelGGL(fctp_pass_out, dim3(512), dim3(256), 0, stream,
                       Xs, Xv, zt, ztv, Wsi0, Wsi1, out, N, 128);

    int geh = (E + 255) / 256;
    hipLaunchKernelGGL(hist_kernel, dim3(geh), dim3(256), 0, stream,
                       edst, cnt, E);
    hipLaunchKernelGGL(scan_block, dim3(nb), dim3(SCAN_B), 0, stream,
                       cnt, off, bsum, N);
    hipLaunchKernelGGL(scan_sums, dim3(1), dim3(64), 0, stream, bsum, nb);
    hipLaunchKernelGGL(scan_add, dim3(nb), dim3(SCAN_B), 0, stream,
                       off, bsum, N);
    hipLaunchKernelGGL(scatter_kernel, dim3(geh), dim3(256), 0, stream,
                       edst, esrc, eattr, off, cursor, perm, sperm, eattr_p, E);

    // fused w-gemm + aggregate: single pass over all edges, w staged in LDS
    int ga = (N * 64 + 255) / 256;
    hipLaunchKernelGGL(aggregate6, dim3(ga), dim3(256), 0, stream,
                       off, sperm, perm, elem, tpwt, eattr_p, xli,
                       aggs, aggv, N);

    // agg f32 -> f16 (aggh aliases R; Xs/Xv dead), then stage C
    int n4 = N * 64;                           // (4N*64)/4 float4 groups
    int gc = (n4 + 255) / 256;
    hipLaunchKernelGGL(aggcvt_kernel, dim3(gc), dim3(256), 0, stream,
                       aggs, aggh, n4);
    hipLaunchKernelGGL(fctp_stageC_mfma, dim3(512), dim3(256), 0, stream,
                       aggh, aggh + (size_t)N * 64, zt, ztv, Wl20, Wl21,
                       out, N, 128);
}